// Round 1
// baseline (2142.438 us; speedup 1.0000x reference)
//
#include <hip/hip_runtime.h>
#include <math.h>

#define N_NODES 192000
#define EDGES   2000000
#define HID     64
#define BN_ROWS 16000   // B*NN
#define T_WIN   12
#define B_SZ    8
#define NN_SZ   2000
#define FIN     8
#define BN_EPS  1e-5f
#define RROWS   16

__device__ __forceinline__ float sigf(float x){ return 1.0f/(1.0f+expf(-x)); }

// ---------- degree / normalization ----------
__global__ void fill_deg(float* deg){
    int i = blockIdx.x*blockDim.x + threadIdx.x;
    if (i < N_NODES) deg[i] = 1.0f;   // self-loop weight
}

__global__ void deg_accum(const int* __restrict__ col, const float* __restrict__ w, float* deg){
    int e = blockIdx.x*blockDim.x + threadIdx.x;
    if (e < EDGES) atomicAdd(&deg[col[e]], w[e]);
}

__global__ void deg_to_dis(float* deg){
    int i = blockIdx.x*blockDim.x + threadIdx.x;
    if (i < N_NODES) deg[i] = rsqrtf(deg[i]);   // deg >= 1 always
}

// ---------- dense linears ----------
// hlin = x @ W1   (x:[N,8], W1:[8,64])
__global__ void lin1(const float* __restrict__ x, const float* __restrict__ W1, float* __restrict__ out){
    __shared__ float Ws[8*64];
    for (int idx = threadIdx.x; idx < 512; idx += blockDim.x) Ws[idx] = W1[idx];
    __syncthreads();
    int gid = blockIdx.x*blockDim.x + threadIdx.x;
    if (gid >= N_NODES*64) return;
    int i = gid >> 6, f = gid & 63;
    const float* xr = x + i*FIN;
    float acc = 0.f;
    #pragma unroll
    for (int k = 0; k < FIN; k++) acc += xr[k]*Ws[k*64+f];
    out[gid] = acc;
}

// hlin = h @ W2   (h:[N,64], W2:[64,64])
__global__ void lin2(const float* __restrict__ h, const float* __restrict__ W2, float* __restrict__ out){
    __shared__ float Ws[64*64];
    for (int idx = threadIdx.x; idx < 4096; idx += blockDim.x) Ws[idx] = W2[idx];
    __syncthreads();
    int gid = blockIdx.x*blockDim.x + threadIdx.x;
    if (gid >= N_NODES*64) return;
    int i = gid >> 6, f = gid & 63;
    const float* hr = h + i*64;
    float acc = 0.f;
    #pragma unroll 8
    for (int k = 0; k < 64; k++) acc += hr[k]*Ws[k*64+f];
    out[gid] = acc;
}

// ---------- GCN aggregation ----------
__global__ void self_loop_init(const float* __restrict__ hlin, const float* __restrict__ dis,
                               float* __restrict__ outA){
    int gid = blockIdx.x*blockDim.x + threadIdx.x;
    if (gid >= N_NODES*64) return;
    int i = gid >> 6;
    float d = dis[i];
    outA[gid] = hlin[gid]*d*d;
}

__global__ void scatter_edges(const int* __restrict__ row, const int* __restrict__ col,
                              const float* __restrict__ w, const float* __restrict__ dis,
                              const float* __restrict__ hlin, float* __restrict__ outA){
    int gid = blockIdx.x*blockDim.x + threadIdx.x;   // E*64 = 128M < 2^31
    int e = gid >> 6, lane = gid & 63;
    if (e >= EDGES) return;
    int r = row[e], c = col[e];
    float nrm = dis[r]*w[e]*dis[c];
    atomicAdd(&outA[c*64 + lane], hlin[r*64 + lane]*nrm);
}

// ---------- BatchNorm (training-mode batch stats) ----------
__global__ void bias_relu_stats(float* __restrict__ a, const float* __restrict__ bias,
                                float* __restrict__ gsum, float* __restrict__ gsq){
    int f = threadIdx.x & 63;
    float b = bias[f];
    float s = 0.f, s2 = 0.f;
    int stride = gridDim.x*blockDim.x;   // multiple of 64 -> f constant per thread
    for (int idx = blockIdx.x*blockDim.x + threadIdx.x; idx < N_NODES*64; idx += stride){
        float v = fmaxf(a[idx] + b, 0.f);
        a[idx] = v;
        s += v; s2 += v*v;
    }
    __shared__ float s1m[256], s2m[256];
    s1m[threadIdx.x] = s; s2m[threadIdx.x] = s2;
    __syncthreads();
    if (threadIdx.x < 64){
        float t1 = s1m[threadIdx.x]+s1m[threadIdx.x+64]+s1m[threadIdx.x+128]+s1m[threadIdx.x+192];
        float t2 = s2m[threadIdx.x]+s2m[threadIdx.x+64]+s2m[threadIdx.x+128]+s2m[threadIdx.x+192];
        atomicAdd(&gsum[threadIdx.x], t1);
        atomicAdd(&gsq[threadIdx.x], t2);
    }
}

__global__ void bn_finalize(const float* gsum, const float* gsq, const float* g, const float* be,
                            float* scale, float* shift){
    int f = threadIdx.x;
    if (f < 64){
        float mean = gsum[f] * (1.0f/(float)N_NODES);
        float var  = gsq[f]  * (1.0f/(float)N_NODES) - mean*mean;
        var = fmaxf(var, 0.f);
        float sc = g[f]*rsqrtf(var + BN_EPS);
        scale[f] = sc;
        shift[f] = be[f] - mean*sc;
    }
}

__global__ void bn_apply(const float* __restrict__ a, const float* __restrict__ scale,
                         const float* __restrict__ shift, float* __restrict__ out){
    int gid = blockIdx.x*blockDim.x + threadIdx.x;
    if (gid >= N_NODES*64) return;
    int f = gid & 63;
    out[gid] = a[gid]*scale[f] + shift[f];
}

// ---------- LSTM weight prep: transpose to [K,256] input-major ----------
__global__ void prep_weights(const float* __restrict__ Wih1, const float* __restrict__ Whh1,
                             const float* __restrict__ bih1, const float* __restrict__ bhh1,
                             const float* __restrict__ Wih2, const float* __restrict__ Whh2,
                             const float* __restrict__ bih2, const float* __restrict__ bhh2,
                             float* W1T, float* W2T, float* b1c, float* b2c){
    int idx = blockIdx.x*blockDim.x + threadIdx.x;
    if (idx < 192*256){
        int k = idx >> 8, g = idx & 255;
        W1T[idx] = (k < 128) ? Wih1[g*128 + k] : Whh1[g*64 + (k-128)];
    }
    int i2 = idx - 192*256;
    if (i2 >= 0 && i2 < 128*256){
        int k = i2 >> 8, g = i2 & 255;
        W2T[i2] = (k < 64) ? Wih2[g*64 + k] : Whh2[g*64 + (k-64)];
    }
    int i3 = idx - (192*256 + 128*256);
    if (i3 >= 0 && i3 < 256) b1c[i3] = bih1[i3] + bhh1[i3];
    int i4 = i3 - 256;
    if (i4 >= 0 && i4 < 256) b2c[i4] = bih2[i4] + bhh2[i4];
}

// ---------- fused LSTM1+LSTM2 one time step ----------
__global__ __launch_bounds__(256) void lstm_step(
        const float* __restrict__ h1, const float* __restrict__ h2,
        const float* __restrict__ W1T, const float* __restrict__ W2T,
        const float* __restrict__ b1c, const float* __restrict__ b2c,
        float* __restrict__ h1s, float* __restrict__ c1s,
        float* __restrict__ h2s, float* __restrict__ c2s, int t){
    __shared__ float xs[RROWS*192];
    __shared__ float gsm[RROWS*256];
    int tid = threadIdx.x;
    int j0 = blockIdx.x * RROWS;

    // stage inputs: xs[r][k] = k<64: h1[rowg][k] | k<128: h2[rowg][k-64] | k<192: h1s[j][k-128]
    for (int idx = tid; idx < RROWS*192; idx += 256){
        int r = idx / 192, k = idx - r*192;
        int j = j0 + r;
        float v;
        if (k < 128){
            int b = j / NN_SZ, n = j - b*NN_SZ;
            int rowg = (b*T_WIN + t)*NN_SZ + n;
            v = (k < 64) ? h1[rowg*64 + k] : h2[rowg*64 + (k-64)];
        } else {
            v = h1s[j*64 + (k-128)];
        }
        xs[idx] = v;
    }
    __syncthreads();

    int cg = tid & 63;   // cols cg*4 .. cg*4+3
    int rg = tid >> 6;   // rows rg*4 .. rg*4+3
    float acc[4][4];

    // ---- phase 1: gates1 = [xt | h1_prev] @ W1T + b1c ----
    {
        float4 bv = *(const float4*)&b1c[cg*4];
        #pragma unroll
        for (int rr = 0; rr < 4; rr++){ acc[rr][0]=bv.x; acc[rr][1]=bv.y; acc[rr][2]=bv.z; acc[rr][3]=bv.w; }
    }
    for (int k = 0; k < 192; k++){
        float4 wv = *(const float4*)&W1T[k*256 + cg*4];
        #pragma unroll
        for (int rr = 0; rr < 4; rr++){
            float a = xs[(rg*4+rr)*192 + k];
            acc[rr][0] += a*wv.x; acc[rr][1] += a*wv.y; acc[rr][2] += a*wv.z; acc[rr][3] += a*wv.w;
        }
    }
    #pragma unroll
    for (int rr = 0; rr < 4; rr++)
        *(float4*)&gsm[(rg*4+rr)*256 + cg*4] = make_float4(acc[rr][0],acc[rr][1],acc[rr][2],acc[rr][3]);
    __syncthreads();

    // ---- cell update 1; build xs2 (reuse xs): [r][0:64]=h1_new, [r][64:128]=h2_prev ----
    for (int it = 0; it < RROWS/4; it++){
        int r = (tid >> 6) + it*4;
        int f = tid & 63;
        int j = j0 + r;
        float gi = gsm[r*256 + f];
        float gf = gsm[r*256 + 64 + f];
        float gg = gsm[r*256 + 128 + f];
        float go = gsm[r*256 + 192 + f];
        float cn = sigf(gf)*c1s[j*64+f] + sigf(gi)*tanhf(gg);
        float hn = sigf(go)*tanhf(cn);
        c1s[j*64+f] = cn;
        h1s[j*64+f] = hn;
        xs[r*128 + f]      = hn;
        xs[r*128 + 64 + f] = h2s[j*64+f];
    }
    __syncthreads();

    // ---- phase 2: gates2 = [y1_t | h2_prev] @ W2T + b2c ----
    {
        float4 bv = *(const float4*)&b2c[cg*4];
        #pragma unroll
        for (int rr = 0; rr < 4; rr++){ acc[rr][0]=bv.x; acc[rr][1]=bv.y; acc[rr][2]=bv.z; acc[rr][3]=bv.w; }
    }
    for (int k = 0; k < 128; k++){
        float4 wv = *(const float4*)&W2T[k*256 + cg*4];
        #pragma unroll
        for (int rr = 0; rr < 4; rr++){
            float a = xs[(rg*4+rr)*128 + k];
            acc[rr][0] += a*wv.x; acc[rr][1] += a*wv.y; acc[rr][2] += a*wv.z; acc[rr][3] += a*wv.w;
        }
    }
    #pragma unroll
    for (int rr = 0; rr < 4; rr++)
        *(float4*)&gsm[(rg*4+rr)*256 + cg*4] = make_float4(acc[rr][0],acc[rr][1],acc[rr][2],acc[rr][3]);
    __syncthreads();

    // ---- cell update 2 ----
    for (int it = 0; it < RROWS/4; it++){
        int r = (tid >> 6) + it*4;
        int f = tid & 63;
        int j = j0 + r;
        float gi = gsm[r*256 + f];
        float gf = gsm[r*256 + 64 + f];
        float gg = gsm[r*256 + 128 + f];
        float go = gsm[r*256 + 192 + f];
        float cn = sigf(gf)*c2s[j*64+f] + sigf(gi)*tanhf(gg);
        float hn = sigf(go)*tanhf(cn);
        c2s[j*64+f] = cn;
        h2s[j*64+f] = hn;
    }
}

// ---------- FC head ----------
__global__ __launch_bounds__(256) void fc_head(
        const float* __restrict__ h1s, const float* __restrict__ h2s,
        const float* __restrict__ inner, const float* __restrict__ x,
        const float* __restrict__ fc1_w, const float* __restrict__ fc1_b,
        const float* __restrict__ fc3_w, const float* __restrict__ fc3_b,
        float* __restrict__ out){
    __shared__ float zsm[4][226];
    int wv = threadIdx.x >> 6;
    int f  = threadIdx.x & 63;
    int j  = blockIdx.x*4 + wv;
    int b = j / NN_SZ, n = j - b*NN_SZ;
    for (int k = f; k < 225; k += 64){
        float v;
        if (k < 64)        v = h1s[j*64 + k];
        else if (k < 128)  v = h2s[j*64 + (k-64)];
        else if (k == 128) v = inner[j];
        else {
            int kk = k - 129;
            int w_ = kk >> 3, ff = kk & 7;
            v = x[((b*T_WIN + w_)*NN_SZ + n)*FIN + ff];
        }
        zsm[wv][k] = v;
    }
    __syncthreads();
    float acc = fc1_b[f];
    for (int k = 0; k < 225; k++) acc += zsm[wv][k]*fc1_w[k*64 + f];
    float p = fmaxf(acc, 0.f) * fc3_w[f];
    #pragma unroll
    for (int off = 32; off > 0; off >>= 1) p += __shfl_down(p, off, 64);
    if (f == 0) out[j] = fmaxf(p + fc3_b[0], 0.f);
}

extern "C" void kernel_launch(void* const* d_in, const int* in_sizes, int n_in,
                              void* d_out, int out_size, void* d_ws, size_t ws_size,
                              hipStream_t stream){
    const int*   adj  = (const int*)d_in[0];
    const int*   row  = adj;
    const int*   col  = adj + EDGES;
    const float* aw   = (const float*)d_in[1];
    const float* x    = (const float*)d_in[2];
    const float* inner= (const float*)d_in[3];
    const float* W1   = (const float*)d_in[4];
    const float* b1   = (const float*)d_in[5];
    const float* W2   = (const float*)d_in[6];
    const float* b2   = (const float*)d_in[7];
    const float* g1   = (const float*)d_in[8];
    const float* be1  = (const float*)d_in[9];
    const float* g2   = (const float*)d_in[10];
    const float* be2  = (const float*)d_in[11];
    const float* Wih1 = (const float*)d_in[12];
    const float* Whh1 = (const float*)d_in[13];
    const float* bih1 = (const float*)d_in[14];
    const float* bhh1 = (const float*)d_in[15];
    const float* Wih2 = (const float*)d_in[16];
    const float* Whh2 = (const float*)d_in[17];
    const float* bih2 = (const float*)d_in[18];
    const float* bhh2 = (const float*)d_in[19];
    const float* fc1w = (const float*)d_in[20];
    const float* fc1b = (const float*)d_in[21];
    const float* fc3w = (const float*)d_in[22];
    const float* fc3b = (const float*)d_in[23];
    float* out = (float*)d_out;

    float* ws = (float*)d_ws;
    const size_t NB = (size_t)N_NODES*64;            // 12,288,000 floats
    float* bufX = ws;                                 // hlin (both layers), then h2
    float* bufY = ws + NB;                            // gcnA, then LSTM states + weightsT
    float* bufZ = ws + 2*NB;                          // h1
    float* dis  = ws + 3*NB;                          // [N]
    float* gsum = dis + N_NODES;                      // 64
    float* gsq  = gsum + 64;                          // 64
    float* scal = gsq + 64;                           // 64
    float* shif = scal + 64;                          // 64
    // aliases into bufY after GCN phase:
    float* h1s = bufY;
    float* c1s = bufY + (size_t)BN_ROWS*64;
    float* h2s = bufY + (size_t)2*BN_ROWS*64;
    float* c2s = bufY + (size_t)3*BN_ROWS*64;
    float* W1T = bufY + (size_t)4*BN_ROWS*64;         // 4,096,000 (16B aligned)
    float* W2T = W1T + 192*256;
    float* b1c = W2T + 128*256;
    float* b2c = b1c + 256;

    float* hlin = bufX;
    float* gcnA = bufY;
    float* h1   = bufZ;
    float* h2   = bufX;   // written after hlin is dead

    // degrees / symmetric norm
    fill_deg  <<<750, 256, 0, stream>>>(dis);
    deg_accum <<<(EDGES+255)/256, 256, 0, stream>>>(col, aw, dis);
    deg_to_dis<<<750, 256, 0, stream>>>(dis);

    // ---- GCN layer 1 ----
    lin1<<<48000, 256, 0, stream>>>(x, W1, hlin);
    self_loop_init<<<48000, 256, 0, stream>>>(hlin, dis, gcnA);
    scatter_edges<<<EDGES/4, 256, 0, stream>>>(row, col, aw, dis, hlin, gcnA);
    hipMemsetAsync(gsum, 0, 128*sizeof(float), stream);
    bias_relu_stats<<<1024, 256, 0, stream>>>(gcnA, b1, gsum, gsq);
    bn_finalize<<<1, 64, 0, stream>>>(gsum, gsq, g1, be1, scal, shif);
    bn_apply<<<48000, 256, 0, stream>>>(gcnA, scal, shif, h1);

    // ---- GCN layer 2 ----
    lin2<<<48000, 256, 0, stream>>>(h1, W2, hlin);
    self_loop_init<<<48000, 256, 0, stream>>>(hlin, dis, gcnA);
    scatter_edges<<<EDGES/4, 256, 0, stream>>>(row, col, aw, dis, hlin, gcnA);
    hipMemsetAsync(gsum, 0, 128*sizeof(float), stream);
    bias_relu_stats<<<1024, 256, 0, stream>>>(gcnA, b2, gsum, gsq);
    bn_finalize<<<1, 64, 0, stream>>>(gsum, gsq, g2, be2, scal, shif);
    bn_apply<<<48000, 256, 0, stream>>>(gcnA, scal, shif, h2);   // h2 -> bufX (hlin dead)

    // ---- LSTMs (states alias bufY: gcnA dead after bn_apply) ----
    prep_weights<<<(192*256 + 128*256 + 512 + 255)/256, 256, 0, stream>>>(
        Wih1, Whh1, bih1, bhh1, Wih2, Whh2, bih2, bhh2, W1T, W2T, b1c, b2c);
    hipMemsetAsync(h1s, 0, (size_t)4*BN_ROWS*64*sizeof(float), stream);
    for (int t = 0; t < T_WIN; t++)
        lstm_step<<<BN_ROWS/RROWS, 256, 0, stream>>>(h1, h2, W1T, W2T, b1c, b2c,
                                                     h1s, c1s, h2s, c2s, t);

    // ---- FC head ----
    fc_head<<<BN_ROWS/4, 256, 0, stream>>>(h1s, h2s, inner, x, fc1w, fc1b, fc3w, fc3b, out);
}

// Round 2
// 1717.247 us; speedup vs baseline: 1.2476x; 1.2476x over previous
//
#include <hip/hip_runtime.h>
#include <math.h>

#define N_NODES 192000
#define EDGES   2000000
#define HID     64
#define BN_ROWS 16000   // B*NN
#define T_WIN   12
#define B_SZ    8
#define NN_SZ   2000
#define FIN     8
#define BN_EPS  1e-5f
#define RROWS   16

__device__ __forceinline__ float sigf(float x){ return 1.0f/(1.0f+expf(-x)); }

// ---------- degree / normalization ----------
__global__ void fill_deg(float* deg){
    int i = blockIdx.x*blockDim.x + threadIdx.x;
    if (i < N_NODES) deg[i] = 1.0f;   // self-loop weight
}

__global__ void deg_accum(const int* __restrict__ col, const float* __restrict__ w, float* deg){
    int e = blockIdx.x*blockDim.x + threadIdx.x;
    if (e < EDGES) atomicAdd(&deg[col[e]], w[e]);
}

__global__ void deg_to_dis(float* deg){
    int i = blockIdx.x*blockDim.x + threadIdx.x;
    if (i < N_NODES) deg[i] = rsqrtf(deg[i]);   // deg >= 1 always
}

// ---------- CSR build ----------
__global__ void hist_col(const int* __restrict__ col, int* __restrict__ cnt){
    int e = blockIdx.x*blockDim.x + threadIdx.x;
    if (e < EDGES) atomicAdd(&cnt[col[e]], 1);
}

// per-block exclusive scan of 256 counts; block totals to bsum
__global__ void scanA(const int* __restrict__ cnt, int* __restrict__ excl, int* __restrict__ bsum){
    __shared__ int sm[256];
    int i = blockIdx.x*256 + threadIdx.x;
    int v = cnt[i];
    sm[threadIdx.x] = v;
    __syncthreads();
    #pragma unroll
    for (int off = 1; off < 256; off <<= 1){
        int t = (threadIdx.x >= off) ? sm[threadIdx.x - off] : 0;
        __syncthreads();
        sm[threadIdx.x] += t;
        __syncthreads();
    }
    excl[i] = sm[threadIdx.x] - v;
    if (threadIdx.x == 255) bsum[blockIdx.x] = sm[255];
}

// scan the 750 block sums (single block, 1024 threads)
__global__ void scanB(const int* __restrict__ bsum, int* __restrict__ bscan, int nb){
    __shared__ int sm[1024];
    int tid = threadIdx.x;
    int v = (tid < nb) ? bsum[tid] : 0;
    sm[tid] = v;
    __syncthreads();
    #pragma unroll
    for (int off = 1; off < 1024; off <<= 1){
        int t = (tid >= off) ? sm[tid - off] : 0;
        __syncthreads();
        sm[tid] += t;
        __syncthreads();
    }
    bscan[tid] = sm[tid] - v;
}

__global__ void scanC(const int* __restrict__ excl, const int* __restrict__ bscan,
                      int* __restrict__ offsets, int* __restrict__ cursor){
    int i = blockIdx.x*256 + threadIdx.x;
    int off = excl[i] + bscan[i >> 8];
    offsets[i] = off;
    cursor[i]  = off;
    if (i == N_NODES-1) offsets[N_NODES] = EDGES;
}

__global__ void build_csr(const int* __restrict__ row, const int* __restrict__ col,
                          const float* __restrict__ w, const float* __restrict__ dis,
                          int* __restrict__ cursor, int* __restrict__ rows_s,
                          float* __restrict__ norm_s){
    int e = blockIdx.x*blockDim.x + threadIdx.x;
    if (e >= EDGES) return;
    int r = row[e], c = col[e];
    float nr = dis[r]*w[e]*dis[c];
    int p = atomicAdd(&cursor[c], 1);
    rows_s[p] = r;
    norm_s[p] = nr;
}

// ---------- dense linears ----------
// hlin = x @ W1   (x:[N,8], W1:[8,64])
__global__ void lin1(const float* __restrict__ x, const float* __restrict__ W1, float* __restrict__ out){
    __shared__ float Ws[8*64];
    for (int idx = threadIdx.x; idx < 512; idx += blockDim.x) Ws[idx] = W1[idx];
    __syncthreads();
    int gid = blockIdx.x*blockDim.x + threadIdx.x;
    if (gid >= N_NODES*64) return;
    int i = gid >> 6, f = gid & 63;
    const float* xr = x + i*FIN;
    float acc = 0.f;
    #pragma unroll
    for (int k = 0; k < FIN; k++) acc += xr[k]*Ws[k*64+f];
    out[gid] = acc;
}

// hlin = h @ W2   (h:[N,64], W2:[64,64])
__global__ void lin2(const float* __restrict__ h, const float* __restrict__ W2, float* __restrict__ out){
    __shared__ float Ws[64*64];
    for (int idx = threadIdx.x; idx < 4096; idx += blockDim.x) Ws[idx] = W2[idx];
    __syncthreads();
    int gid = blockIdx.x*blockDim.x + threadIdx.x;
    if (gid >= N_NODES*64) return;
    int i = gid >> 6, f = gid & 63;
    const float* hr = h + i*64;
    float acc = 0.f;
    #pragma unroll 8
    for (int k = 0; k < 64; k++) acc += hr[k]*Ws[k*64+f];
    out[gid] = acc;
}

// ---------- GCN aggregation: one wave per destination node ----------
// outA[j,f] = relu( bias[f] + dis[j]^2*hlin[j,f] + sum_k norm_s[k]*hlin[rows_s[k],f] )
__global__ __launch_bounds__(256) void gather_csr(
        const int* __restrict__ offsets, const int* __restrict__ rows_s,
        const float* __restrict__ norm_s, const float* __restrict__ dis,
        const float* __restrict__ hlin, const float* __restrict__ bias,
        float* __restrict__ outA){
    int j = blockIdx.x*4 + (threadIdx.x >> 6);
    int f = threadIdx.x & 63;
    float d = dis[j];
    float acc = hlin[j*64 + f]*d*d;
    int k  = offsets[j];
    int k1 = offsets[j+1];
    for (; k+2 <= k1; k += 2){
        int   r0 = rows_s[k],   r1 = rows_s[k+1];
        float n0 = norm_s[k],   n1 = norm_s[k+1];
        acc += hlin[r0*64 + f]*n0;
        acc += hlin[r1*64 + f]*n1;
    }
    if (k < k1){
        int r0 = rows_s[k];
        acc += hlin[r0*64 + f]*norm_s[k];
    }
    outA[j*64 + f] = fmaxf(acc + bias[f], 0.f);
}

// ---------- BatchNorm (training-mode batch stats) ----------
__global__ void stats_only(const float* __restrict__ a,
                           float* __restrict__ gsum, float* __restrict__ gsq){
    float s = 0.f, s2 = 0.f;
    int stride = gridDim.x*blockDim.x;   // multiple of 64 -> feature const per thread
    for (int idx = blockIdx.x*blockDim.x + threadIdx.x; idx < N_NODES*64; idx += stride){
        float v = a[idx];
        s += v; s2 += v*v;
    }
    __shared__ float s1m[256], s2m[256];
    s1m[threadIdx.x] = s; s2m[threadIdx.x] = s2;
    __syncthreads();
    if (threadIdx.x < 64){
        float t1 = s1m[threadIdx.x]+s1m[threadIdx.x+64]+s1m[threadIdx.x+128]+s1m[threadIdx.x+192];
        float t2 = s2m[threadIdx.x]+s2m[threadIdx.x+64]+s2m[threadIdx.x+128]+s2m[threadIdx.x+192];
        atomicAdd(&gsum[threadIdx.x], t1);
        atomicAdd(&gsq[threadIdx.x], t2);
    }
}

__global__ void bn_finalize(const float* gsum, const float* gsq, const float* g, const float* be,
                            float* scale, float* shift){
    int f = threadIdx.x;
    if (f < 64){
        float mean = gsum[f] * (1.0f/(float)N_NODES);
        float var  = gsq[f]  * (1.0f/(float)N_NODES) - mean*mean;
        var = fmaxf(var, 0.f);
        float sc = g[f]*rsqrtf(var + BN_EPS);
        scale[f] = sc;
        shift[f] = be[f] - mean*sc;
    }
}

__global__ void bn_apply(const float* __restrict__ a, const float* __restrict__ scale,
                         const float* __restrict__ shift, float* __restrict__ out){
    int gid = blockIdx.x*blockDim.x + threadIdx.x;
    if (gid >= N_NODES*64) return;
    int f = gid & 63;
    out[gid] = a[gid]*scale[f] + shift[f];
}

// ---------- LSTM weight prep: transpose to [K,256] input-major ----------
__global__ void prep_weights(const float* __restrict__ Wih1, const float* __restrict__ Whh1,
                             const float* __restrict__ bih1, const float* __restrict__ bhh1,
                             const float* __restrict__ Wih2, const float* __restrict__ Whh2,
                             const float* __restrict__ bih2, const float* __restrict__ bhh2,
                             float* W1T, float* W2T, float* b1c, float* b2c){
    int idx = blockIdx.x*blockDim.x + threadIdx.x;
    if (idx < 192*256){
        int k = idx >> 8, g = idx & 255;
        W1T[idx] = (k < 128) ? Wih1[g*128 + k] : Whh1[g*64 + (k-128)];
    }
    int i2 = idx - 192*256;
    if (i2 >= 0 && i2 < 128*256){
        int k = i2 >> 8, g = i2 & 255;
        W2T[i2] = (k < 64) ? Wih2[g*64 + k] : Whh2[g*64 + (k-64)];
    }
    int i3 = idx - (192*256 + 128*256);
    if (i3 >= 0 && i3 < 256) b1c[i3] = bih1[i3] + bhh1[i3];
    int i4 = i3 - 256;
    if (i4 >= 0 && i4 < 256) b2c[i4] = bih2[i4] + bhh2[i4];
}

// ---------- fused LSTM1+LSTM2 one time step ----------
__global__ __launch_bounds__(256) void lstm_step(
        const float* __restrict__ h1, const float* __restrict__ h2,
        const float* __restrict__ W1T, const float* __restrict__ W2T,
        const float* __restrict__ b1c, const float* __restrict__ b2c,
        float* __restrict__ h1s, float* __restrict__ c1s,
        float* __restrict__ h2s, float* __restrict__ c2s, int t){
    __shared__ float xs[RROWS*192];
    __shared__ float gsm[RROWS*256];
    int tid = threadIdx.x;
    int j0 = blockIdx.x * RROWS;

    for (int idx = tid; idx < RROWS*192; idx += 256){
        int r = idx / 192, k = idx - r*192;
        int j = j0 + r;
        float v;
        if (k < 128){
            int b = j / NN_SZ, n = j - b*NN_SZ;
            int rowg = (b*T_WIN + t)*NN_SZ + n;
            v = (k < 64) ? h1[rowg*64 + k] : h2[rowg*64 + (k-64)];
        } else {
            v = h1s[j*64 + (k-128)];
        }
        xs[idx] = v;
    }
    __syncthreads();

    int cg = tid & 63;
    int rg = tid >> 6;
    float acc[4][4];

    {
        float4 bv = *(const float4*)&b1c[cg*4];
        #pragma unroll
        for (int rr = 0; rr < 4; rr++){ acc[rr][0]=bv.x; acc[rr][1]=bv.y; acc[rr][2]=bv.z; acc[rr][3]=bv.w; }
    }
    for (int k = 0; k < 192; k++){
        float4 wv = *(const float4*)&W1T[k*256 + cg*4];
        #pragma unroll
        for (int rr = 0; rr < 4; rr++){
            float a = xs[(rg*4+rr)*192 + k];
            acc[rr][0] += a*wv.x; acc[rr][1] += a*wv.y; acc[rr][2] += a*wv.z; acc[rr][3] += a*wv.w;
        }
    }
    #pragma unroll
    for (int rr = 0; rr < 4; rr++)
        *(float4*)&gsm[(rg*4+rr)*256 + cg*4] = make_float4(acc[rr][0],acc[rr][1],acc[rr][2],acc[rr][3]);
    __syncthreads();

    for (int it = 0; it < RROWS/4; it++){
        int r = (tid >> 6) + it*4;
        int f = tid & 63;
        int j = j0 + r;
        float gi = gsm[r*256 + f];
        float gf = gsm[r*256 + 64 + f];
        float gg = gsm[r*256 + 128 + f];
        float go = gsm[r*256 + 192 + f];
        float cn = sigf(gf)*c1s[j*64+f] + sigf(gi)*tanhf(gg);
        float hn = sigf(go)*tanhf(cn);
        c1s[j*64+f] = cn;
        h1s[j*64+f] = hn;
        xs[r*128 + f]      = hn;
        xs[r*128 + 64 + f] = h2s[j*64+f];
    }
    __syncthreads();

    {
        float4 bv = *(const float4*)&b2c[cg*4];
        #pragma unroll
        for (int rr = 0; rr < 4; rr++){ acc[rr][0]=bv.x; acc[rr][1]=bv.y; acc[rr][2]=bv.z; acc[rr][3]=bv.w; }
    }
    for (int k = 0; k < 128; k++){
        float4 wv = *(const float4*)&W2T[k*256 + cg*4];
        #pragma unroll
        for (int rr = 0; rr < 4; rr++){
            float a = xs[(rg*4+rr)*128 + k];
            acc[rr][0] += a*wv.x; acc[rr][1] += a*wv.y; acc[rr][2] += a*wv.z; acc[rr][3] += a*wv.w;
        }
    }
    #pragma unroll
    for (int rr = 0; rr < 4; rr++)
        *(float4*)&gsm[(rg*4+rr)*256 + cg*4] = make_float4(acc[rr][0],acc[rr][1],acc[rr][2],acc[rr][3]);
    __syncthreads();

    for (int it = 0; it < RROWS/4; it++){
        int r = (tid >> 6) + it*4;
        int f = tid & 63;
        int j = j0 + r;
        float gi = gsm[r*256 + f];
        float gf = gsm[r*256 + 64 + f];
        float gg = gsm[r*256 + 128 + f];
        float go = gsm[r*256 + 192 + f];
        float cn = sigf(gf)*c2s[j*64+f] + sigf(gi)*tanhf(gg);
        float hn = sigf(go)*tanhf(cn);
        c2s[j*64+f] = cn;
        h2s[j*64+f] = hn;
    }
}

// ---------- FC head ----------
__global__ __launch_bounds__(256) void fc_head(
        const float* __restrict__ h1s, const float* __restrict__ h2s,
        const float* __restrict__ inner, const float* __restrict__ x,
        const float* __restrict__ fc1_w, const float* __restrict__ fc1_b,
        const float* __restrict__ fc3_w, const float* __restrict__ fc3_b,
        float* __restrict__ out){
    __shared__ float zsm[4][226];
    int wv = threadIdx.x >> 6;
    int f  = threadIdx.x & 63;
    int j  = blockIdx.x*4 + wv;
    int b = j / NN_SZ, n = j - b*NN_SZ;
    for (int k = f; k < 225; k += 64){
        float v;
        if (k < 64)        v = h1s[j*64 + k];
        else if (k < 128)  v = h2s[j*64 + (k-64)];
        else if (k == 128) v = inner[j];
        else {
            int kk = k - 129;
            int w_ = kk >> 3, ff = kk & 7;
            v = x[((b*T_WIN + w_)*NN_SZ + n)*FIN + ff];
        }
        zsm[wv][k] = v;
    }
    __syncthreads();
    float acc = fc1_b[f];
    for (int k = 0; k < 225; k++) acc += zsm[wv][k]*fc1_w[k*64 + f];
    float p = fmaxf(acc, 0.f) * fc3_w[f];
    #pragma unroll
    for (int off = 32; off > 0; off >>= 1) p += __shfl_down(p, off, 64);
    if (f == 0) out[j] = fmaxf(p + fc3_b[0], 0.f);
}

extern "C" void kernel_launch(void* const* d_in, const int* in_sizes, int n_in,
                              void* d_out, int out_size, void* d_ws, size_t ws_size,
                              hipStream_t stream){
    const int*   adj  = (const int*)d_in[0];
    const int*   row  = adj;
    const int*   col  = adj + EDGES;
    const float* aw   = (const float*)d_in[1];
    const float* x    = (const float*)d_in[2];
    const float* inner= (const float*)d_in[3];
    const float* W1   = (const float*)d_in[4];
    const float* b1   = (const float*)d_in[5];
    const float* W2   = (const float*)d_in[6];
    const float* b2   = (const float*)d_in[7];
    const float* g1   = (const float*)d_in[8];
    const float* be1  = (const float*)d_in[9];
    const float* g2   = (const float*)d_in[10];
    const float* be2  = (const float*)d_in[11];
    const float* Wih1 = (const float*)d_in[12];
    const float* Whh1 = (const float*)d_in[13];
    const float* bih1 = (const float*)d_in[14];
    const float* bhh1 = (const float*)d_in[15];
    const float* Wih2 = (const float*)d_in[16];
    const float* Whh2 = (const float*)d_in[17];
    const float* bih2 = (const float*)d_in[18];
    const float* bhh2 = (const float*)d_in[19];
    const float* fc1w = (const float*)d_in[20];
    const float* fc1b = (const float*)d_in[21];
    const float* fc3w = (const float*)d_in[22];
    const float* fc3b = (const float*)d_in[23];
    float* out = (float*)d_out;

    float* ws = (float*)d_ws;
    const size_t NB = (size_t)N_NODES*64;            // 12,288,000 floats
    float* bufX = ws;                                 // hlin (both layers), then h2
    float* bufY = ws + NB;                            // gcnA, then LSTM states + weightsT
    float* bufZ = ws + 2*NB;                          // h1
    float* dis  = ws + 3*NB;                          // [N]
    float* gsum = dis + N_NODES;                      // 64
    float* gsq  = gsum + 64;                          // 64
    float* scal = gsq + 64;                           // 64
    float* shif = scal + 64;                          // 64
    // CSR arrays
    int* cnt     = (int*)(shif + 64);                 // N
    int* excl    = cnt + N_NODES;                     // N
    int* bsum    = excl + N_NODES;                    // 1024
    int* bscan   = bsum + 1024;                       // 1024
    int* offsets = bscan + 1024;                      // N+1
    int* cursor  = offsets + (N_NODES+1);             // N
    int* rows_s  = cursor + N_NODES;                  // E
    float* norm_s= (float*)(rows_s + EDGES);          // E

    // aliases into bufY after GCN phase:
    float* h1s = bufY;
    float* c1s = bufY + (size_t)BN_ROWS*64;
    float* h2s = bufY + (size_t)2*BN_ROWS*64;
    float* c2s = bufY + (size_t)3*BN_ROWS*64;
    float* W1T = bufY + (size_t)4*BN_ROWS*64;
    float* W2T = W1T + 192*256;
    float* b1c = W2T + 128*256;
    float* b2c = b1c + 256;

    float* hlin = bufX;
    float* gcnA = bufY;
    float* h1   = bufZ;
    float* h2   = bufX;   // written after hlin is dead

    // degrees / symmetric norm
    fill_deg  <<<750, 256, 0, stream>>>(dis);
    deg_accum <<<(EDGES+255)/256, 256, 0, stream>>>(col, aw, dis);
    deg_to_dis<<<750, 256, 0, stream>>>(dis);

    // CSR build (used by both layers)
    hipMemsetAsync(cnt, 0, N_NODES*sizeof(int), stream);
    hist_col <<<(EDGES+255)/256, 256, 0, stream>>>(col, cnt);
    scanA    <<<750, 256, 0, stream>>>(cnt, excl, bsum);
    scanB    <<<1, 1024, 0, stream>>>(bsum, bscan, 750);
    scanC    <<<750, 256, 0, stream>>>(excl, bscan, offsets, cursor);
    build_csr<<<(EDGES+255)/256, 256, 0, stream>>>(row, col, aw, dis, cursor, rows_s, norm_s);

    // ---- GCN layer 1 ----
    lin1<<<48000, 256, 0, stream>>>(x, W1, hlin);
    gather_csr<<<N_NODES/4, 256, 0, stream>>>(offsets, rows_s, norm_s, dis, hlin, b1, gcnA);
    hipMemsetAsync(gsum, 0, 128*sizeof(float), stream);
    stats_only<<<1024, 256, 0, stream>>>(gcnA, gsum, gsq);
    bn_finalize<<<1, 64, 0, stream>>>(gsum, gsq, g1, be1, scal, shif);
    bn_apply<<<48000, 256, 0, stream>>>(gcnA, scal, shif, h1);

    // ---- GCN layer 2 ----
    lin2<<<48000, 256, 0, stream>>>(h1, W2, hlin);
    gather_csr<<<N_NODES/4, 256, 0, stream>>>(offsets, rows_s, norm_s, dis, hlin, b2, gcnA);
    hipMemsetAsync(gsum, 0, 128*sizeof(float), stream);
    stats_only<<<1024, 256, 0, stream>>>(gcnA, gsum, gsq);
    bn_finalize<<<1, 64, 0, stream>>>(gsum, gsq, g2, be2, scal, shif);
    bn_apply<<<48000, 256, 0, stream>>>(gcnA, scal, shif, h2);   // h2 -> bufX

    // ---- LSTMs (states alias bufY: gcnA dead after bn_apply) ----
    prep_weights<<<(192*256 + 128*256 + 512 + 255)/256, 256, 0, stream>>>(
        Wih1, Whh1, bih1, bhh1, Wih2, Whh2, bih2, bhh2, W1T, W2T, b1c, b2c);
    hipMemsetAsync(h1s, 0, (size_t)4*BN_ROWS*64*sizeof(float), stream);
    for (int t = 0; t < T_WIN; t++)
        lstm_step<<<BN_ROWS/RROWS, 256, 0, stream>>>(h1, h2, W1T, W2T, b1c, b2c,
                                                     h1s, c1s, h2s, c2s, t);

    // ---- FC head ----
    fc_head<<<BN_ROWS/4, 256, 0, stream>>>(h1s, h2s, inner, x, fc1w, fc1b, fc3w, fc3b, out);
}

// Round 3
// 1657.965 us; speedup vs baseline: 1.2922x; 1.0358x over previous
//
#include <hip/hip_runtime.h>
#include <math.h>

#define N_NODES 192000
#define EDGES   2000000
#define HID     64
#define BN_ROWS 16000   // B*NN
#define T_WIN   12
#define B_SZ    8
#define NN_SZ   2000
#define FIN     8
#define BN_EPS  1e-5f

__device__ __forceinline__ float sigf(float x){ return 1.0f/(1.0f+expf(-x)); }

// ---------- degree / normalization ----------
__global__ void fill_deg(float* deg){
    int i = blockIdx.x*blockDim.x + threadIdx.x;
    if (i < N_NODES) deg[i] = 1.0f;   // self-loop weight
}

__global__ void deg_accum(const int* __restrict__ col, const float* __restrict__ w, float* deg){
    int e = blockIdx.x*blockDim.x + threadIdx.x;
    if (e < EDGES) atomicAdd(&deg[col[e]], w[e]);
}

__global__ void deg_to_dis(float* deg){
    int i = blockIdx.x*blockDim.x + threadIdx.x;
    if (i < N_NODES) deg[i] = rsqrtf(deg[i]);   // deg >= 1 always
}

// ---------- CSR build ----------
__global__ void hist_col(const int* __restrict__ col, int* __restrict__ cnt){
    int e = blockIdx.x*blockDim.x + threadIdx.x;
    if (e < EDGES) atomicAdd(&cnt[col[e]], 1);
}

__global__ void scanA(const int* __restrict__ cnt, int* __restrict__ excl, int* __restrict__ bsum){
    __shared__ int sm[256];
    int i = blockIdx.x*256 + threadIdx.x;
    int v = cnt[i];
    sm[threadIdx.x] = v;
    __syncthreads();
    #pragma unroll
    for (int off = 1; off < 256; off <<= 1){
        int t = (threadIdx.x >= off) ? sm[threadIdx.x - off] : 0;
        __syncthreads();
        sm[threadIdx.x] += t;
        __syncthreads();
    }
    excl[i] = sm[threadIdx.x] - v;
    if (threadIdx.x == 255) bsum[blockIdx.x] = sm[255];
}

__global__ void scanB(const int* __restrict__ bsum, int* __restrict__ bscan, int nb){
    __shared__ int sm[1024];
    int tid = threadIdx.x;
    int v = (tid < nb) ? bsum[tid] : 0;
    sm[tid] = v;
    __syncthreads();
    #pragma unroll
    for (int off = 1; off < 1024; off <<= 1){
        int t = (tid >= off) ? sm[tid - off] : 0;
        __syncthreads();
        sm[tid] += t;
        __syncthreads();
    }
    bscan[tid] = sm[tid] - v;
}

__global__ void scanC(const int* __restrict__ excl, const int* __restrict__ bscan,
                      int* __restrict__ offsets, int* __restrict__ cursor){
    int i = blockIdx.x*256 + threadIdx.x;
    int off = excl[i] + bscan[i >> 8];
    offsets[i] = off;
    cursor[i]  = off;
    if (i == N_NODES-1) offsets[N_NODES] = EDGES;
}

__global__ void build_csr(const int* __restrict__ row, const int* __restrict__ col,
                          const float* __restrict__ w, const float* __restrict__ dis,
                          int* __restrict__ cursor, int* __restrict__ rows_s,
                          float* __restrict__ norm_s){
    int e = blockIdx.x*blockDim.x + threadIdx.x;
    if (e >= EDGES) return;
    int r = row[e], c = col[e];
    float nr = dis[r]*w[e]*dis[c];
    int p = atomicAdd(&cursor[c], 1);
    rows_s[p] = r;
    norm_s[p] = nr;
}

// ---------- lin1: hlin = x @ W1   (x:[N,8], W1:[8,64]) ----------
__global__ void lin1(const float* __restrict__ x, const float* __restrict__ W1, float* __restrict__ out){
    __shared__ float Ws[8*64];
    for (int idx = threadIdx.x; idx < 512; idx += blockDim.x) Ws[idx] = W1[idx];
    __syncthreads();
    int gid = blockIdx.x*blockDim.x + threadIdx.x;
    if (gid >= N_NODES*64) return;
    int i = gid >> 6, f = gid & 63;
    const float* xr = x + i*FIN;
    float acc = 0.f;
    #pragma unroll
    for (int k = 0; k < FIN; k++) acc += xr[k]*Ws[k*64+f];
    out[gid] = acc;
}

// ---------- lin2_bn: h1 = BN(gcnA); hlin = h1 @ W2 (register-tiled) ----------
// 128 rows/block, 128 threads, per-thread 8x8 tile
#define L2ROWS 128
#define XS2    132   // padded stride (132*4 = 528 B, 16B-aligned)
__global__ __launch_bounds__(128) void lin2_bn(
        const float* __restrict__ gcnA, const float* __restrict__ scal,
        const float* __restrict__ shif, const float* __restrict__ W2,
        float* __restrict__ h1_out, float* __restrict__ hlin){
    __shared__ float Ws[64*64];
    __shared__ float xsT[64*XS2];
    int tid = threadIdx.x;
    int r0 = blockIdx.x * L2ROWS;

    for (int i = tid; i < 1024; i += 128)
        *(float4*)&Ws[i*4] = *(const float4*)&W2[i*4];

    int k4 = tid & 15;          // float4 index along k
    int rb = tid >> 4;          // 0..7
    float4 sc = *(const float4*)&scal[k4*4];
    float4 sh = *(const float4*)&shif[k4*4];
    for (int it = 0; it < 16; it++){
        int r = it*8 + rb;      // 0..127
        float4 v = *(const float4*)&gcnA[(size_t)(r0+r)*64 + k4*4];
        v.x = v.x*sc.x+sh.x; v.y = v.y*sc.y+sh.y; v.z = v.z*sc.z+sh.z; v.w = v.w*sc.w+sh.w;
        *(float4*)&h1_out[(size_t)(r0+r)*64 + k4*4] = v;
        xsT[(k4*4+0)*XS2 + r] = v.x;
        xsT[(k4*4+1)*XS2 + r] = v.y;
        xsT[(k4*4+2)*XS2 + r] = v.z;
        xsT[(k4*4+3)*XS2 + r] = v.w;
    }
    __syncthreads();

    int cg = tid & 7;    // cols cg*8..+7
    int rg = tid >> 3;   // rows rg*8..+7 (0..15)
    float acc[8][8];
    #pragma unroll
    for (int i = 0; i < 8; i++)
        #pragma unroll
        for (int j = 0; j < 8; j++) acc[i][j] = 0.f;

    float4 a0 = *(float4*)&xsT[0*XS2 + rg*8];
    float4 a1 = *(float4*)&xsT[0*XS2 + rg*8 + 4];
    float4 w0 = *(float4*)&Ws[0*64 + cg*8];
    float4 w1 = *(float4*)&Ws[0*64 + cg*8 + 4];
    for (int k = 0; k < 64; k++){
        float4 na0, na1, nw0, nw1;
        if (k < 63){
            na0 = *(float4*)&xsT[(k+1)*XS2 + rg*8];
            na1 = *(float4*)&xsT[(k+1)*XS2 + rg*8 + 4];
            nw0 = *(float4*)&Ws[(k+1)*64 + cg*8];
            nw1 = *(float4*)&Ws[(k+1)*64 + cg*8 + 4];
        }
        float ar[8] = {a0.x,a0.y,a0.z,a0.w,a1.x,a1.y,a1.z,a1.w};
        float wc[8] = {w0.x,w0.y,w0.z,w0.w,w1.x,w1.y,w1.z,w1.w};
        #pragma unroll
        for (int i = 0; i < 8; i++)
            #pragma unroll
            for (int j = 0; j < 8; j++) acc[i][j] += ar[i]*wc[j];
        a0=na0; a1=na1; w0=nw0; w1=nw1;
    }
    #pragma unroll
    for (int i = 0; i < 8; i++){
        size_t r = (size_t)(r0 + rg*8 + i);
        *(float4*)&hlin[r*64 + cg*8]     = make_float4(acc[i][0],acc[i][1],acc[i][2],acc[i][3]);
        *(float4*)&hlin[r*64 + cg*8 + 4] = make_float4(acc[i][4],acc[i][5],acc[i][6],acc[i][7]);
    }
}

// ---------- GCN aggregation: one wave per destination node ----------
__global__ __launch_bounds__(256) void gather_csr(
        const int* __restrict__ offsets, const int* __restrict__ rows_s,
        const float* __restrict__ norm_s, const float* __restrict__ dis,
        const float* __restrict__ hlin, const float* __restrict__ bias,
        float* __restrict__ outA){
    int j = blockIdx.x*4 + (threadIdx.x >> 6);
    int f = threadIdx.x & 63;
    float d = dis[j];
    float acc = hlin[j*64 + f]*d*d;
    int k  = offsets[j];
    int k1 = offsets[j+1];
    for (; k+2 <= k1; k += 2){
        int   r0 = rows_s[k],   r1 = rows_s[k+1];
        float n0 = norm_s[k],   n1 = norm_s[k+1];
        acc += hlin[r0*64 + f]*n0;
        acc += hlin[r1*64 + f]*n1;
    }
    if (k < k1){
        int r0 = rows_s[k];
        acc += hlin[r0*64 + f]*norm_s[k];
    }
    outA[j*64 + f] = fmaxf(acc + bias[f], 0.f);
}

// ---------- BatchNorm stats / finalize / apply ----------
__global__ void stats_only(const float* __restrict__ a,
                           float* __restrict__ gsum, float* __restrict__ gsq){
    float s = 0.f, s2 = 0.f;
    int stride = gridDim.x*blockDim.x;
    for (int idx = blockIdx.x*blockDim.x + threadIdx.x; idx < N_NODES*64; idx += stride){
        float v = a[idx];
        s += v; s2 += v*v;
    }
    __shared__ float s1m[256], s2m[256];
    s1m[threadIdx.x] = s; s2m[threadIdx.x] = s2;
    __syncthreads();
    if (threadIdx.x < 64){
        float t1 = s1m[threadIdx.x]+s1m[threadIdx.x+64]+s1m[threadIdx.x+128]+s1m[threadIdx.x+192];
        float t2 = s2m[threadIdx.x]+s2m[threadIdx.x+64]+s2m[threadIdx.x+128]+s2m[threadIdx.x+192];
        atomicAdd(&gsum[threadIdx.x], t1);
        atomicAdd(&gsq[threadIdx.x], t2);
    }
}

__global__ void bn_finalize(const float* gsum, const float* gsq, const float* g, const float* be,
                            float* scale, float* shift){
    int f = threadIdx.x;
    if (f < 64){
        float mean = gsum[f] * (1.0f/(float)N_NODES);
        float var  = gsq[f]  * (1.0f/(float)N_NODES) - mean*mean;
        var = fmaxf(var, 0.f);
        float sc = g[f]*rsqrtf(var + BN_EPS);
        scale[f] = sc;
        shift[f] = be[f] - mean*sc;
    }
}

__global__ void bn_apply(const float* __restrict__ a, const float* __restrict__ scale,
                         const float* __restrict__ shift, float* __restrict__ out){
    int gid = blockIdx.x*blockDim.x + threadIdx.x;
    if (gid >= N_NODES*64) return;
    int f = gid & 63;
    out[gid] = a[gid]*scale[f] + shift[f];
}

// ---------- LSTM weight prep: transpose to [K,256] input-major ----------
__global__ void prep_weights(const float* __restrict__ Wih1, const float* __restrict__ Whh1,
                             const float* __restrict__ bih1, const float* __restrict__ bhh1,
                             const float* __restrict__ Wih2, const float* __restrict__ Whh2,
                             const float* __restrict__ bih2, const float* __restrict__ bhh2,
                             float* W1T, float* W2T, float* b1c, float* b2c){
    int idx = blockIdx.x*blockDim.x + threadIdx.x;
    if (idx < 192*256){
        int k = idx >> 8, g = idx & 255;
        W1T[idx] = (k < 128) ? Wih1[g*128 + k] : Whh1[g*64 + (k-128)];
    }
    int i2 = idx - 192*256;
    if (i2 >= 0 && i2 < 128*256){
        int k = i2 >> 8, g = i2 & 255;
        W2T[i2] = (k < 64) ? Wih2[g*64 + k] : Whh2[g*64 + (k-64)];
    }
    int i3 = idx - (192*256 + 128*256);
    if (i3 >= 0 && i3 < 256) b1c[i3] = bih1[i3] + bhh1[i3];
    int i4 = i3 - 256;
    if (i4 >= 0 && i4 < 256) b2c[i4] = bih2[i4] + bhh2[i4];
}

// ---------- fused LSTM1+LSTM2 one time step ----------
// 64 rows/block, 256 threads; per thread: 4 rows x (4 cols x 4 gates).
// Cell update fully in registers (no gates LDS round-trip).
#define XSL 68   // padded stride (68*4 = 272 B, 16B-aligned)
__global__ __launch_bounds__(256) void lstm_step(
        const float* __restrict__ h1, const float* __restrict__ h2,
        const float* __restrict__ W1T, const float* __restrict__ W2T,
        const float* __restrict__ b1c, const float* __restrict__ b2c,
        float* __restrict__ h1s, float* __restrict__ c1s,
        float* __restrict__ h2s, float* __restrict__ c2s, int t){
    __shared__ float xsT[192*XSL];
    int tid = threadIdx.x;
    int j0 = blockIdx.x * 64;

    // ---- stage xsT[k][r]: k<64: h1 | k<128: h2 | k<192: h1s (prev hidden) ----
    {
        int k4 = tid & 15;      // float4 along k
        int rb = tid >> 4;      // 0..15
        int ka = k4*4;
        for (int it = 0; it < 4; it++){
            int r = it*16 + rb;
            int j = j0 + r;
            int b = j / NN_SZ, n = j - b*NN_SZ;
            size_t rowg = (size_t)((b*T_WIN + t)*NN_SZ + n);
            float4 va = *(const float4*)&h1[rowg*64 + ka];
            float4 vb = *(const float4*)&h2[rowg*64 + ka];
            float4 vc = *(const float4*)&h1s[(size_t)j*64 + ka];
            xsT[(ka+0)*XSL+r]=va.x; xsT[(ka+1)*XSL+r]=va.y; xsT[(ka+2)*XSL+r]=va.z; xsT[(ka+3)*XSL+r]=va.w;
            xsT[(64+ka+0)*XSL+r]=vb.x; xsT[(64+ka+1)*XSL+r]=vb.y; xsT[(64+ka+2)*XSL+r]=vb.z; xsT[(64+ka+3)*XSL+r]=vb.w;
            xsT[(128+ka+0)*XSL+r]=vc.x; xsT[(128+ka+1)*XSL+r]=vc.y; xsT[(128+ka+2)*XSL+r]=vc.z; xsT[(128+ka+3)*XSL+r]=vc.w;
        }
    }
    __syncthreads();

    int cg = tid & 15;   // hidden units cg*4..+3 (per gate)
    int rg = tid >> 4;   // rows rg*4..+3 (0..15)
    float acc[4][16];    // [row][gate*4 + cc]

    // ---- phase 1: gates1, K=192 ----
    {
        float bc[16];
        *(float4*)&bc[0]  = *(const float4*)&b1c[      cg*4];
        *(float4*)&bc[4]  = *(const float4*)&b1c[ 64 + cg*4];
        *(float4*)&bc[8]  = *(const float4*)&b1c[128 + cg*4];
        *(float4*)&bc[12] = *(const float4*)&b1c[192 + cg*4];
        #pragma unroll
        for (int rr = 0; rr < 4; rr++)
            #pragma unroll
            for (int q = 0; q < 16; q++) acc[rr][q] = bc[q];

        float4 av = *(const float4*)&xsT[0*XSL + rg*4];
        float4 w0 = *(const float4*)&W1T[      cg*4];
        float4 w1 = *(const float4*)&W1T[ 64 + cg*4];
        float4 w2 = *(const float4*)&W1T[128 + cg*4];
        float4 w3 = *(const float4*)&W1T[192 + cg*4];
        for (int k = 0; k < 192; k++){
            float4 nav, nw0, nw1, nw2, nw3;
            if (k < 191){
                nav = *(const float4*)&xsT[(k+1)*XSL + rg*4];
                const float* wp = &W1T[(k+1)*256 + cg*4];
                nw0 = *(const float4*)&wp[0];   nw1 = *(const float4*)&wp[64];
                nw2 = *(const float4*)&wp[128]; nw3 = *(const float4*)&wp[192];
            }
            float ar[4] = {av.x, av.y, av.z, av.w};
            float wc[16] = {w0.x,w0.y,w0.z,w0.w, w1.x,w1.y,w1.z,w1.w,
                            w2.x,w2.y,w2.z,w2.w, w3.x,w3.y,w3.z,w3.w};
            #pragma unroll
            for (int rr = 0; rr < 4; rr++)
                #pragma unroll
                for (int q = 0; q < 16; q++) acc[rr][q] += ar[rr]*wc[q];
            av=nav; w0=nw0; w1=nw1; w2=nw2; w3=nw3;
        }
    }
    __syncthreads();   // phase-1 xsT reads complete before overwrite

    // ---- cell update 1 (in-register) + stage phase-2 inputs ----
    #pragma unroll
    for (int rr = 0; rr < 4; rr++){
        int r = rg*4 + rr;
        size_t j = (size_t)(j0 + r);
        float4 co = *(const float4*)&c1s[j*64 + cg*4];
        float cold[4] = {co.x, co.y, co.z, co.w};
        float cn[4], hn[4];
        #pragma unroll
        for (int cc = 0; cc < 4; cc++){
            float gi = acc[rr][cc], gf = acc[rr][4+cc], gg = acc[rr][8+cc], go = acc[rr][12+cc];
            cn[cc] = sigf(gf)*cold[cc] + sigf(gi)*tanhf(gg);
            hn[cc] = sigf(go)*tanhf(cn[cc]);
        }
        *(float4*)&c1s[j*64 + cg*4] = make_float4(cn[0],cn[1],cn[2],cn[3]);
        *(float4*)&h1s[j*64 + cg*4] = make_float4(hn[0],hn[1],hn[2],hn[3]);
        float4 hp = *(const float4*)&h2s[j*64 + cg*4];
        float hpv[4] = {hp.x, hp.y, hp.z, hp.w};
        #pragma unroll
        for (int cc = 0; cc < 4; cc++){
            xsT[(cg*4+cc)*XSL + r]      = hn[cc];
            xsT[(64+cg*4+cc)*XSL + r]   = hpv[cc];
        }
    }
    __syncthreads();

    // ---- phase 2: gates2, K=128 ----
    {
        float bc[16];
        *(float4*)&bc[0]  = *(const float4*)&b2c[      cg*4];
        *(float4*)&bc[4]  = *(const float4*)&b2c[ 64 + cg*4];
        *(float4*)&bc[8]  = *(const float4*)&b2c[128 + cg*4];
        *(float4*)&bc[12] = *(const float4*)&b2c[192 + cg*4];
        #pragma unroll
        for (int rr = 0; rr < 4; rr++)
            #pragma unroll
            for (int q = 0; q < 16; q++) acc[rr][q] = bc[q];

        float4 av = *(const float4*)&xsT[0*XSL + rg*4];
        float4 w0 = *(const float4*)&W2T[      cg*4];
        float4 w1 = *(const float4*)&W2T[ 64 + cg*4];
        float4 w2 = *(const float4*)&W2T[128 + cg*4];
        float4 w3 = *(const float4*)&W2T[192 + cg*4];
        for (int k = 0; k < 128; k++){
            float4 nav, nw0, nw1, nw2, nw3;
            if (k < 127){
                nav = *(const float4*)&xsT[(k+1)*XSL + rg*4];
                const float* wp = &W2T[(k+1)*256 + cg*4];
                nw0 = *(const float4*)&wp[0];   nw1 = *(const float4*)&wp[64];
                nw2 = *(const float4*)&wp[128]; nw3 = *(const float4*)&wp[192];
            }
            float ar[4] = {av.x, av.y, av.z, av.w};
            float wc[16] = {w0.x,w0.y,w0.z,w0.w, w1.x,w1.y,w1.z,w1.w,
                            w2.x,w2.y,w2.z,w2.w, w3.x,w3.y,w3.z,w3.w};
            #pragma unroll
            for (int rr = 0; rr < 4; rr++)
                #pragma unroll
                for (int q = 0; q < 16; q++) acc[rr][q] += ar[rr]*wc[q];
            av=nav; w0=nw0; w1=nw1; w2=nw2; w3=nw3;
        }
    }

    // ---- cell update 2 ----
    #pragma unroll
    for (int rr = 0; rr < 4; rr++){
        size_t j = (size_t)(j0 + rg*4 + rr);
        float4 co = *(const float4*)&c2s[j*64 + cg*4];
        float cold[4] = {co.x, co.y, co.z, co.w};
        float cn[4], hn[4];
        #pragma unroll
        for (int cc = 0; cc < 4; cc++){
            float gi = acc[rr][cc], gf = acc[rr][4+cc], gg = acc[rr][8+cc], go = acc[rr][12+cc];
            cn[cc] = sigf(gf)*cold[cc] + sigf(gi)*tanhf(gg);
            hn[cc] = sigf(go)*tanhf(cn[cc]);
        }
        *(float4*)&c2s[j*64 + cg*4] = make_float4(cn[0],cn[1],cn[2],cn[3]);
        *(float4*)&h2s[j*64 + cg*4] = make_float4(hn[0],hn[1],hn[2],hn[3]);
    }
}

// ---------- FC head ----------
__global__ __launch_bounds__(256) void fc_head(
        const float* __restrict__ h1s, const float* __restrict__ h2s,
        const float* __restrict__ inner, const float* __restrict__ x,
        const float* __restrict__ fc1_w, const float* __restrict__ fc1_b,
        const float* __restrict__ fc3_w, const float* __restrict__ fc3_b,
        float* __restrict__ out){
    __shared__ float zsm[4][226];
    int wv = threadIdx.x >> 6;
    int f  = threadIdx.x & 63;
    int j  = blockIdx.x*4 + wv;
    int b = j / NN_SZ, n = j - b*NN_SZ;
    for (int k = f; k < 225; k += 64){
        float v;
        if (k < 64)        v = h1s[j*64 + k];
        else if (k < 128)  v = h2s[j*64 + (k-64)];
        else if (k == 128) v = inner[j];
        else {
            int kk = k - 129;
            int w_ = kk >> 3, ff = kk & 7;
            v = x[((b*T_WIN + w_)*NN_SZ + n)*FIN + ff];
        }
        zsm[wv][k] = v;
    }
    __syncthreads();
    float acc = fc1_b[f];
    for (int k = 0; k < 225; k++) acc += zsm[wv][k]*fc1_w[k*64 + f];
    float p = fmaxf(acc, 0.f) * fc3_w[f];
    #pragma unroll
    for (int off = 32; off > 0; off >>= 1) p += __shfl_down(p, off, 64);
    if (f == 0) out[j] = fmaxf(p + fc3_b[0], 0.f);
}

extern "C" void kernel_launch(void* const* d_in, const int* in_sizes, int n_in,
                              void* d_out, int out_size, void* d_ws, size_t ws_size,
                              hipStream_t stream){
    const int*   adj  = (const int*)d_in[0];
    const int*   row  = adj;
    const int*   col  = adj + EDGES;
    const float* aw   = (const float*)d_in[1];
    const float* x    = (const float*)d_in[2];
    const float* inner= (const float*)d_in[3];
    const float* W1   = (const float*)d_in[4];
    const float* b1   = (const float*)d_in[5];
    const float* W2   = (const float*)d_in[6];
    const float* b2   = (const float*)d_in[7];
    const float* g1   = (const float*)d_in[8];
    const float* be1  = (const float*)d_in[9];
    const float* g2   = (const float*)d_in[10];
    const float* be2  = (const float*)d_in[11];
    const float* Wih1 = (const float*)d_in[12];
    const float* Whh1 = (const float*)d_in[13];
    const float* bih1 = (const float*)d_in[14];
    const float* bhh1 = (const float*)d_in[15];
    const float* Wih2 = (const float*)d_in[16];
    const float* Whh2 = (const float*)d_in[17];
    const float* bih2 = (const float*)d_in[18];
    const float* bhh2 = (const float*)d_in[19];
    const float* fc1w = (const float*)d_in[20];
    const float* fc1b = (const float*)d_in[21];
    const float* fc3w = (const float*)d_in[22];
    const float* fc3b = (const float*)d_in[23];
    float* out = (float*)d_out;

    float* ws = (float*)d_ws;
    const size_t NB = (size_t)N_NODES*64;            // 12,288,000 floats
    float* bufX = ws;                                 // hlin (layer2 linear out), then h2
    float* bufY = ws + NB;                            // gcnA, then LSTM states + weightsT
    float* bufZ = ws + 2*NB;                          // h1
    float* dis  = ws + 3*NB;                          // [N]
    float* gsum = dis + N_NODES;                      // 64
    float* gsq  = gsum + 64;                          // 64
    float* scal = gsq + 64;                           // 64
    float* shif = scal + 64;                          // 64
    int* cnt     = (int*)(shif + 64);                 // N
    int* excl    = cnt + N_NODES;                     // N
    int* bsum    = excl + N_NODES;                    // 1024
    int* bscan   = bsum + 1024;                       // 1024
    int* offsets = bscan + 1024;                      // N+1
    int* cursor  = offsets + (N_NODES+1);             // N
    int* rows_s  = cursor + N_NODES;                  // E
    float* norm_s= (float*)(rows_s + EDGES);          // E

    float* h1s = bufY;
    float* c1s = bufY + (size_t)BN_ROWS*64;
    float* h2s = bufY + (size_t)2*BN_ROWS*64;
    float* c2s = bufY + (size_t)3*BN_ROWS*64;
    float* W1T = bufY + (size_t)4*BN_ROWS*64;
    float* W2T = W1T + 192*256;
    float* b1c = W2T + 128*256;
    float* b2c = b1c + 256;

    float* hlin = bufX;
    float* gcnA = bufY;
    float* h1   = bufZ;
    float* h2   = bufX;   // written after hlin is dead

    // degrees / symmetric norm
    fill_deg  <<<750, 256, 0, stream>>>(dis);
    deg_accum <<<(EDGES+255)/256, 256, 0, stream>>>(col, aw, dis);
    deg_to_dis<<<750, 256, 0, stream>>>(dis);

    // CSR build (used by both layers)
    hipMemsetAsync(cnt, 0, N_NODES*sizeof(int), stream);
    hist_col <<<(EDGES+255)/256, 256, 0, stream>>>(col, cnt);
    scanA    <<<750, 256, 0, stream>>>(cnt, excl, bsum);
    scanB    <<<1, 1024, 0, stream>>>(bsum, bscan, 750);
    scanC    <<<750, 256, 0, stream>>>(excl, bscan, offsets, cursor);
    build_csr<<<(EDGES+255)/256, 256, 0, stream>>>(row, col, aw, dis, cursor, rows_s, norm_s);

    // ---- GCN layer 1 ----
    lin1<<<48000, 256, 0, stream>>>(x, W1, hlin);
    gather_csr<<<N_NODES/4, 256, 0, stream>>>(offsets, rows_s, norm_s, dis, hlin, b1, gcnA);
    hipMemsetAsync(gsum, 0, 128*sizeof(float), stream);
    stats_only<<<1024, 256, 0, stream>>>(gcnA, gsum, gsq);
    bn_finalize<<<1, 64, 0, stream>>>(gsum, gsq, g1, be1, scal, shif);

    // ---- fused BN(layer1) + layer-2 linear ----
    lin2_bn<<<N_NODES/L2ROWS, 128, 0, stream>>>(gcnA, scal, shif, W2, h1, hlin);

    // ---- GCN layer 2 ----
    gather_csr<<<N_NODES/4, 256, 0, stream>>>(offsets, rows_s, norm_s, dis, hlin, b2, gcnA);
    hipMemsetAsync(gsum, 0, 128*sizeof(float), stream);
    stats_only<<<1024, 256, 0, stream>>>(gcnA, gsum, gsq);
    bn_finalize<<<1, 64, 0, stream>>>(gsum, gsq, g2, be2, scal, shif);
    bn_apply<<<48000, 256, 0, stream>>>(gcnA, scal, shif, h2);   // h2 -> bufX (hlin dead)

    // ---- LSTMs (states alias bufY: gcnA dead after bn_apply) ----
    prep_weights<<<(192*256 + 128*256 + 512 + 255)/256, 256, 0, stream>>>(
        Wih1, Whh1, bih1, bhh1, Wih2, Whh2, bih2, bhh2, W1T, W2T, b1c, b2c);
    hipMemsetAsync(h1s, 0, (size_t)4*BN_ROWS*64*sizeof(float), stream);
    for (int t = 0; t < T_WIN; t++)
        lstm_step<<<BN_ROWS/64, 256, 0, stream>>>(h1, h2, W1T, W2T, b1c, b2c,
                                                  h1s, c1s, h2s, c2s, t);

    // ---- FC head ----
    fc_head<<<BN_ROWS/4, 256, 0, stream>>>(h1s, h2s, inner, x, fc1w, fc1b, fc3w, fc3b, out);
}

// Round 4
// 1436.605 us; speedup vs baseline: 1.4913x; 1.1541x over previous
//
#include <hip/hip_runtime.h>
#include <math.h>

#define N_NODES 192000
#define EDGES   2000000
#define HID     64
#define BN_ROWS 16000   // B*NN
#define T_WIN   12
#define B_SZ    8
#define NN_SZ   2000
#define FIN     8
#define BN_EPS  1e-5f

typedef _Float16 f16x2 __attribute__((ext_vector_type(2)));
union F16x2U { float f; f16x2 h; };
union F4H    { float4 f4; f16x2 h[4]; };

__device__ __forceinline__ float sigf(float x){ return 1.0f/(1.0f+expf(-x)); }

__device__ __forceinline__ float dot2f(f16x2 a, f16x2 b, float c){
#if __has_builtin(__builtin_amdgcn_fdot2)
    return __builtin_amdgcn_fdot2(a, b, c, false);
#else
    return c + (float)a[0]*(float)b[0] + (float)a[1]*(float)b[1];
#endif
}

__device__ __forceinline__ float packf16(float a, float b){
    F16x2U u; u.h[0] = (_Float16)a; u.h[1] = (_Float16)b; return u.f;
}

// ---------- edge preprocessing: degree + histogram in one pass ----------
__global__ void edge_pre(const int* __restrict__ col, const float* __restrict__ w,
                         float* __restrict__ deg, int* __restrict__ cnt){
    int e = blockIdx.x*blockDim.x + threadIdx.x;
    if (e < EDGES){
        int c = col[e];
        atomicAdd(&deg[c], w[e]);
        atomicAdd(&cnt[c], 1);
    }
}

__global__ void scanA(const int* __restrict__ cnt, int* __restrict__ excl, int* __restrict__ bsum){
    __shared__ int sm[256];
    int i = blockIdx.x*256 + threadIdx.x;
    int v = cnt[i];
    sm[threadIdx.x] = v;
    __syncthreads();
    #pragma unroll
    for (int off = 1; off < 256; off <<= 1){
        int t = (threadIdx.x >= off) ? sm[threadIdx.x - off] : 0;
        __syncthreads();
        sm[threadIdx.x] += t;
        __syncthreads();
    }
    excl[i] = sm[threadIdx.x] - v;
    if (threadIdx.x == 255) bsum[blockIdx.x] = sm[255];
}

__global__ void scanB(const int* __restrict__ bsum, int* __restrict__ bscan, int nb){
    __shared__ int sm[1024];
    int tid = threadIdx.x;
    int v = (tid < nb) ? bsum[tid] : 0;
    sm[tid] = v;
    __syncthreads();
    #pragma unroll
    for (int off = 1; off < 1024; off <<= 1){
        int t = (tid >= off) ? sm[tid - off] : 0;
        __syncthreads();
        sm[tid] += t;
        __syncthreads();
    }
    bscan[tid] = sm[tid] - v;
}

// offsets/cursor + deg -> dis (in place)
__global__ void scanC(const int* __restrict__ excl, const int* __restrict__ bscan,
                      float* __restrict__ degdis,
                      int* __restrict__ offsets, int* __restrict__ cursor){
    int i = blockIdx.x*256 + threadIdx.x;
    int off = excl[i] + bscan[i >> 8];
    offsets[i] = off;
    cursor[i]  = off;
    degdis[i]  = rsqrtf(degdis[i] + 1.0f);   // + self-loop weight
    if (i == N_NODES-1) offsets[N_NODES] = EDGES;
}

__global__ void build_csr(const int* __restrict__ row, const int* __restrict__ col,
                          const float* __restrict__ w, const float* __restrict__ dis,
                          int* __restrict__ cursor, int2* __restrict__ edge_s){
    int e = blockIdx.x*blockDim.x + threadIdx.x;
    if (e >= EDGES) return;
    int r = row[e], c = col[e];
    float nr = dis[r]*w[e]*dis[c];
    int p = atomicAdd(&cursor[c], 1);
    int2 ev; ev.x = r; ev.y = __float_as_int(nr);
    edge_s[p] = ev;
}

// ---------- layer-1 gather with fused x@W1 (x rows are 32 B) ----------
__device__ __forceinline__ float dot8(float4 lo, float4 hi, const float* wc){
    return lo.x*wc[0]+lo.y*wc[1]+lo.z*wc[2]+lo.w*wc[3]
         + hi.x*wc[4]+hi.y*wc[5]+hi.z*wc[6]+hi.w*wc[7];
}

__global__ __launch_bounds__(256) void gather1(
        const int* __restrict__ offsets, const int2* __restrict__ edge_s,
        const float* __restrict__ dis, const float* __restrict__ x,
        const float* __restrict__ W1, const float* __restrict__ bias,
        float* __restrict__ outA){
    __shared__ float W1s[512];
    for (int i = threadIdx.x; i < 512; i += 256) W1s[i] = W1[i];
    __syncthreads();
    int j = blockIdx.x*4 + (threadIdx.x >> 6);
    int f = threadIdx.x & 63;
    float wc[8];
    #pragma unroll
    for (int q = 0; q < 8; q++) wc[q] = W1s[q*64 + f];

    float d = dis[j];
    float4 slo = *(const float4*)&x[(size_t)j*8];
    float4 shi = *(const float4*)&x[(size_t)j*8 + 4];
    float acc = dot8(slo, shi, wc)*d*d;

    int k  = offsets[j];
    int k1 = offsets[j+1];
    for (; k+2 <= k1; k += 2){
        int2 e0 = edge_s[k], e1 = edge_s[k+1];
        float4 a0 = *(const float4*)&x[(size_t)e0.x*8];
        float4 a1 = *(const float4*)&x[(size_t)e0.x*8 + 4];
        float4 b0 = *(const float4*)&x[(size_t)e1.x*8];
        float4 b1 = *(const float4*)&x[(size_t)e1.x*8 + 4];
        acc += dot8(a0, a1, wc)*__int_as_float(e0.y);
        acc += dot8(b0, b1, wc)*__int_as_float(e1.y);
    }
    if (k < k1){
        int2 e0 = edge_s[k];
        float4 a0 = *(const float4*)&x[(size_t)e0.x*8];
        float4 a1 = *(const float4*)&x[(size_t)e0.x*8 + 4];
        acc += dot8(a0, a1, wc)*__int_as_float(e0.y);
    }
    outA[(size_t)j*64 + f] = fmaxf(acc + bias[f], 0.f);
}

// ---------- layer-2 gather (reads hlin rows) ----------
__global__ __launch_bounds__(256) void gather2(
        const int* __restrict__ offsets, const int2* __restrict__ edge_s,
        const float* __restrict__ dis, const float* __restrict__ hlin,
        const float* __restrict__ bias, float* __restrict__ outA){
    int j = blockIdx.x*4 + (threadIdx.x >> 6);
    int f = threadIdx.x & 63;
    float d = dis[j];
    float acc = hlin[(size_t)j*64 + f]*d*d;
    int k  = offsets[j];
    int k1 = offsets[j+1];
    for (; k+2 <= k1; k += 2){
        int2 e0 = edge_s[k], e1 = edge_s[k+1];
        acc += hlin[(size_t)e0.x*64 + f]*__int_as_float(e0.y);
        acc += hlin[(size_t)e1.x*64 + f]*__int_as_float(e1.y);
    }
    if (k < k1){
        int2 e0 = edge_s[k];
        acc += hlin[(size_t)e0.x*64 + f]*__int_as_float(e0.y);
    }
    outA[(size_t)j*64 + f] = fmaxf(acc + bias[f], 0.f);
}

// ---------- lin2_bn: h1 = BN(gcnA); hlin = h1 @ W2 (register-tiled) ----------
#define L2ROWS 128
#define XS2    132
__global__ __launch_bounds__(128) void lin2_bn(
        const float* __restrict__ gcnA, const float* __restrict__ scal,
        const float* __restrict__ shif, const float* __restrict__ W2,
        float* __restrict__ h1_out, float* __restrict__ hlin){
    __shared__ float Ws[64*64];
    __shared__ float xsT[64*XS2];
    int tid = threadIdx.x;
    int r0 = blockIdx.x * L2ROWS;

    for (int i = tid; i < 1024; i += 128)
        *(float4*)&Ws[i*4] = *(const float4*)&W2[i*4];

    int k4 = tid & 15;
    int rb = tid >> 4;
    float4 sc = *(const float4*)&scal[k4*4];
    float4 sh = *(const float4*)&shif[k4*4];
    for (int it = 0; it < 16; it++){
        int r = it*8 + rb;
        float4 v = *(const float4*)&gcnA[(size_t)(r0+r)*64 + k4*4];
        v.x = v.x*sc.x+sh.x; v.y = v.y*sc.y+sh.y; v.z = v.z*sc.z+sh.z; v.w = v.w*sc.w+sh.w;
        *(float4*)&h1_out[(size_t)(r0+r)*64 + k4*4] = v;
        xsT[(k4*4+0)*XS2 + r] = v.x;
        xsT[(k4*4+1)*XS2 + r] = v.y;
        xsT[(k4*4+2)*XS2 + r] = v.z;
        xsT[(k4*4+3)*XS2 + r] = v.w;
    }
    __syncthreads();

    int cg = tid & 7;
    int rg = tid >> 3;
    float acc[8][8];
    #pragma unroll
    for (int i = 0; i < 8; i++)
        #pragma unroll
        for (int j = 0; j < 8; j++) acc[i][j] = 0.f;

    float4 a0 = *(float4*)&xsT[0*XS2 + rg*8];
    float4 a1 = *(float4*)&xsT[0*XS2 + rg*8 + 4];
    float4 w0 = *(float4*)&Ws[0*64 + cg*8];
    float4 w1 = *(float4*)&Ws[0*64 + cg*8 + 4];
    for (int k = 0; k < 64; k++){
        float4 na0, na1, nw0, nw1;
        if (k < 63){
            na0 = *(float4*)&xsT[(k+1)*XS2 + rg*8];
            na1 = *(float4*)&xsT[(k+1)*XS2 + rg*8 + 4];
            nw0 = *(float4*)&Ws[(k+1)*64 + cg*8];
            nw1 = *(float4*)&Ws[(k+1)*64 + cg*8 + 4];
        }
        float ar[8] = {a0.x,a0.y,a0.z,a0.w,a1.x,a1.y,a1.z,a1.w};
        float wcv[8] = {w0.x,w0.y,w0.z,w0.w,w1.x,w1.y,w1.z,w1.w};
        #pragma unroll
        for (int i = 0; i < 8; i++)
            #pragma unroll
            for (int j = 0; j < 8; j++) acc[i][j] += ar[i]*wcv[j];
        a0=na0; a1=na1; w0=nw0; w1=nw1;
    }
    #pragma unroll
    for (int i = 0; i < 8; i++){
        size_t r = (size_t)(r0 + rg*8 + i);
        *(float4*)&hlin[r*64 + cg*8]     = make_float4(acc[i][0],acc[i][1],acc[i][2],acc[i][3]);
        *(float4*)&hlin[r*64 + cg*8 + 4] = make_float4(acc[i][4],acc[i][5],acc[i][6],acc[i][7]);
    }
}

// ---------- BatchNorm stats / finalize ----------
__global__ void stats_only(const float* __restrict__ a,
                           float* __restrict__ gsum, float* __restrict__ gsq){
    float s = 0.f, s2 = 0.f;
    int stride = gridDim.x*blockDim.x;
    for (int idx = blockIdx.x*blockDim.x + threadIdx.x; idx < N_NODES*64; idx += stride){
        float v = a[idx];
        s += v; s2 += v*v;
    }
    __shared__ float s1m[256], s2m[256];
    s1m[threadIdx.x] = s; s2m[threadIdx.x] = s2;
    __syncthreads();
    if (threadIdx.x < 64){
        float t1 = s1m[threadIdx.x]+s1m[threadIdx.x+64]+s1m[threadIdx.x+128]+s1m[threadIdx.x+192];
        float t2 = s2m[threadIdx.x]+s2m[threadIdx.x+64]+s2m[threadIdx.x+128]+s2m[threadIdx.x+192];
        atomicAdd(&gsum[threadIdx.x], t1);
        atomicAdd(&gsq[threadIdx.x], t2);
    }
}

__global__ void bn_finalize(const float* gsum, const float* gsq, const float* g, const float* be,
                            float* scale, float* shift){
    int f = threadIdx.x;
    if (f < 64){
        float mean = gsum[f] * (1.0f/(float)N_NODES);
        float var  = gsq[f]  * (1.0f/(float)N_NODES) - mean*mean;
        var = fmaxf(var, 0.f);
        float sc = g[f]*rsqrtf(var + BN_EPS);
        scale[f] = sc;
        shift[f] = be[f] - mean*sc;
    }
}

// ---------- LSTM weight prep: f16x2 pairs along K, [K/2][256] ----------
__global__ void prep_weights(const float* __restrict__ Wih1, const float* __restrict__ Whh1,
                             const float* __restrict__ bih1, const float* __restrict__ bhh1,
                             const float* __restrict__ Wih2, const float* __restrict__ Whh2,
                             const float* __restrict__ bih2, const float* __restrict__ bhh2,
                             float* W1P, float* W2P, float* b1c, float* b2c){
    int idx = blockIdx.x*blockDim.x + threadIdx.x;
    if (idx < 96*256){
        int k2 = idx >> 8, g = idx & 255;
        int k = 2*k2;
        float a = (k   < 128) ? Wih1[g*128 + k]   : Whh1[g*64 + (k-128)];
        float b = (k+1 < 128) ? Wih1[g*128 + k+1] : Whh1[g*64 + (k+1-128)];
        W1P[idx] = packf16(a, b);
    }
    int i2 = idx - 96*256;
    if (i2 >= 0 && i2 < 64*256){
        int k2 = i2 >> 8, g = i2 & 255;
        int k = 2*k2;
        float a = (k   < 64) ? Wih2[g*64 + k]   : Whh2[g*64 + (k-64)];
        float b = (k+1 < 64) ? Wih2[g*64 + k+1] : Whh2[g*64 + (k+1-64)];
        W2P[i2] = packf16(a, b);
    }
    int i3 = idx - (96*256 + 64*256);
    if (i3 >= 0 && i3 < 256) b1c[i3] = bih1[i3] + bhh1[i3];
    int i4 = i3 - 256;
    if (i4 >= 0 && i4 < 256) b2c[i4] = bih2[i4] + bhh2[i4];
}

// ---------- fused LSTM1+LSTM2 one time step (f16 dot2, fp32 accum) ----------
// 32 rows/block (500 blocks), 256 threads; thread: 2 rows x 16 gate-cols.
// BN of layer-2 GCN output fused into staging.
#define XSP 36   // stride in f16x2 units (36*4 B = 144 B, 16B-aligned)
__global__ __launch_bounds__(256) void lstm_step(
        const float* __restrict__ h1, const float* __restrict__ g2raw,
        const float* __restrict__ scal2, const float* __restrict__ shif2,
        const float* __restrict__ W1P, const float* __restrict__ W2P,
        const float* __restrict__ b1c, const float* __restrict__ b2c,
        float* __restrict__ h1s, float* __restrict__ c1s,
        float* __restrict__ h2s, float* __restrict__ c2s, int t){
    __shared__ float xsP[96*XSP];
    int tid = threadIdx.x;
    int j0 = blockIdx.x * 32;

    // stage pairs along k: seg0 k2[0,32): h1 | seg1 [32,64): BN2(g2raw) | seg2 [64,96): h1s
    {
        int k4 = tid & 15;      // float4 group along k
        int rb = tid >> 4;      // 0..15
        int ka = k4*4;
        float4 sc2 = *(const float4*)&scal2[ka];
        float4 sh2 = *(const float4*)&shif2[ka];
        for (int it = 0; it < 2; it++){
            int r = it*16 + rb;
            int j = j0 + r;
            int b = j / NN_SZ, n = j - b*NN_SZ;
            size_t rowg = (size_t)((b*T_WIN + t)*NN_SZ + n);
            float4 va = *(const float4*)&h1[rowg*64 + ka];
            float4 vr = *(const float4*)&g2raw[rowg*64 + ka];
            float4 vb;
            vb.x = vr.x*sc2.x+sh2.x; vb.y = vr.y*sc2.y+sh2.y;
            vb.z = vr.z*sc2.z+sh2.z; vb.w = vr.w*sc2.w+sh2.w;
            float4 vc = *(const float4*)&h1s[(size_t)j*64 + ka];
            int p = ka >> 1;
            xsP[(p  )*XSP + r]    = packf16(va.x, va.y);
            xsP[(p+1)*XSP + r]    = packf16(va.z, va.w);
            xsP[(32+p  )*XSP + r] = packf16(vb.x, vb.y);
            xsP[(32+p+1)*XSP + r] = packf16(vb.z, vb.w);
            xsP[(64+p  )*XSP + r] = packf16(vc.x, vc.y);
            xsP[(64+p+1)*XSP + r] = packf16(vc.z, vc.w);
        }
    }
    __syncthreads();

    int cg = tid & 15;   // hidden units cg*4..+3 per gate
    int rg = tid >> 4;   // rows rg*2, rg*2+1
    float acc[2][16];

    // ---- phase 1: gates1, 96 k-pairs ----
    {
        float bc[16];
        *(float4*)&bc[0]  = *(const float4*)&b1c[      cg*4];
        *(float4*)&bc[4]  = *(const float4*)&b1c[ 64 + cg*4];
        *(float4*)&bc[8]  = *(const float4*)&b1c[128 + cg*4];
        *(float4*)&bc[12] = *(const float4*)&b1c[192 + cg*4];
        #pragma unroll
        for (int rr = 0; rr < 2; rr++)
            #pragma unroll
            for (int q = 0; q < 16; q++) acc[rr][q] = bc[q];

        float2 av = *(const float2*)&xsP[0*XSP + rg*2];
        float4 w0 = *(const float4*)&W1P[      cg*4];
        float4 w1 = *(const float4*)&W1P[ 64 + cg*4];
        float4 w2 = *(const float4*)&W1P[128 + cg*4];
        float4 w3 = *(const float4*)&W1P[192 + cg*4];
        for (int k2 = 0; k2 < 96; k2++){
            float2 nav; float4 nw0, nw1, nw2, nw3;
            if (k2 < 95){
                nav = *(const float2*)&xsP[(k2+1)*XSP + rg*2];
                const float* wp = &W1P[(k2+1)*256 + cg*4];
                nw0 = *(const float4*)&wp[0];   nw1 = *(const float4*)&wp[64];
                nw2 = *(const float4*)&wp[128]; nw3 = *(const float4*)&wp[192];
            }
            F16x2U a0, a1; a0.f = av.x; a1.f = av.y;
            F4H W0, W1v, W2v, W3v; W0.f4=w0; W1v.f4=w1; W2v.f4=w2; W3v.f4=w3;
            #pragma unroll
            for (int cc = 0; cc < 4; cc++){
                acc[0][cc]    = dot2f(a0.h, W0.h[cc],  acc[0][cc]);
                acc[0][4+cc]  = dot2f(a0.h, W1v.h[cc], acc[0][4+cc]);
                acc[0][8+cc]  = dot2f(a0.h, W2v.h[cc], acc[0][8+cc]);
                acc[0][12+cc] = dot2f(a0.h, W3v.h[cc], acc[0][12+cc]);
                acc[1][cc]    = dot2f(a1.h, W0.h[cc],  acc[1][cc]);
                acc[1][4+cc]  = dot2f(a1.h, W1v.h[cc], acc[1][4+cc]);
                acc[1][8+cc]  = dot2f(a1.h, W2v.h[cc], acc[1][8+cc]);
                acc[1][12+cc] = dot2f(a1.h, W3v.h[cc], acc[1][12+cc]);
            }
            av=nav; w0=nw0; w1=nw1; w2=nw2; w3=nw3;
        }
    }
    __syncthreads();   // phase-1 LDS reads complete before overwrite

    // ---- cell update 1 (in-register) + stage phase-2 inputs ----
    #pragma unroll
    for (int rr = 0; rr < 2; rr++){
        int r = rg*2 + rr;
        size_t j = (size_t)(j0 + r);
        float4 co = *(const float4*)&c1s[j*64 + cg*4];
        float cold[4] = {co.x, co.y, co.z, co.w};
        float cn[4], hn[4];
        #pragma unroll
        for (int cc = 0; cc < 4; cc++){
            float gi = acc[rr][cc], gf = acc[rr][4+cc], gg = acc[rr][8+cc], go = acc[rr][12+cc];
            cn[cc] = sigf(gf)*cold[cc] + sigf(gi)*tanhf(gg);
            hn[cc] = sigf(go)*tanhf(cn[cc]);
        }
        *(float4*)&c1s[j*64 + cg*4] = make_float4(cn[0],cn[1],cn[2],cn[3]);
        *(float4*)&h1s[j*64 + cg*4] = make_float4(hn[0],hn[1],hn[2],hn[3]);
        float4 hp = *(const float4*)&h2s[j*64 + cg*4];
        xsP[(cg*2  )*XSP + r]    = packf16(hn[0], hn[1]);
        xsP[(cg*2+1)*XSP + r]    = packf16(hn[2], hn[3]);
        xsP[(32+cg*2  )*XSP + r] = packf16(hp.x, hp.y);
        xsP[(32+cg*2+1)*XSP + r] = packf16(hp.z, hp.w);
    }
    __syncthreads();

    // ---- phase 2: gates2, 64 k-pairs ----
    {
        float bc[16];
        *(float4*)&bc[0]  = *(const float4*)&b2c[      cg*4];
        *(float4*)&bc[4]  = *(const float4*)&b2c[ 64 + cg*4];
        *(float4*)&bc[8]  = *(const float4*)&b2c[128 + cg*4];
        *(float4*)&bc[12] = *(const float4*)&b2c[192 + cg*4];
        #pragma unroll
        for (int rr = 0; rr < 2; rr++)
            #pragma unroll
            for (int q = 0; q < 16; q++) acc[rr][q] = bc[q];

        float2 av = *(const float2*)&xsP[0*XSP + rg*2];
        float4 w0 = *(const float4*)&W2P[      cg*4];
        float4 w1 = *(const float4*)&W2P[ 64 + cg*4];
        float4 w2 = *(const float4*)&W2P[128 + cg*4];
        float4 w3 = *(const float4*)&W2P[192 + cg*4];
        for (int k2 = 0; k2 < 64; k2++){
            float2 nav; float4 nw0, nw1, nw2, nw3;
            if (k2 < 63){
                nav = *(const float2*)&xsP[(k2+1)*XSP + rg*2];
                const float* wp = &W2P[(k2+1)*256 + cg*4];
                nw0 = *(const float4*)&wp[0];   nw1 = *(const float4*)&wp[64];
                nw2 = *(const float4*)&wp[128]; nw3 = *(const float4*)&wp[192];
            }
            F16x2U a0, a1; a0.f = av.x; a1.f = av.y;
            F4H W0, W1v, W2v, W3v; W0.f4=w0; W1v.f4=w1; W2v.f4=w2; W3v.f4=w3;
            #pragma unroll
            for (int cc = 0; cc < 4; cc++){
                acc[0][cc]    = dot2f(a0.h, W0.h[cc],  acc[0][cc]);
                acc[0][4+cc]  = dot2f(a0.h, W1v.h[cc], acc[0][4+cc]);
                acc[0][8+cc]  = dot2f(a0.h, W2v.h[cc], acc[0][8+cc]);
                acc[0][12+cc] = dot2f(a0.h, W3v.h[cc], acc[0][12+cc]);
                acc[1][cc]    = dot2f(a1.h, W0.h[cc],  acc[1][cc]);
                acc[1][4+cc]  = dot2f(a1.h, W1v.h[cc], acc[1][4+cc]);
                acc[1][8+cc]  = dot2f(a1.h, W2v.h[cc], acc[1][8+cc]);
                acc[1][12+cc] = dot2f(a1.h, W3v.h[cc], acc[1][12+cc]);
            }
            av=nav; w0=nw0; w1=nw1; w2=nw2; w3=nw3;
        }
    }

    // ---- cell update 2 ----
    #pragma unroll
    for (int rr = 0; rr < 2; rr++){
        size_t j = (size_t)(j0 + rg*2 + rr);
        float4 co = *(const float4*)&c2s[j*64 + cg*4];
        float cold[4] = {co.x, co.y, co.z, co.w};
        float cn[4], hn[4];
        #pragma unroll
        for (int cc = 0; cc < 4; cc++){
            float gi = acc[rr][cc], gf = acc[rr][4+cc], gg = acc[rr][8+cc], go = acc[rr][12+cc];
            cn[cc] = sigf(gf)*cold[cc] + sigf(gi)*tanhf(gg);
            hn[cc] = sigf(go)*tanhf(cn[cc]);
        }
        *(float4*)&c2s[j*64 + cg*4] = make_float4(cn[0],cn[1],cn[2],cn[3]);
        *(float4*)&h2s[j*64 + cg*4] = make_float4(hn[0],hn[1],hn[2],hn[3]);
    }
}

// ---------- FC head ----------
__global__ __launch_bounds__(256) void fc_head(
        const float* __restrict__ h1s, const float* __restrict__ h2s,
        const float* __restrict__ inner, const float* __restrict__ x,
        const float* __restrict__ fc1_w, const float* __restrict__ fc1_b,
        const float* __restrict__ fc3_w, const float* __restrict__ fc3_b,
        float* __restrict__ out){
    __shared__ float zsm[4][226];
    int wv = threadIdx.x >> 6;
    int f  = threadIdx.x & 63;
    int j  = blockIdx.x*4 + wv;
    int b = j / NN_SZ, n = j - b*NN_SZ;
    for (int k = f; k < 225; k += 64){
        float v;
        if (k < 64)        v = h1s[j*64 + k];
        else if (k < 128)  v = h2s[j*64 + (k-64)];
        else if (k == 128) v = inner[j];
        else {
            int kk = k - 129;
            int w_ = kk >> 3, ff = kk & 7;
            v = x[((b*T_WIN + w_)*NN_SZ + n)*FIN + ff];
        }
        zsm[wv][k] = v;
    }
    __syncthreads();
    float acc = fc1_b[f];
    for (int k = 0; k < 225; k++) acc += zsm[wv][k]*fc1_w[k*64 + f];
    float p = fmaxf(acc, 0.f) * fc3_w[f];
    #pragma unroll
    for (int off = 32; off > 0; off >>= 1) p += __shfl_down(p, off, 64);
    if (f == 0) out[j] = fmaxf(p + fc3_b[0], 0.f);
}

extern "C" void kernel_launch(void* const* d_in, const int* in_sizes, int n_in,
                              void* d_out, int out_size, void* d_ws, size_t ws_size,
                              hipStream_t stream){
    const int*   adj  = (const int*)d_in[0];
    const int*   row  = adj;
    const int*   col  = adj + EDGES;
    const float* aw   = (const float*)d_in[1];
    const float* x    = (const float*)d_in[2];
    const float* inner= (const float*)d_in[3];
    const float* W1   = (const float*)d_in[4];
    const float* b1   = (const float*)d_in[5];
    const float* W2   = (const float*)d_in[6];
    const float* b2   = (const float*)d_in[7];
    const float* g1   = (const float*)d_in[8];
    const float* be1  = (const float*)d_in[9];
    const float* g2   = (const float*)d_in[10];
    const float* be2  = (const float*)d_in[11];
    const float* Wih1 = (const float*)d_in[12];
    const float* Whh1 = (const float*)d_in[13];
    const float* bih1 = (const float*)d_in[14];
    const float* bhh1 = (const float*)d_in[15];
    const float* Wih2 = (const float*)d_in[16];
    const float* Whh2 = (const float*)d_in[17];
    const float* bih2 = (const float*)d_in[18];
    const float* bhh2 = (const float*)d_in[19];
    const float* fc1w = (const float*)d_in[20];
    const float* fc1b = (const float*)d_in[21];
    const float* fc3w = (const float*)d_in[22];
    const float* fc3b = (const float*)d_in[23];
    float* out = (float*)d_out;

    float* ws = (float*)d_ws;
    const size_t NB = (size_t)N_NODES*64;            // 12,288,000 floats
    float* bufX = ws;                                 // hlin2 -> LSTM states + packed W
    float* bufY = ws + NB;                            // gcnA1 -> gcnA2 (live through LSTM)
    float* bufZ = ws + 2*NB;                          // h1 = BN1 out (live through LSTM)
    // tail (8B-aligned: 3*NB even)
    int2*  edge_s  = (int2*)(ws + 3*NB);              // E int2
    float* degdis  = ws + 3*NB + (size_t)2*EDGES;     // N (deg, then dis in place)
    float* gsum    = degdis + N_NODES;                // 64
    float* gsq     = gsum + 64;
    float* scal    = gsq + 64;
    float* shif    = scal + 64;
    float* scal2   = shif + 64;
    float* shif2   = scal2 + 64;
    int* cnt     = (int*)(shif2 + 64);                // N
    int* excl    = cnt + N_NODES;                     // N
    int* bsum    = excl + N_NODES;                    // 1024
    int* bscan   = bsum + 1024;                       // 1024
    int* offsets = bscan + 1024;                      // N+2
    int* cursor  = offsets + (N_NODES+2);             // N

    // LSTM-phase aliases into bufX (hlin2 dead after gather2)
    float* h1s = bufX;
    float* c1s = bufX + (size_t)BN_ROWS*64;
    float* h2s = bufX + (size_t)2*BN_ROWS*64;
    float* c2s = bufX + (size_t)3*BN_ROWS*64;
    float* W1P = bufX + (size_t)4*BN_ROWS*64;         // 96*256
    float* W2P = W1P + 96*256;                        // 64*256
    float* b1c = W2P + 64*256;
    float* b2c = b1c + 256;

    float* gcnA1 = bufY;
    float* h1    = bufZ;
    float* hlin2 = bufX;
    float* gcnA2 = bufY;

    // ---- edge preprocessing ----
    hipMemsetAsync(degdis, 0, N_NODES*sizeof(float), stream);
    hipMemsetAsync(cnt,    0, N_NODES*sizeof(int),   stream);
    edge_pre <<<(EDGES+255)/256, 256, 0, stream>>>(col, aw, degdis, cnt);
    scanA    <<<750, 256, 0, stream>>>(cnt, excl, bsum);
    scanB    <<<1, 1024, 0, stream>>>(bsum, bscan, 750);
    scanC    <<<750, 256, 0, stream>>>(excl, bscan, degdis, offsets, cursor);
    build_csr<<<(EDGES+255)/256, 256, 0, stream>>>(row, col, aw, degdis, cursor, edge_s);

    // ---- GCN layer 1 (x@W1 fused into gather) ----
    gather1<<<N_NODES/4, 256, 0, stream>>>(offsets, edge_s, degdis, x, W1, b1, gcnA1);
    hipMemsetAsync(gsum, 0, 128*sizeof(float), stream);
    stats_only<<<1024, 256, 0, stream>>>(gcnA1, gsum, gsq);
    bn_finalize<<<1, 64, 0, stream>>>(gsum, gsq, g1, be1, scal, shif);

    // ---- fused BN1 + layer-2 linear ----
    lin2_bn<<<N_NODES/L2ROWS, 128, 0, stream>>>(gcnA1, scal, shif, W2, h1, hlin2);

    // ---- GCN layer 2 ----
    gather2<<<N_NODES/4, 256, 0, stream>>>(offsets, edge_s, degdis, hlin2, b2, gcnA2);
    hipMemsetAsync(gsum, 0, 128*sizeof(float), stream);
    stats_only<<<1024, 256, 0, stream>>>(gcnA2, gsum, gsq);
    bn_finalize<<<1, 64, 0, stream>>>(gsum, gsq, g2, be2, scal2, shif2);   // BN2 applied in lstm staging

    // ---- LSTMs (states/weights alias bufX: hlin2 dead after gather2) ----
    prep_weights<<<(96*256 + 64*256 + 512 + 255)/256, 256, 0, stream>>>(
        Wih1, Whh1, bih1, bhh1, Wih2, Whh2, bih2, bhh2, W1P, W2P, b1c, b2c);
    hipMemsetAsync(h1s, 0, (size_t)4*BN_ROWS*64*sizeof(float), stream);
    for (int t = 0; t < T_WIN; t++)
        lstm_step<<<BN_ROWS/32, 256, 0, stream>>>(h1, gcnA2, scal2, shif2,
                                                  W1P, W2P, b1c, b2c,
                                                  h1s, c1s, h2s, c2s, t);

    // ---- FC head ----
    fc_head<<<BN_ROWS/4, 256, 0, stream>>>(h1s, h2s, inner, x, fc1w, fc1b, fc3w, fc3b, out);
}

// Round 5
// 1239.609 us; speedup vs baseline: 1.7283x; 1.1589x over previous
//
#include <hip/hip_runtime.h>
#include <math.h>

#define N_NODES 192000
#define EDGES   2000000
#define HID     64
#define BN_ROWS 16000   // B*NN
#define T_WIN   12
#define B_SZ    8
#define NN_SZ   2000
#define FIN     8
#define BN_EPS  1e-5f

typedef _Float16 f16x2 __attribute__((ext_vector_type(2)));
union F16x2U { float f; f16x2 h; };
union F4H    { float4 f4; f16x2 h[4]; };

__device__ __forceinline__ float sigf(float x){ return 1.0f/(1.0f+expf(-x)); }

__device__ __forceinline__ float dot2f(f16x2 a, f16x2 b, float c){
#if __has_builtin(__builtin_amdgcn_fdot2)
    return __builtin_amdgcn_fdot2(a, b, c, false);
#else
    return c + (float)a[0]*(float)b[0] + (float)a[1]*(float)b[1];
#endif
}

__device__ __forceinline__ float packf16(float a, float b){
    F16x2U u; u.h[0] = (_Float16)a; u.h[1] = (_Float16)b; return u.f;
}

// ---------- edge preprocessing: degree + histogram in one pass ----------
__global__ void edge_pre(const int* __restrict__ col, const float* __restrict__ w,
                         float* __restrict__ deg, int* __restrict__ cnt){
    int e = blockIdx.x*blockDim.x + threadIdx.x;
    if (e < EDGES){
        int c = col[e];
        atomicAdd(&deg[c], w[e]);
        atomicAdd(&cnt[c], 1);
    }
}

__global__ void scanA(const int* __restrict__ cnt, int* __restrict__ excl, int* __restrict__ bsum){
    __shared__ int sm[256];
    int i = blockIdx.x*256 + threadIdx.x;
    int v = cnt[i];
    sm[threadIdx.x] = v;
    __syncthreads();
    #pragma unroll
    for (int off = 1; off < 256; off <<= 1){
        int t = (threadIdx.x >= off) ? sm[threadIdx.x - off] : 0;
        __syncthreads();
        sm[threadIdx.x] += t;
        __syncthreads();
    }
    excl[i] = sm[threadIdx.x] - v;
    if (threadIdx.x == 255) bsum[blockIdx.x] = sm[255];
}

__global__ void scanB(const int* __restrict__ bsum, int* __restrict__ bscan, int nb){
    __shared__ int sm[1024];
    int tid = threadIdx.x;
    int v = (tid < nb) ? bsum[tid] : 0;
    sm[tid] = v;
    __syncthreads();
    #pragma unroll
    for (int off = 1; off < 1024; off <<= 1){
        int t = (tid >= off) ? sm[tid - off] : 0;
        __syncthreads();
        sm[tid] += t;
        __syncthreads();
    }
    bscan[tid] = sm[tid] - v;
}

__global__ void scanC(const int* __restrict__ excl, const int* __restrict__ bscan,
                      float* __restrict__ degdis,
                      int* __restrict__ offsets, int* __restrict__ cursor){
    int i = blockIdx.x*256 + threadIdx.x;
    int off = excl[i] + bscan[i >> 8];
    offsets[i] = off;
    cursor[i]  = off;
    degdis[i]  = rsqrtf(degdis[i] + 1.0f);   // + self-loop weight
    if (i == N_NODES-1) offsets[N_NODES] = EDGES;
}

__global__ void build_csr(const int* __restrict__ row, const int* __restrict__ col,
                          const float* __restrict__ w, const float* __restrict__ dis,
                          int* __restrict__ cursor, int2* __restrict__ edge_s){
    int e = blockIdx.x*blockDim.x + threadIdx.x;
    if (e >= EDGES) return;
    int r = row[e], c = col[e];
    float nr = dis[r]*w[e]*dis[c];
    int p = atomicAdd(&cursor[c], 1);
    int2 ev; ev.x = r; ev.y = __float_as_int(nr);
    edge_s[p] = ev;
}

// ---------- layer-1 aggregation in 8-wide input space: aggx = A_hat @ x ----------
// 8 lanes per node, 32 nodes per 256-block.
__global__ __launch_bounds__(256) void aggx_k(
        const int* __restrict__ offsets, const int2* __restrict__ edge_s,
        const float* __restrict__ dis, const float* __restrict__ x,
        float* __restrict__ ax){
    int g   = blockIdx.x*32 + (threadIdx.x >> 3);
    int sub = threadIdx.x & 7;
    float d = dis[g];
    float acc = x[(size_t)g*8 + sub]*d*d;
    int k  = offsets[g];
    int k1 = offsets[g+1];
    for (; k+4 <= k1; k += 4){
        int2 e0 = edge_s[k], e1 = edge_s[k+1], e2 = edge_s[k+2], e3 = edge_s[k+3];
        float v0 = x[(size_t)e0.x*8 + sub];
        float v1 = x[(size_t)e1.x*8 + sub];
        float v2 = x[(size_t)e2.x*8 + sub];
        float v3 = x[(size_t)e3.x*8 + sub];
        acc += v0*__int_as_float(e0.y);
        acc += v1*__int_as_float(e1.y);
        acc += v2*__int_as_float(e2.y);
        acc += v3*__int_as_float(e3.y);
    }
    for (; k < k1; k++){
        int2 e0 = edge_s[k];
        acc += x[(size_t)e0.x*8 + sub]*__int_as_float(e0.y);
    }
    ax[(size_t)g*8 + sub] = acc;
}

// ---------- gcnA1 = relu(aggx @ W1 + b1), fused BN1 stats ----------
__global__ __launch_bounds__(256) void lin1b_stats(
        const float* __restrict__ ax, const float* __restrict__ W1,
        const float* __restrict__ b1, float* __restrict__ out,
        float* __restrict__ gsum, float* __restrict__ gsq){
    __shared__ float Ws[512];
    for (int i = threadIdx.x; i < 512; i += 256) Ws[i] = W1[i];
    __syncthreads();
    int f = threadIdx.x & 63;
    float wc[8];
    #pragma unroll
    for (int q = 0; q < 8; q++) wc[q] = Ws[q*64 + f];
    float bb = b1[f];
    float s = 0.f, s2 = 0.f;
    int stride = gridDim.x*blockDim.x;   // multiple of 64
    for (int idx = blockIdx.x*blockDim.x + threadIdx.x; idx < N_NODES*64; idx += stride){
        int j = idx >> 6;
        const float* ar = ax + (size_t)j*8;
        float acc = bb;
        #pragma unroll
        for (int q = 0; q < 8; q++) acc += ar[q]*wc[q];
        float v = fmaxf(acc, 0.f);
        out[idx] = v;
        s += v; s2 += v*v;
    }
    __shared__ float s1m[256], s2m[256];
    s1m[threadIdx.x] = s; s2m[threadIdx.x] = s2;
    __syncthreads();
    if (threadIdx.x < 64){
        float t1 = s1m[threadIdx.x]+s1m[threadIdx.x+64]+s1m[threadIdx.x+128]+s1m[threadIdx.x+192];
        float t2 = s2m[threadIdx.x]+s2m[threadIdx.x+64]+s2m[threadIdx.x+128]+s2m[threadIdx.x+192];
        atomicAdd(&gsum[threadIdx.x], t1);
        atomicAdd(&gsq[threadIdx.x], t2);
    }
}

// ---------- lin2_bn: h1 = BN(gcnA1); hlinH = pack_f16(h1 @ W2) ----------
#define L2ROWS 128
#define XS2    132
__global__ __launch_bounds__(128) void lin2_bn(
        const float* __restrict__ gcnA, const float* __restrict__ scal,
        const float* __restrict__ shif, const float* __restrict__ W2,
        float* __restrict__ h1_out, float* __restrict__ hlinH){
    __shared__ float Ws[64*64];
    __shared__ float xsT[64*XS2];
    int tid = threadIdx.x;
    int r0 = blockIdx.x * L2ROWS;

    for (int i = tid; i < 1024; i += 128)
        *(float4*)&Ws[i*4] = *(const float4*)&W2[i*4];

    int k4 = tid & 15;
    int rb = tid >> 4;
    float4 sc = *(const float4*)&scal[k4*4];
    float4 sh = *(const float4*)&shif[k4*4];
    for (int it = 0; it < 16; it++){
        int r = it*8 + rb;
        float4 v = *(const float4*)&gcnA[(size_t)(r0+r)*64 + k4*4];
        v.x = v.x*sc.x+sh.x; v.y = v.y*sc.y+sh.y; v.z = v.z*sc.z+sh.z; v.w = v.w*sc.w+sh.w;
        *(float4*)&h1_out[(size_t)(r0+r)*64 + k4*4] = v;
        xsT[(k4*4+0)*XS2 + r] = v.x;
        xsT[(k4*4+1)*XS2 + r] = v.y;
        xsT[(k4*4+2)*XS2 + r] = v.z;
        xsT[(k4*4+3)*XS2 + r] = v.w;
    }
    __syncthreads();

    int cg = tid & 7;
    int rg = tid >> 3;
    float acc[8][8];
    #pragma unroll
    for (int i = 0; i < 8; i++)
        #pragma unroll
        for (int j = 0; j < 8; j++) acc[i][j] = 0.f;

    float4 a0 = *(float4*)&xsT[0*XS2 + rg*8];
    float4 a1 = *(float4*)&xsT[0*XS2 + rg*8 + 4];
    float4 w0 = *(float4*)&Ws[0*64 + cg*8];
    float4 w1 = *(float4*)&Ws[0*64 + cg*8 + 4];
    for (int k = 0; k < 64; k++){
        float4 na0, na1, nw0, nw1;
        if (k < 63){
            na0 = *(float4*)&xsT[(k+1)*XS2 + rg*8];
            na1 = *(float4*)&xsT[(k+1)*XS2 + rg*8 + 4];
            nw0 = *(float4*)&Ws[(k+1)*64 + cg*8];
            nw1 = *(float4*)&Ws[(k+1)*64 + cg*8 + 4];
        }
        float ar[8] = {a0.x,a0.y,a0.z,a0.w,a1.x,a1.y,a1.z,a1.w};
        float wcv[8] = {w0.x,w0.y,w0.z,w0.w,w1.x,w1.y,w1.z,w1.w};
        #pragma unroll
        for (int i = 0; i < 8; i++)
            #pragma unroll
            for (int j = 0; j < 8; j++) acc[i][j] += ar[i]*wcv[j];
        a0=na0; a1=na1; w0=nw0; w1=nw1;
    }
    #pragma unroll
    for (int i = 0; i < 8; i++){
        size_t r = (size_t)(r0 + rg*8 + i);
        float4 pk;
        pk.x = packf16(acc[i][0], acc[i][1]);
        pk.y = packf16(acc[i][2], acc[i][3]);
        pk.z = packf16(acc[i][4], acc[i][5]);
        pk.w = packf16(acc[i][6], acc[i][7]);
        *(float4*)&hlinH[r*32 + cg*4] = pk;
    }
}

// ---------- layer-2 gather over packed f16 rows (128 B/row), fp32 accum ----------
// 32 lanes per node (one f16x2 pair per lane), 8 nodes per 256-block.
__global__ __launch_bounds__(256) void gather2h(
        const int* __restrict__ offsets, const int2* __restrict__ edge_s,
        const float* __restrict__ dis, const float* __restrict__ hlinH,
        const float* __restrict__ bias, float* __restrict__ outA){
    int j = blockIdx.x*8 + (threadIdx.x >> 5);
    int p = threadIdx.x & 31;
    float d = dis[j];
    float dd = d*d;
    F16x2U u; u.f = hlinH[(size_t)j*32 + p];
    float ax = (float)u.h[0]*dd;
    float ay = (float)u.h[1]*dd;
    int k  = offsets[j];
    int k1 = offsets[j+1];
    for (; k+2 <= k1; k += 2){
        int2 e0 = edge_s[k], e1 = edge_s[k+1];
        F16x2U a, b;
        a.f = hlinH[(size_t)e0.x*32 + p];
        b.f = hlinH[(size_t)e1.x*32 + p];
        float n0 = __int_as_float(e0.y), n1 = __int_as_float(e1.y);
        ax += (float)a.h[0]*n0; ay += (float)a.h[1]*n0;
        ax += (float)b.h[0]*n1; ay += (float)b.h[1]*n1;
    }
    if (k < k1){
        int2 e0 = edge_s[k];
        F16x2U a; a.f = hlinH[(size_t)e0.x*32 + p];
        float n0 = __int_as_float(e0.y);
        ax += (float)a.h[0]*n0; ay += (float)a.h[1]*n0;
    }
    float2 bv = *(const float2*)&bias[2*p];
    float2 ob;
    ob.x = fmaxf(ax + bv.x, 0.f);
    ob.y = fmaxf(ay + bv.y, 0.f);
    *(float2*)&outA[(size_t)j*64 + 2*p] = ob;
}

// ---------- BatchNorm stats / finalize ----------
__global__ void stats_only(const float* __restrict__ a,
                           float* __restrict__ gsum, float* __restrict__ gsq){
    float s = 0.f, s2 = 0.f;
    int stride = gridDim.x*blockDim.x;
    for (int idx = blockIdx.x*blockDim.x + threadIdx.x; idx < N_NODES*64; idx += stride){
        float v = a[idx];
        s += v; s2 += v*v;
    }
    __shared__ float s1m[256], s2m[256];
    s1m[threadIdx.x] = s; s2m[threadIdx.x] = s2;
    __syncthreads();
    if (threadIdx.x < 64){
        float t1 = s1m[threadIdx.x]+s1m[threadIdx.x+64]+s1m[threadIdx.x+128]+s1m[threadIdx.x+192];
        float t2 = s2m[threadIdx.x]+s2m[threadIdx.x+64]+s2m[threadIdx.x+128]+s2m[threadIdx.x+192];
        atomicAdd(&gsum[threadIdx.x], t1);
        atomicAdd(&gsq[threadIdx.x], t2);
    }
}

__global__ void bn_finalize(const float* gsum, const float* gsq, const float* g, const float* be,
                            float* scale, float* shift){
    int f = threadIdx.x;
    if (f < 64){
        float mean = gsum[f] * (1.0f/(float)N_NODES);
        float var  = gsq[f]  * (1.0f/(float)N_NODES) - mean*mean;
        var = fmaxf(var, 0.f);
        float sc = g[f]*rsqrtf(var + BN_EPS);
        scale[f] = sc;
        shift[f] = be[f] - mean*sc;
    }
}

// ---------- LSTM weight prep: f16x2 pairs along K, [K/2][256] ----------
__global__ void prep_weights(const float* __restrict__ Wih1, const float* __restrict__ Whh1,
                             const float* __restrict__ bih1, const float* __restrict__ bhh1,
                             const float* __restrict__ Wih2, const float* __restrict__ Whh2,
                             const float* __restrict__ bih2, const float* __restrict__ bhh2,
                             float* W1P, float* W2P, float* b1c, float* b2c){
    int idx = blockIdx.x*blockDim.x + threadIdx.x;
    if (idx < 96*256){
        int k2 = idx >> 8, g = idx & 255;
        int k = 2*k2;
        float a = (k   < 128) ? Wih1[g*128 + k]   : Whh1[g*64 + (k-128)];
        float b = (k+1 < 128) ? Wih1[g*128 + k+1] : Whh1[g*64 + (k+1-128)];
        W1P[idx] = packf16(a, b);
    }
    int i2 = idx - 96*256;
    if (i2 >= 0 && i2 < 64*256){
        int k2 = i2 >> 8, g = i2 & 255;
        int k = 2*k2;
        float a = (k   < 64) ? Wih2[g*64 + k]   : Whh2[g*64 + (k-64)];
        float b = (k+1 < 64) ? Wih2[g*64 + k+1] : Whh2[g*64 + (k+1-64)];
        W2P[i2] = packf16(a, b);
    }
    int i3 = idx - (96*256 + 64*256);
    if (i3 >= 0 && i3 < 256) b1c[i3] = bih1[i3] + bhh1[i3];
    int i4 = i3 - 256;
    if (i4 >= 0 && i4 < 256) b2c[i4] = bih2[i4] + bhh2[i4];
}

// ---------- fused LSTM1+LSTM2 one time step (f16 dot2, fp32 accum) ----------
#define XSP 36
__global__ __launch_bounds__(256) void lstm_step(
        const float* __restrict__ h1, const float* __restrict__ g2raw,
        const float* __restrict__ scal2, const float* __restrict__ shif2,
        const float* __restrict__ W1P, const float* __restrict__ W2P,
        const float* __restrict__ b1c, const float* __restrict__ b2c,
        float* __restrict__ h1s, float* __restrict__ c1s,
        float* __restrict__ h2s, float* __restrict__ c2s, int t){
    __shared__ float xsP[96*XSP];
    int tid = threadIdx.x;
    int j0 = blockIdx.x * 32;

    {
        int k4 = tid & 15;
        int rb = tid >> 4;
        int ka = k4*4;
        float4 sc2 = *(const float4*)&scal2[ka];
        float4 sh2 = *(const float4*)&shif2[ka];
        for (int it = 0; it < 2; it++){
            int r = it*16 + rb;
            int j = j0 + r;
            int b = j / NN_SZ, n = j - b*NN_SZ;
            size_t rowg = (size_t)((b*T_WIN + t)*NN_SZ + n);
            float4 va = *(const float4*)&h1[rowg*64 + ka];
            float4 vr = *(const float4*)&g2raw[rowg*64 + ka];
            float4 vb;
            vb.x = vr.x*sc2.x+sh2.x; vb.y = vr.y*sc2.y+sh2.y;
            vb.z = vr.z*sc2.z+sh2.z; vb.w = vr.w*sc2.w+sh2.w;
            float4 vc = *(const float4*)&h1s[(size_t)j*64 + ka];
            int p = ka >> 1;
            xsP[(p  )*XSP + r]    = packf16(va.x, va.y);
            xsP[(p+1)*XSP + r]    = packf16(va.z, va.w);
            xsP[(32+p  )*XSP + r] = packf16(vb.x, vb.y);
            xsP[(32+p+1)*XSP + r] = packf16(vb.z, vb.w);
            xsP[(64+p  )*XSP + r] = packf16(vc.x, vc.y);
            xsP[(64+p+1)*XSP + r] = packf16(vc.z, vc.w);
        }
    }
    __syncthreads();

    int cg = tid & 15;
    int rg = tid >> 4;
    float acc[2][16];

    // ---- phase 1: gates1, 96 k-pairs ----
    {
        float bc[16];
        *(float4*)&bc[0]  = *(const float4*)&b1c[      cg*4];
        *(float4*)&bc[4]  = *(const float4*)&b1c[ 64 + cg*4];
        *(float4*)&bc[8]  = *(const float4*)&b1c[128 + cg*4];
        *(float4*)&bc[12] = *(const float4*)&b1c[192 + cg*4];
        #pragma unroll
        for (int rr = 0; rr < 2; rr++)
            #pragma unroll
            for (int q = 0; q < 16; q++) acc[rr][q] = bc[q];

        float2 av = *(const float2*)&xsP[0*XSP + rg*2];
        float4 w0 = *(const float4*)&W1P[      cg*4];
        float4 w1 = *(const float4*)&W1P[ 64 + cg*4];
        float4 w2 = *(const float4*)&W1P[128 + cg*4];
        float4 w3 = *(const float4*)&W1P[192 + cg*4];
        for (int k2 = 0; k2 < 96; k2++){
            float2 nav; float4 nw0, nw1, nw2, nw3;
            if (k2 < 95){
                nav = *(const float2*)&xsP[(k2+1)*XSP + rg*2];
                const float* wp = &W1P[(k2+1)*256 + cg*4];
                nw0 = *(const float4*)&wp[0];   nw1 = *(const float4*)&wp[64];
                nw2 = *(const float4*)&wp[128]; nw3 = *(const float4*)&wp[192];
            }
            F16x2U a0, a1; a0.f = av.x; a1.f = av.y;
            F4H W0, W1v, W2v, W3v; W0.f4=w0; W1v.f4=w1; W2v.f4=w2; W3v.f4=w3;
            #pragma unroll
            for (int cc = 0; cc < 4; cc++){
                acc[0][cc]    = dot2f(a0.h, W0.h[cc],  acc[0][cc]);
                acc[0][4+cc]  = dot2f(a0.h, W1v.h[cc], acc[0][4+cc]);
                acc[0][8+cc]  = dot2f(a0.h, W2v.h[cc], acc[0][8+cc]);
                acc[0][12+cc] = dot2f(a0.h, W3v.h[cc], acc[0][12+cc]);
                acc[1][cc]    = dot2f(a1.h, W0.h[cc],  acc[1][cc]);
                acc[1][4+cc]  = dot2f(a1.h, W1v.h[cc], acc[1][4+cc]);
                acc[1][8+cc]  = dot2f(a1.h, W2v.h[cc], acc[1][8+cc]);
                acc[1][12+cc] = dot2f(a1.h, W3v.h[cc], acc[1][12+cc]);
            }
            av=nav; w0=nw0; w1=nw1; w2=nw2; w3=nw3;
        }
    }
    __syncthreads();

    // ---- cell update 1 (in-register) + stage phase-2 inputs ----
    #pragma unroll
    for (int rr = 0; rr < 2; rr++){
        int r = rg*2 + rr;
        size_t j = (size_t)(j0 + r);
        float4 co = *(const float4*)&c1s[j*64 + cg*4];
        float cold[4] = {co.x, co.y, co.z, co.w};
        float cn[4], hn[4];
        #pragma unroll
        for (int cc = 0; cc < 4; cc++){
            float gi = acc[rr][cc], gf = acc[rr][4+cc], gg = acc[rr][8+cc], go = acc[rr][12+cc];
            cn[cc] = sigf(gf)*cold[cc] + sigf(gi)*tanhf(gg);
            hn[cc] = sigf(go)*tanhf(cn[cc]);
        }
        *(float4*)&c1s[j*64 + cg*4] = make_float4(cn[0],cn[1],cn[2],cn[3]);
        *(float4*)&h1s[j*64 + cg*4] = make_float4(hn[0],hn[1],hn[2],hn[3]);
        float4 hp = *(const float4*)&h2s[j*64 + cg*4];
        xsP[(cg*2  )*XSP + r]    = packf16(hn[0], hn[1]);
        xsP[(cg*2+1)*XSP + r]    = packf16(hn[2], hn[3]);
        xsP[(32+cg*2  )*XSP + r] = packf16(hp.x, hp.y);
        xsP[(32+cg*2+1)*XSP + r] = packf16(hp.z, hp.w);
    }
    __syncthreads();

    // ---- phase 2: gates2, 64 k-pairs ----
    {
        float bc[16];
        *(float4*)&bc[0]  = *(const float4*)&b2c[      cg*4];
        *(float4*)&bc[4]  = *(const float4*)&b2c[ 64 + cg*4];
        *(float4*)&bc[8]  = *(const float4*)&b2c[128 + cg*4];
        *(float4*)&bc[12] = *(const float4*)&b2c[192 + cg*4];
        #pragma unroll
        for (int rr = 0; rr < 2; rr++)
            #pragma unroll
            for (int q = 0; q < 16; q++) acc[rr][q] = bc[q];

        float2 av = *(const float2*)&xsP[0*XSP + rg*2];
        float4 w0 = *(const float4*)&W2P[      cg*4];
        float4 w1 = *(const float4*)&W2P[ 64 + cg*4];
        float4 w2 = *(const float4*)&W2P[128 + cg*4];
        float4 w3 = *(const float4*)&W2P[192 + cg*4];
        for (int k2 = 0; k2 < 64; k2++){
            float2 nav; float4 nw0, nw1, nw2, nw3;
            if (k2 < 63){
                nav = *(const float2*)&xsP[(k2+1)*XSP + rg*2];
                const float* wp = &W2P[(k2+1)*256 + cg*4];
                nw0 = *(const float4*)&wp[0];   nw1 = *(const float4*)&wp[64];
                nw2 = *(const float4*)&wp[128]; nw3 = *(const float4*)&wp[192];
            }
            F16x2U a0, a1; a0.f = av.x; a1.f = av.y;
            F4H W0, W1v, W2v, W3v; W0.f4=w0; W1v.f4=w1; W2v.f4=w2; W3v.f4=w3;
            #pragma unroll
            for (int cc = 0; cc < 4; cc++){
                acc[0][cc]    = dot2f(a0.h, W0.h[cc],  acc[0][cc]);
                acc[0][4+cc]  = dot2f(a0.h, W1v.h[cc], acc[0][4+cc]);
                acc[0][8+cc]  = dot2f(a0.h, W2v.h[cc], acc[0][8+cc]);
                acc[0][12+cc] = dot2f(a0.h, W3v.h[cc], acc[0][12+cc]);
                acc[1][cc]    = dot2f(a1.h, W0.h[cc],  acc[1][cc]);
                acc[1][4+cc]  = dot2f(a1.h, W1v.h[cc], acc[1][4+cc]);
                acc[1][8+cc]  = dot2f(a1.h, W2v.h[cc], acc[1][8+cc]);
                acc[1][12+cc] = dot2f(a1.h, W3v.h[cc], acc[1][12+cc]);
            }
            av=nav; w0=nw0; w1=nw1; w2=nw2; w3=nw3;
        }
    }

    // ---- cell update 2 ----
    #pragma unroll
    for (int rr = 0; rr < 2; rr++){
        size_t j = (size_t)(j0 + rg*2 + rr);
        float4 co = *(const float4*)&c2s[j*64 + cg*4];
        float cold[4] = {co.x, co.y, co.z, co.w};
        float cn[4], hn[4];
        #pragma unroll
        for (int cc = 0; cc < 4; cc++){
            float gi = acc[rr][cc], gf = acc[rr][4+cc], gg = acc[rr][8+cc], go = acc[rr][12+cc];
            cn[cc] = sigf(gf)*cold[cc] + sigf(gi)*tanhf(gg);
            hn[cc] = sigf(go)*tanhf(cn[cc]);
        }
        *(float4*)&c2s[j*64 + cg*4] = make_float4(cn[0],cn[1],cn[2],cn[3]);
        *(float4*)&h2s[j*64 + cg*4] = make_float4(hn[0],hn[1],hn[2],hn[3]);
    }
}

// ---------- FC head ----------
__global__ __launch_bounds__(256) void fc_head(
        const float* __restrict__ h1s, const float* __restrict__ h2s,
        const float* __restrict__ inner, const float* __restrict__ x,
        const float* __restrict__ fc1_w, const float* __restrict__ fc1_b,
        const float* __restrict__ fc3_w, const float* __restrict__ fc3_b,
        float* __restrict__ out){
    __shared__ float zsm[4][226];
    int wv = threadIdx.x >> 6;
    int f  = threadIdx.x & 63;
    int j  = blockIdx.x*4 + wv;
    int b = j / NN_SZ, n = j - b*NN_SZ;
    for (int k = f; k < 225; k += 64){
        float v;
        if (k < 64)        v = h1s[j*64 + k];
        else if (k < 128)  v = h2s[j*64 + (k-64)];
        else if (k == 128) v = inner[j];
        else {
            int kk = k - 129;
            int w_ = kk >> 3, ff = kk & 7;
            v = x[((b*T_WIN + w_)*NN_SZ + n)*FIN + ff];
        }
        zsm[wv][k] = v;
    }
    __syncthreads();
    float acc = fc1_b[f];
    for (int k = 0; k < 225; k++) acc += zsm[wv][k]*fc1_w[k*64 + f];
    float p = fmaxf(acc, 0.f) * fc3_w[f];
    #pragma unroll
    for (int off = 32; off > 0; off >>= 1) p += __shfl_down(p, off, 64);
    if (f == 0) out[j] = fmaxf(p + fc3_b[0], 0.f);
}

extern "C" void kernel_launch(void* const* d_in, const int* in_sizes, int n_in,
                              void* d_out, int out_size, void* d_ws, size_t ws_size,
                              hipStream_t stream){
    const int*   adj  = (const int*)d_in[0];
    const int*   row  = adj;
    const int*   col  = adj + EDGES;
    const float* aw   = (const float*)d_in[1];
    const float* x    = (const float*)d_in[2];
    const float* inner= (const float*)d_in[3];
    const float* W1   = (const float*)d_in[4];
    const float* b1   = (const float*)d_in[5];
    const float* W2   = (const float*)d_in[6];
    const float* b2   = (const float*)d_in[7];
    const float* g1   = (const float*)d_in[8];
    const float* be1  = (const float*)d_in[9];
    const float* g2   = (const float*)d_in[10];
    const float* be2  = (const float*)d_in[11];
    const float* Wih1 = (const float*)d_in[12];
    const float* Whh1 = (const float*)d_in[13];
    const float* bih1 = (const float*)d_in[14];
    const float* bhh1 = (const float*)d_in[15];
    const float* Wih2 = (const float*)d_in[16];
    const float* Whh2 = (const float*)d_in[17];
    const float* bih2 = (const float*)d_in[18];
    const float* bhh2 = (const float*)d_in[19];
    const float* fc1w = (const float*)d_in[20];
    const float* fc1b = (const float*)d_in[21];
    const float* fc3w = (const float*)d_in[22];
    const float* fc3b = (const float*)d_in[23];
    float* out = (float*)d_out;

    float* ws = (float*)d_ws;
    const size_t NB = (size_t)N_NODES*64;            // 12,288,000 floats
    float* bufX = ws;                                 // hlinH + aggx -> LSTM states + W
    float* bufY = ws + NB;                            // gcnA1 -> gcnA2 (live through LSTM)
    float* bufZ = ws + 2*NB;                          // h1 = BN1 out (live through LSTM)
    int2*  edge_s  = (int2*)(ws + 3*NB);              // E int2
    float* degdis  = ws + 3*NB + (size_t)2*EDGES;     // N
    float* gsum    = degdis + N_NODES;
    float* gsq     = gsum + 64;
    float* scal    = gsq + 64;
    float* shif    = scal + 64;
    float* scal2   = shif + 64;
    float* shif2   = scal2 + 64;
    int* cnt     = (int*)(shif2 + 64);                // N
    int* excl    = cnt + N_NODES;                     // N
    int* bsum    = excl + N_NODES;                    // 1024
    int* bscan   = bsum + 1024;                       // 1024
    int* offsets = bscan + 1024;                      // N+2
    int* cursor  = offsets + (N_NODES+2);             // N

    // phase-1 aliases in bufX
    float* hlinH = bufX;                              // N*32 packed f16
    float* ax    = bufX + (size_t)N_NODES*32 + 64;    // N*8

    // LSTM-phase aliases into bufX (hlinH/ax dead after gather2h)
    float* h1s = bufX;
    float* c1s = bufX + (size_t)BN_ROWS*64;
    float* h2s = bufX + (size_t)2*BN_ROWS*64;
    float* c2s = bufX + (size_t)3*BN_ROWS*64;
    float* W1P = bufX + (size_t)4*BN_ROWS*64;
    float* W2P = W1P + 96*256;
    float* b1c = W2P + 64*256;
    float* b2c = b1c + 256;

    float* gcnA1 = bufY;
    float* h1    = bufZ;
    float* gcnA2 = bufY;

    // ---- edge preprocessing ----
    hipMemsetAsync(degdis, 0, N_NODES*sizeof(float), stream);
    hipMemsetAsync(cnt,    0, N_NODES*sizeof(int),   stream);
    edge_pre <<<(EDGES+255)/256, 256, 0, stream>>>(col, aw, degdis, cnt);
    scanA    <<<750, 256, 0, stream>>>(cnt, excl, bsum);
    scanB    <<<1, 1024, 0, stream>>>(bsum, bscan, 750);
    scanC    <<<750, 256, 0, stream>>>(excl, bscan, degdis, offsets, cursor);
    build_csr<<<(EDGES+255)/256, 256, 0, stream>>>(row, col, aw, degdis, cursor, edge_s);

    // ---- GCN layer 1: aggregate in 8-wide space, then transform (+BN1 stats) ----
    aggx_k<<<N_NODES/32, 256, 0, stream>>>(offsets, edge_s, degdis, x, ax);
    hipMemsetAsync(gsum, 0, 128*sizeof(float), stream);
    lin1b_stats<<<1024, 256, 0, stream>>>(ax, W1, b1, gcnA1, gsum, gsq);
    bn_finalize<<<1, 64, 0, stream>>>(gsum, gsq, g1, be1, scal, shif);

    // ---- fused BN1 + layer-2 linear (packed f16 output) ----
    lin2_bn<<<N_NODES/L2ROWS, 128, 0, stream>>>(gcnA1, scal, shif, W2, h1, hlinH);

    // ---- GCN layer 2 (f16 rows, fp32 accumulate) ----
    gather2h<<<N_NODES/8, 256, 0, stream>>>(offsets, edge_s, degdis, hlinH, b2, gcnA2);
    hipMemsetAsync(gsum, 0, 128*sizeof(float), stream);
    stats_only<<<1024, 256, 0, stream>>>(gcnA2, gsum, gsq);
    bn_finalize<<<1, 64, 0, stream>>>(gsum, gsq, g2, be2, scal2, shif2);

    // ---- LSTMs ----
    prep_weights<<<(96*256 + 64*256 + 512 + 255)/256, 256, 0, stream>>>(
        Wih1, Whh1, bih1, bhh1, Wih2, Whh2, bih2, bhh2, W1P, W2P, b1c, b2c);
    hipMemsetAsync(h1s, 0, (size_t)4*BN_ROWS*64*sizeof(float), stream);
    for (int t = 0; t < T_WIN; t++)
        lstm_step<<<BN_ROWS/32, 256, 0, stream>>>(h1, gcnA2, scal2, shif2,
                                                  W1P, W2P, b1c, b2c,
                                                  h1s, c1s, h2s, c2s, t);

    // ---- FC head ----
    fc_head<<<BN_ROWS/4, 256, 0, stream>>>(h1s, h2s, inner, x, fc1w, fc1b, fc3w, fc3b, out);
}

// Round 6
// 1123.050 us; speedup vs baseline: 1.9077x; 1.1038x over previous
//
#include <hip/hip_runtime.h>
#include <math.h>

#define N_NODES 192000
#define EDGES   2000000
#define HID     64
#define BN_ROWS 16000   // B*NN
#define T_WIN   12
#define B_SZ    8
#define NN_SZ   2000
#define FIN     8
#define BN_EPS  1e-5f

typedef _Float16 f16x2 __attribute__((ext_vector_type(2)));
union F16x2U { float f; f16x2 h; };
union F4H    { float4 f4; f16x2 h[4]; };
union F2H    { float2 f2; f16x2 h[2]; };

__device__ __forceinline__ float sigf(float x){ return 1.0f/(1.0f+expf(-x)); }

__device__ __forceinline__ float dot2f(f16x2 a, f16x2 b, float c){
#if __has_builtin(__builtin_amdgcn_fdot2)
    return __builtin_amdgcn_fdot2(a, b, c, false);
#else
    return c + (float)a[0]*(float)b[0] + (float)a[1]*(float)b[1];
#endif
}

__device__ __forceinline__ float packf16(float a, float b){
    F16x2U u; u.h[0] = (_Float16)a; u.h[1] = (_Float16)b; return u.f;
}

// ---------- edge preprocessing: packed (count<<32 | fixed-point degree) ----------
__global__ void edge_pre(const int* __restrict__ col, const float* __restrict__ w,
                         unsigned long long* __restrict__ dc){
    int e = blockIdx.x*blockDim.x + threadIdx.x;
    if (e < EDGES){
        int c = col[e];
        unsigned int fx = (unsigned int)(w[e]*16777216.0f + 0.5f);   // w in [0,1)
        atomicAdd(&dc[c], (1ULL << 32) | (unsigned long long)fx);
    }
}

__global__ void scanA(const unsigned long long* __restrict__ dc,
                      int* __restrict__ excl, int* __restrict__ bsum){
    __shared__ int sm[256];
    int i = blockIdx.x*256 + threadIdx.x;
    int v = (int)(dc[i] >> 32);
    sm[threadIdx.x] = v;
    __syncthreads();
    #pragma unroll
    for (int off = 1; off < 256; off <<= 1){
        int t = (threadIdx.x >= off) ? sm[threadIdx.x - off] : 0;
        __syncthreads();
        sm[threadIdx.x] += t;
        __syncthreads();
    }
    excl[i] = sm[threadIdx.x] - v;
    if (threadIdx.x == 255) bsum[blockIdx.x] = sm[255];
}

__global__ void scanB(const int* __restrict__ bsum, int* __restrict__ bscan, int nb){
    __shared__ int sm[1024];
    int tid = threadIdx.x;
    int v = (tid < nb) ? bsum[tid] : 0;
    sm[tid] = v;
    __syncthreads();
    #pragma unroll
    for (int off = 1; off < 1024; off <<= 1){
        int t = (tid >= off) ? sm[tid - off] : 0;
        __syncthreads();
        sm[tid] += t;
        __syncthreads();
    }
    bscan[tid] = sm[tid] - v;
}

__global__ void scanC(const int* __restrict__ excl, const int* __restrict__ bscan,
                      const unsigned long long* __restrict__ dc,
                      float* __restrict__ dis,
                      int* __restrict__ offsets, int* __restrict__ cursor){
    int i = blockIdx.x*256 + threadIdx.x;
    int off = excl[i] + bscan[i >> 8];
    offsets[i] = off;
    cursor[i]  = off;
    float deg = (float)(unsigned int)(dc[i] & 0xffffffffULL) * (1.0f/16777216.0f);
    dis[i] = rsqrtf(deg + 1.0f);   // + self-loop weight
    if (i == N_NODES-1) offsets[N_NODES] = EDGES;
}

__global__ void build_csr(const int* __restrict__ row, const int* __restrict__ col,
                          const float* __restrict__ w, const float* __restrict__ dis,
                          int* __restrict__ cursor, int2* __restrict__ edge_s){
    int e = blockIdx.x*blockDim.x + threadIdx.x;
    if (e >= EDGES) return;
    int r = row[e], c = col[e];
    float nr = dis[r]*w[e]*dis[c];
    int p = atomicAdd(&cursor[c], 1);
    int2 ev; ev.x = r; ev.y = __float_as_int(nr);
    edge_s[p] = ev;
}

// ---------- layer-1 aggregation in 8-wide input space: aggx = A_hat @ x ----------
__global__ __launch_bounds__(256) void aggx_k(
        const int* __restrict__ offsets, const int2* __restrict__ edge_s,
        const float* __restrict__ dis, const float* __restrict__ x,
        float* __restrict__ ax){
    int g   = blockIdx.x*32 + (threadIdx.x >> 3);
    int sub = threadIdx.x & 7;
    float d = dis[g];
    float acc = x[(size_t)g*8 + sub]*d*d;
    int k  = offsets[g];
    int k1 = offsets[g+1];
    for (; k+4 <= k1; k += 4){
        int2 e0 = edge_s[k], e1 = edge_s[k+1], e2 = edge_s[k+2], e3 = edge_s[k+3];
        float v0 = x[(size_t)e0.x*8 + sub];
        float v1 = x[(size_t)e1.x*8 + sub];
        float v2 = x[(size_t)e2.x*8 + sub];
        float v3 = x[(size_t)e3.x*8 + sub];
        acc += v0*__int_as_float(e0.y);
        acc += v1*__int_as_float(e1.y);
        acc += v2*__int_as_float(e2.y);
        acc += v3*__int_as_float(e3.y);
    }
    for (; k < k1; k++){
        int2 e0 = edge_s[k];
        acc += x[(size_t)e0.x*8 + sub]*__int_as_float(e0.y);
    }
    ax[(size_t)g*8 + sub] = acc;
}

// ---------- gcnA1 = relu(aggx @ W1 + b1), fused BN1 stats ----------
__global__ __launch_bounds__(256) void lin1b_stats(
        const float* __restrict__ ax, const float* __restrict__ W1,
        const float* __restrict__ b1, float* __restrict__ out,
        float* __restrict__ gsum, float* __restrict__ gsq){
    __shared__ float Ws[512];
    for (int i = threadIdx.x; i < 512; i += 256) Ws[i] = W1[i];
    __syncthreads();
    int f = threadIdx.x & 63;
    float wc[8];
    #pragma unroll
    for (int q = 0; q < 8; q++) wc[q] = Ws[q*64 + f];
    float bb = b1[f];
    float s = 0.f, s2 = 0.f;
    int stride = gridDim.x*blockDim.x;   // multiple of 64
    for (int idx = blockIdx.x*blockDim.x + threadIdx.x; idx < N_NODES*64; idx += stride){
        int j = idx >> 6;
        const float* ar = ax + (size_t)j*8;
        float acc = bb;
        #pragma unroll
        for (int q = 0; q < 8; q++) acc += ar[q]*wc[q];
        float v = fmaxf(acc, 0.f);
        out[idx] = v;
        s += v; s2 += v*v;
    }
    __shared__ float s1m[256], s2m[256];
    s1m[threadIdx.x] = s; s2m[threadIdx.x] = s2;
    __syncthreads();
    if (threadIdx.x < 64){
        float t1 = s1m[threadIdx.x]+s1m[threadIdx.x+64]+s1m[threadIdx.x+128]+s1m[threadIdx.x+192];
        float t2 = s2m[threadIdx.x]+s2m[threadIdx.x+64]+s2m[threadIdx.x+128]+s2m[threadIdx.x+192];
        atomicAdd(&gsum[threadIdx.x], t1);
        atomicAdd(&gsq[threadIdx.x], t2);
    }
}

// ---------- lin2_bn: h1 = BN(gcnA1); hlinH = pack_f16(h1 @ W2) ----------
#define L2ROWS 128
#define XS2    132
__global__ __launch_bounds__(128) void lin2_bn(
        const float* __restrict__ gcnA, const float* __restrict__ scal,
        const float* __restrict__ shif, const float* __restrict__ W2,
        float* __restrict__ h1_out, float* __restrict__ hlinH){
    __shared__ float Ws[64*64];
    __shared__ float xsT[64*XS2];
    int tid = threadIdx.x;
    int r0 = blockIdx.x * L2ROWS;

    for (int i = tid; i < 1024; i += 128)
        *(float4*)&Ws[i*4] = *(const float4*)&W2[i*4];

    int k4 = tid & 15;
    int rb = tid >> 4;
    float4 sc = *(const float4*)&scal[k4*4];
    float4 sh = *(const float4*)&shif[k4*4];
    for (int it = 0; it < 16; it++){
        int r = it*8 + rb;
        float4 v = *(const float4*)&gcnA[(size_t)(r0+r)*64 + k4*4];
        v.x = v.x*sc.x+sh.x; v.y = v.y*sc.y+sh.y; v.z = v.z*sc.z+sh.z; v.w = v.w*sc.w+sh.w;
        *(float4*)&h1_out[(size_t)(r0+r)*64 + k4*4] = v;
        xsT[(k4*4+0)*XS2 + r] = v.x;
        xsT[(k4*4+1)*XS2 + r] = v.y;
        xsT[(k4*4+2)*XS2 + r] = v.z;
        xsT[(k4*4+3)*XS2 + r] = v.w;
    }
    __syncthreads();

    int cg = tid & 7;
    int rg = tid >> 3;
    float acc[8][8];
    #pragma unroll
    for (int i = 0; i < 8; i++)
        #pragma unroll
        for (int j = 0; j < 8; j++) acc[i][j] = 0.f;

    float4 a0 = *(float4*)&xsT[0*XS2 + rg*8];
    float4 a1 = *(float4*)&xsT[0*XS2 + rg*8 + 4];
    float4 w0 = *(float4*)&Ws[0*64 + cg*8];
    float4 w1 = *(float4*)&Ws[0*64 + cg*8 + 4];
    for (int k = 0; k < 64; k++){
        float4 na0, na1, nw0, nw1;
        if (k < 63){
            na0 = *(float4*)&xsT[(k+1)*XS2 + rg*8];
            na1 = *(float4*)&xsT[(k+1)*XS2 + rg*8 + 4];
            nw0 = *(float4*)&Ws[(k+1)*64 + cg*8];
            nw1 = *(float4*)&Ws[(k+1)*64 + cg*8 + 4];
        }
        float ar[8] = {a0.x,a0.y,a0.z,a0.w,a1.x,a1.y,a1.z,a1.w};
        float wcv[8] = {w0.x,w0.y,w0.z,w0.w,w1.x,w1.y,w1.z,w1.w};
        #pragma unroll
        for (int i = 0; i < 8; i++)
            #pragma unroll
            for (int j = 0; j < 8; j++) acc[i][j] += ar[i]*wcv[j];
        a0=na0; a1=na1; w0=nw0; w1=nw1;
    }
    #pragma unroll
    for (int i = 0; i < 8; i++){
        size_t r = (size_t)(r0 + rg*8 + i);
        float4 pk;
        pk.x = packf16(acc[i][0], acc[i][1]);
        pk.y = packf16(acc[i][2], acc[i][3]);
        pk.z = packf16(acc[i][4], acc[i][5]);
        pk.w = packf16(acc[i][6], acc[i][7]);
        *(float4*)&hlinH[r*32 + cg*4] = pk;
    }
}

// ---------- layer-2 gather over packed f16 rows (128 B/row), fp32 accum ----------
__global__ __launch_bounds__(256) void gather2h(
        const int* __restrict__ offsets, const int2* __restrict__ edge_s,
        const float* __restrict__ dis, const float* __restrict__ hlinH,
        const float* __restrict__ bias, float* __restrict__ outA){
    int j = blockIdx.x*8 + (threadIdx.x >> 5);
    int p = threadIdx.x & 31;
    float d = dis[j];
    float dd = d*d;
    F16x2U u; u.f = hlinH[(size_t)j*32 + p];
    float ax = (float)u.h[0]*dd;
    float ay = (float)u.h[1]*dd;
    int k  = offsets[j];
    int k1 = offsets[j+1];
    for (; k+2 <= k1; k += 2){
        int2 e0 = edge_s[k], e1 = edge_s[k+1];
        F16x2U a, b;
        a.f = hlinH[(size_t)e0.x*32 + p];
        b.f = hlinH[(size_t)e1.x*32 + p];
        float n0 = __int_as_float(e0.y), n1 = __int_as_float(e1.y);
        ax += (float)a.h[0]*n0; ay += (float)a.h[1]*n0;
        ax += (float)b.h[0]*n1; ay += (float)b.h[1]*n1;
    }
    if (k < k1){
        int2 e0 = edge_s[k];
        F16x2U a; a.f = hlinH[(size_t)e0.x*32 + p];
        float n0 = __int_as_float(e0.y);
        ax += (float)a.h[0]*n0; ay += (float)a.h[1]*n0;
    }
    float2 bv = *(const float2*)&bias[2*p];
    float2 ob;
    ob.x = fmaxf(ax + bv.x, 0.f);
    ob.y = fmaxf(ay + bv.y, 0.f);
    *(float2*)&outA[(size_t)j*64 + 2*p] = ob;
}

// ---------- BatchNorm stats / finalize ----------
__global__ void stats_only(const float* __restrict__ a,
                           float* __restrict__ gsum, float* __restrict__ gsq){
    float s = 0.f, s2 = 0.f;
    int stride = gridDim.x*blockDim.x;
    for (int idx = blockIdx.x*blockDim.x + threadIdx.x; idx < N_NODES*64; idx += stride){
        float v = a[idx];
        s += v; s2 += v*v;
    }
    __shared__ float s1m[256], s2m[256];
    s1m[threadIdx.x] = s; s2m[threadIdx.x] = s2;
    __syncthreads();
    if (threadIdx.x < 64){
        float t1 = s1m[threadIdx.x]+s1m[threadIdx.x+64]+s1m[threadIdx.x+128]+s1m[threadIdx.x+192];
        float t2 = s2m[threadIdx.x]+s2m[threadIdx.x+64]+s2m[threadIdx.x+128]+s2m[threadIdx.x+192];
        atomicAdd(&gsum[threadIdx.x], t1);
        atomicAdd(&gsq[threadIdx.x], t2);
    }
}

__global__ void bn_finalize(const float* gsum, const float* gsq, const float* g, const float* be,
                            float* scale, float* shift){
    int f = threadIdx.x;
    if (f < 64){
        float mean = gsum[f] * (1.0f/(float)N_NODES);
        float var  = gsq[f]  * (1.0f/(float)N_NODES) - mean*mean;
        var = fmaxf(var, 0.f);
        float sc = g[f]*rsqrtf(var + BN_EPS);
        scale[f] = sc;
        shift[f] = be[f] - mean*sc;
    }
}

// ---------- LSTM weight prep: f16x2 pairs along K, [K/2][256] ----------
__global__ void prep_weights(const float* __restrict__ Wih1, const float* __restrict__ Whh1,
                             const float* __restrict__ bih1, const float* __restrict__ bhh1,
                             const float* __restrict__ Wih2, const float* __restrict__ Whh2,
                             const float* __restrict__ bih2, const float* __restrict__ bhh2,
                             float* W1P, float* W2P, float* b1c, float* b2c){
    int idx = blockIdx.x*blockDim.x + threadIdx.x;
    if (idx < 96*256){
        int k2 = idx >> 8, g = idx & 255;
        int k = 2*k2;
        float a = (k   < 128) ? Wih1[g*128 + k]   : Whh1[g*64 + (k-128)];
        float b = (k+1 < 128) ? Wih1[g*128 + k+1] : Whh1[g*64 + (k+1-128)];
        W1P[idx] = packf16(a, b);
    }
    int i2 = idx - 96*256;
    if (i2 >= 0 && i2 < 64*256){
        int k2 = i2 >> 8, g = i2 & 255;
        int k = 2*k2;
        float a = (k   < 64) ? Wih2[g*64 + k]   : Whh2[g*64 + (k-64)];
        float b = (k+1 < 64) ? Wih2[g*64 + k+1] : Whh2[g*64 + (k+1-64)];
        W2P[i2] = packf16(a, b);
    }
    int i3 = idx - (96*256 + 64*256);
    if (i3 >= 0 && i3 < 256) b1c[i3] = bih1[i3] + bhh1[i3];
    int i4 = i3 - 256;
    if (i4 >= 0 && i4 < 256) b2c[i4] = bih2[i4] + bhh2[i4];
}

// ---------- fused LSTM1+LSTM2 one time step (f16 dot2, fp32 accum) ----------
// 64 rows/block (250 blocks), 256 threads; thread: 8 rows x (2 cols x 4 gates).
// 4x less L1 weight traffic per row vs the 2-row tile.
#define XSP 68   // 64 rows + 4 pad; k2*XSP*4 B = 272*k2 (16B-aligned)
__global__ __launch_bounds__(256) void lstm_step(
        const float* __restrict__ h1, const float* __restrict__ g2raw,
        const float* __restrict__ scal2, const float* __restrict__ shif2,
        const float* __restrict__ W1P, const float* __restrict__ W2P,
        const float* __restrict__ b1c, const float* __restrict__ b2c,
        float* __restrict__ h1s, float* __restrict__ c1s,
        float* __restrict__ h2s, float* __restrict__ c2s, int t){
    __shared__ float xsP[96*XSP];
    int tid = threadIdx.x;
    int j0 = blockIdx.x * 64;

    // stage pairs along k: k2 [0,32): h1 | [32,64): BN2(g2raw) | [64,96): h1s prev
    {
        int k4 = tid & 15;
        int rb = tid >> 4;
        int ka = k4*4;
        float4 sc2 = *(const float4*)&scal2[ka];
        float4 sh2 = *(const float4*)&shif2[ka];
        for (int it = 0; it < 4; it++){
            int r = it*16 + rb;
            int j = j0 + r;
            int b = j / NN_SZ, n = j - b*NN_SZ;
            size_t rowg = (size_t)((b*T_WIN + t)*NN_SZ + n);
            float4 va = *(const float4*)&h1[rowg*64 + ka];
            float4 vr = *(const float4*)&g2raw[rowg*64 + ka];
            float4 vb;
            vb.x = vr.x*sc2.x+sh2.x; vb.y = vr.y*sc2.y+sh2.y;
            vb.z = vr.z*sc2.z+sh2.z; vb.w = vr.w*sc2.w+sh2.w;
            float4 vc = *(const float4*)&h1s[(size_t)j*64 + ka];
            int p = ka >> 1;
            xsP[(p  )*XSP + r]    = packf16(va.x, va.y);
            xsP[(p+1)*XSP + r]    = packf16(va.z, va.w);
            xsP[(32+p  )*XSP + r] = packf16(vb.x, vb.y);
            xsP[(32+p+1)*XSP + r] = packf16(vb.z, vb.w);
            xsP[(64+p  )*XSP + r] = packf16(vc.x, vc.y);
            xsP[(64+p+1)*XSP + r] = packf16(vc.z, vc.w);
        }
    }
    __syncthreads();

    int cg = tid & 31;   // 2 hidden units per gate: cg*2, cg*2+1
    int rg = tid >> 5;   // 8 row-groups x 8 rows
    float acc[8][8];     // [row][gate*2+cc]

    // ---- phase 1: gates1, 96 k-pairs ----
    {
        float bc[8];
        #pragma unroll
        for (int g = 0; g < 4; g++){
            float2 bv = *(const float2*)&b1c[g*64 + cg*2];
            bc[g*2] = bv.x; bc[g*2+1] = bv.y;
        }
        #pragma unroll
        for (int rr = 0; rr < 8; rr++)
            #pragma unroll
            for (int q = 0; q < 8; q++) acc[rr][q] = bc[q];

        float4 av0 = *(const float4*)&xsP[0*XSP + rg*8];
        float4 av1 = *(const float4*)&xsP[0*XSP + rg*8 + 4];
        float2 w0 = *(const float2*)&W1P[      cg*2];
        float2 w1 = *(const float2*)&W1P[ 64 + cg*2];
        float2 w2 = *(const float2*)&W1P[128 + cg*2];
        float2 w3 = *(const float2*)&W1P[192 + cg*2];
        for (int k2 = 0; k2 < 96; k2++){
            float4 nav0, nav1; float2 nw0, nw1, nw2, nw3;
            if (k2 < 95){
                nav0 = *(const float4*)&xsP[(k2+1)*XSP + rg*8];
                nav1 = *(const float4*)&xsP[(k2+1)*XSP + rg*8 + 4];
                const float* wp = &W1P[(k2+1)*256 + cg*2];
                nw0 = *(const float2*)&wp[0];   nw1 = *(const float2*)&wp[64];
                nw2 = *(const float2*)&wp[128]; nw3 = *(const float2*)&wp[192];
            }
            F4H A0, A1; A0.f4 = av0; A1.f4 = av1;
            F2H Wg0, Wg1, Wg2, Wg3; Wg0.f2=w0; Wg1.f2=w1; Wg2.f2=w2; Wg3.f2=w3;
            #pragma unroll
            for (int rr = 0; rr < 8; rr++){
                f16x2 a = (rr < 4) ? A0.h[rr] : A1.h[rr-4];
                acc[rr][0] = dot2f(a, Wg0.h[0], acc[rr][0]);
                acc[rr][1] = dot2f(a, Wg0.h[1], acc[rr][1]);
                acc[rr][2] = dot2f(a, Wg1.h[0], acc[rr][2]);
                acc[rr][3] = dot2f(a, Wg1.h[1], acc[rr][3]);
                acc[rr][4] = dot2f(a, Wg2.h[0], acc[rr][4]);
                acc[rr][5] = dot2f(a, Wg2.h[1], acc[rr][5]);
                acc[rr][6] = dot2f(a, Wg3.h[0], acc[rr][6]);
                acc[rr][7] = dot2f(a, Wg3.h[1], acc[rr][7]);
            }
            av0=nav0; av1=nav1; w0=nw0; w1=nw1; w2=nw2; w3=nw3;
        }
    }
    __syncthreads();   // phase-1 LDS reads complete before overwrite

    // ---- cell update 1 (in-register) + stage phase-2 inputs ----
    #pragma unroll
    for (int rr = 0; rr < 8; rr++){
        int r = rg*8 + rr;
        size_t j = (size_t)(j0 + r);
        float2 co = *(const float2*)&c1s[j*64 + cg*2];
        float cold[2] = {co.x, co.y};
        float cn[2], hn[2];
        #pragma unroll
        for (int cc = 0; cc < 2; cc++){
            float gi = acc[rr][cc], gf = acc[rr][2+cc], gg = acc[rr][4+cc], go = acc[rr][6+cc];
            cn[cc] = sigf(gf)*cold[cc] + sigf(gi)*tanhf(gg);
            hn[cc] = sigf(go)*tanhf(cn[cc]);
        }
        *(float2*)&c1s[j*64 + cg*2] = make_float2(cn[0],cn[1]);
        *(float2*)&h1s[j*64 + cg*2] = make_float2(hn[0],hn[1]);
        float2 hp = *(const float2*)&h2s[j*64 + cg*2];
        xsP[cg*XSP + r]      = packf16(hn[0], hn[1]);
        xsP[(32+cg)*XSP + r] = packf16(hp.x, hp.y);
    }
    __syncthreads();

    // ---- phase 2: gates2, 64 k-pairs ----
    {
        float bc[8];
        #pragma unroll
        for (int g = 0; g < 4; g++){
            float2 bv = *(const float2*)&b2c[g*64 + cg*2];
            bc[g*2] = bv.x; bc[g*2+1] = bv.y;
        }
        #pragma unroll
        for (int rr = 0; rr < 8; rr++)
            #pragma unroll
            for (int q = 0; q < 8; q++) acc[rr][q] = bc[q];

        float4 av0 = *(const float4*)&xsP[0*XSP + rg*8];
        float4 av1 = *(const float4*)&xsP[0*XSP + rg*8 + 4];
        float2 w0 = *(const float2*)&W2P[      cg*2];
        float2 w1 = *(const float2*)&W2P[ 64 + cg*2];
        float2 w2 = *(const float2*)&W2P[128 + cg*2];
        float2 w3 = *(const float2*)&W2P[192 + cg*2];
        for (int k2 = 0; k2 < 64; k2++){
            float4 nav0, nav1; float2 nw0, nw1, nw2, nw3;
            if (k2 < 63){
                nav0 = *(const float4*)&xsP[(k2+1)*XSP + rg*8];
                nav1 = *(const float4*)&xsP[(k2+1)*XSP + rg*8 + 4];
                const float* wp = &W2P[(k2+1)*256 + cg*2];
                nw0 = *(const float2*)&wp[0];   nw1 = *(const float2*)&wp[64];
                nw2 = *(const float2*)&wp[128]; nw3 = *(const float2*)&wp[192];
            }
            F4H A0, A1; A0.f4 = av0; A1.f4 = av1;
            F2H Wg0, Wg1, Wg2, Wg3; Wg0.f2=w0; Wg1.f2=w1; Wg2.f2=w2; Wg3.f2=w3;
            #pragma unroll
            for (int rr = 0; rr < 8; rr++){
                f16x2 a = (rr < 4) ? A0.h[rr] : A1.h[rr-4];
                acc[rr][0] = dot2f(a, Wg0.h[0], acc[rr][0]);
                acc[rr][1] = dot2f(a, Wg0.h[1], acc[rr][1]);
                acc[rr][2] = dot2f(a, Wg1.h[0], acc[rr][2]);
                acc[rr][3] = dot2f(a, Wg1.h[1], acc[rr][3]);
                acc[rr][4] = dot2f(a, Wg2.h[0], acc[rr][4]);
                acc[rr][5] = dot2f(a, Wg2.h[1], acc[rr][5]);
                acc[rr][6] = dot2f(a, Wg3.h[0], acc[rr][6]);
                acc[rr][7] = dot2f(a, Wg3.h[1], acc[rr][7]);
            }
            av0=nav0; av1=nav1; w0=nw0; w1=nw1; w2=nw2; w3=nw3;
        }
    }

    // ---- cell update 2 ----
    #pragma unroll
    for (int rr = 0; rr < 8; rr++){
        size_t j = (size_t)(j0 + rg*8 + rr);
        float2 co = *(const float2*)&c2s[j*64 + cg*2];
        float cold[2] = {co.x, co.y};
        float cn[2], hn[2];
        #pragma unroll
        for (int cc = 0; cc < 2; cc++){
            float gi = acc[rr][cc], gf = acc[rr][2+cc], gg = acc[rr][4+cc], go = acc[rr][6+cc];
            cn[cc] = sigf(gf)*cold[cc] + sigf(gi)*tanhf(gg);
            hn[cc] = sigf(go)*tanhf(cn[cc]);
        }
        *(float2*)&c2s[j*64 + cg*2] = make_float2(cn[0],cn[1]);
        *(float2*)&h2s[j*64 + cg*2] = make_float2(hn[0],hn[1]);
    }
}

// ---------- FC head ----------
__global__ __launch_bounds__(256) void fc_head(
        const float* __restrict__ h1s, const float* __restrict__ h2s,
        const float* __restrict__ inner, const float* __restrict__ x,
        const float* __restrict__ fc1_w, const float* __restrict__ fc1_b,
        const float* __restrict__ fc3_w, const float* __restrict__ fc3_b,
        float* __restrict__ out){
    __shared__ float zsm[4][226];
    int wv = threadIdx.x >> 6;
    int f  = threadIdx.x & 63;
    int j  = blockIdx.x*4 + wv;
    int b = j / NN_SZ, n = j - b*NN_SZ;
    for (int k = f; k < 225; k += 64){
        float v;
        if (k < 64)        v = h1s[j*64 + k];
        else if (k < 128)  v = h2s[j*64 + (k-64)];
        else if (k == 128) v = inner[j];
        else {
            int kk = k - 129;
            int w_ = kk >> 3, ff = kk & 7;
            v = x[((b*T_WIN + w_)*NN_SZ + n)*FIN + ff];
        }
        zsm[wv][k] = v;
    }
    __syncthreads();
    float acc = fc1_b[f];
    for (int k = 0; k < 225; k++) acc += zsm[wv][k]*fc1_w[k*64 + f];
    float p = fmaxf(acc, 0.f) * fc3_w[f];
    #pragma unroll
    for (int off = 32; off > 0; off >>= 1) p += __shfl_down(p, off, 64);
    if (f == 0) out[j] = fmaxf(p + fc3_b[0], 0.f);
}

extern "C" void kernel_launch(void* const* d_in, const int* in_sizes, int n_in,
                              void* d_out, int out_size, void* d_ws, size_t ws_size,
                              hipStream_t stream){
    const int*   adj  = (const int*)d_in[0];
    const int*   row  = adj;
    const int*   col  = adj + EDGES;
    const float* aw   = (const float*)d_in[1];
    const float* x    = (const float*)d_in[2];
    const float* inner= (const float*)d_in[3];
    const float* W1   = (const float*)d_in[4];
    const float* b1   = (const float*)d_in[5];
    const float* W2   = (const float*)d_in[6];
    const float* b2   = (const float*)d_in[7];
    const float* g1   = (const float*)d_in[8];
    const float* be1  = (const float*)d_in[9];
    const float* g2   = (const float*)d_in[10];
    const float* be2  = (const float*)d_in[11];
    const float* Wih1 = (const float*)d_in[12];
    const float* Whh1 = (const float*)d_in[13];
    const float* bih1 = (const float*)d_in[14];
    const float* bhh1 = (const float*)d_in[15];
    const float* Wih2 = (const float*)d_in[16];
    const float* Whh2 = (const float*)d_in[17];
    const float* bih2 = (const float*)d_in[18];
    const float* bhh2 = (const float*)d_in[19];
    const float* fc1w = (const float*)d_in[20];
    const float* fc1b = (const float*)d_in[21];
    const float* fc3w = (const float*)d_in[22];
    const float* fc3b = (const float*)d_in[23];
    float* out = (float*)d_out;

    float* ws = (float*)d_ws;
    const size_t NB = (size_t)N_NODES*64;            // 12,288,000 floats
    float* bufX = ws;                                 // hlinH + aggx -> LSTM states + W
    float* bufY = ws + NB;                            // gcnA1 -> gcnA2 (live through LSTM)
    float* bufZ = ws + 2*NB;                          // h1 = BN1 out (live through LSTM)
    int2*  edge_s  = (int2*)(ws + 3*NB);              // E int2
    float* degdis  = ws + 3*NB + (size_t)2*EDGES;     // N (dis)
    float* gsum    = degdis + N_NODES;
    float* gsq     = gsum + 64;
    float* scal    = gsq + 64;
    float* shif    = scal + 64;
    float* scal2   = shif + 64;
    float* shif2   = scal2 + 64;
    unsigned long long* dc = (unsigned long long*)(shif2 + 64);   // N ull (8B-aligned)
    int* excl    = (int*)(dc + N_NODES);              // N
    int* bsum    = excl + N_NODES;                    // 1024
    int* bscan   = bsum + 1024;                       // 1024
    int* offsets = bscan + 1024;                      // N+2
    int* cursor  = offsets + (N_NODES+2);             // N

    // phase-1 aliases in bufX
    float* hlinH = bufX;                              // N*32 packed f16
    float* ax    = bufX + (size_t)N_NODES*32 + 64;    // N*8

    // LSTM-phase aliases into bufX (hlinH/ax dead after gather2h)
    float* h1s = bufX;
    float* c1s = bufX + (size_t)BN_ROWS*64;
    float* h2s = bufX + (size_t)2*BN_ROWS*64;
    float* c2s = bufX + (size_t)3*BN_ROWS*64;
    float* W1P = bufX + (size_t)4*BN_ROWS*64;
    float* W2P = W1P + 96*256;
    float* b1c = W2P + 64*256;
    float* b2c = b1c + 256;

    float* gcnA1 = bufY;
    float* h1    = bufZ;
    float* gcnA2 = bufY;

    // ---- edge preprocessing ----
    hipMemsetAsync(dc, 0, N_NODES*sizeof(unsigned long long), stream);
    edge_pre <<<(EDGES+255)/256, 256, 0, stream>>>(col, aw, dc);
    scanA    <<<750, 256, 0, stream>>>(dc, excl, bsum);
    scanB    <<<1, 1024, 0, stream>>>(bsum, bscan, 750);
    scanC    <<<750, 256, 0, stream>>>(excl, bscan, dc, degdis, offsets, cursor);
    build_csr<<<(EDGES+255)/256, 256, 0, stream>>>(row, col, aw, degdis, cursor, edge_s);

    // ---- GCN layer 1: aggregate in 8-wide space, then transform (+BN1 stats) ----
    aggx_k<<<N_NODES/32, 256, 0, stream>>>(offsets, edge_s, degdis, x, ax);
    hipMemsetAsync(gsum, 0, 128*sizeof(float), stream);
    lin1b_stats<<<1024, 256, 0, stream>>>(ax, W1, b1, gcnA1, gsum, gsq);
    bn_finalize<<<1, 64, 0, stream>>>(gsum, gsq, g1, be1, scal, shif);

    // ---- fused BN1 + layer-2 linear (packed f16 output) ----
    lin2_bn<<<N_NODES/L2ROWS, 128, 0, stream>>>(gcnA1, scal, shif, W2, h1, hlinH);

    // ---- GCN layer 2 (f16 rows, fp32 accumulate) ----
    gather2h<<<N_NODES/8, 256, 0, stream>>>(offsets, edge_s, degdis, hlinH, b2, gcnA2);
    hipMemsetAsync(gsum, 0, 128*sizeof(float), stream);
    stats_only<<<1024, 256, 0, stream>>>(gcnA2, gsum, gsq);
    bn_finalize<<<1, 64, 0, stream>>>(gsum, gsq, g2, be2, scal2, shif2);

    // ---- LSTMs ----
    prep_weights<<<(96*256 + 64*256 + 512 + 255)/256, 256, 0, stream>>>(
        Wih1, Whh1, bih1, bhh1, Wih2, Whh2, bih2, bhh2, W1P, W2P, b1c, b2c);
    hipMemsetAsync(h1s, 0, (size_t)4*BN_ROWS*64*sizeof(float), stream);
    for (int t = 0; t < T_WIN; t++)
        lstm_step<<<BN_ROWS/64, 256, 0, stream>>>(h1, gcnA2, scal2, shif2,
                                                  W1P, W2P, b1c, b2c,
                                                  h1s, c1s, h2s, c2s, t);

    // ---- FC head ----
    fc_head<<<BN_ROWS/4, 256, 0, stream>>>(h1s, h2s, inner, x, fc1w, fc1b, fc3w, fc3b, out);
}

// Round 8
// 846.865 us; speedup vs baseline: 2.5298x; 1.3261x over previous
//
#include <hip/hip_runtime.h>
#include <math.h>

#define N_NODES 192000
#define EDGES   2000000
#define HID     64
#define BN_ROWS 16000   // B*NN
#define T_WIN   12
#define B_SZ    8
#define NN_SZ   2000
#define FIN     8
#define BN_EPS  1e-5f

typedef _Float16 f16x2 __attribute__((ext_vector_type(2)));
typedef _Float16 half4 __attribute__((ext_vector_type(4)));
typedef _Float16 half8 __attribute__((ext_vector_type(8)));
typedef float    f32x4 __attribute__((ext_vector_type(4)));
union F16x2U { float f; f16x2 h; };

__device__ __forceinline__ float sigf(float x){ return 1.0f/(1.0f+expf(-x)); }

__device__ __forceinline__ float packf16(float a, float b){
    F16x2U u; u.h[0] = (_Float16)a; u.h[1] = (_Float16)b; return u.f;
}

// ---------- edge preprocessing: packed (count<<32 | fixed-point degree) ----------
__global__ void edge_pre(const int* __restrict__ col, const float* __restrict__ w,
                         unsigned long long* __restrict__ dc){
    int e = blockIdx.x*blockDim.x + threadIdx.x;
    if (e < EDGES){
        int c = col[e];
        unsigned int fx = (unsigned int)(w[e]*16777216.0f + 0.5f);   // w in [0,1)
        atomicAdd(&dc[c], (1ULL << 32) | (unsigned long long)fx);
    }
}

__global__ void scanA(const unsigned long long* __restrict__ dc,
                      int* __restrict__ excl, int* __restrict__ bsum){
    __shared__ int sm[256];
    int i = blockIdx.x*256 + threadIdx.x;
    int v = (int)(dc[i] >> 32);
    sm[threadIdx.x] = v;
    __syncthreads();
    #pragma unroll
    for (int off = 1; off < 256; off <<= 1){
        int t = (threadIdx.x >= off) ? sm[threadIdx.x - off] : 0;
        __syncthreads();
        sm[threadIdx.x] += t;
        __syncthreads();
    }
    excl[i] = sm[threadIdx.x] - v;
    if (threadIdx.x == 255) bsum[blockIdx.x] = sm[255];
}

__global__ void scanB(const int* __restrict__ bsum, int* __restrict__ bscan, int nb){
    __shared__ int sm[1024];
    int tid = threadIdx.x;
    int v = (tid < nb) ? bsum[tid] : 0;
    sm[tid] = v;
    __syncthreads();
    #pragma unroll
    for (int off = 1; off < 1024; off <<= 1){
        int t = (tid >= off) ? sm[tid - off] : 0;
        __syncthreads();
        sm[tid] += t;
        __syncthreads();
    }
    bscan[tid] = sm[tid] - v;
}

__global__ void scanC(const int* __restrict__ excl, const int* __restrict__ bscan,
                      const unsigned long long* __restrict__ dc,
                      float* __restrict__ dis,
                      int* __restrict__ offsets, int* __restrict__ cursor){
    int i = blockIdx.x*256 + threadIdx.x;
    int off = excl[i] + bscan[i >> 8];
    offsets[i] = off;
    cursor[i]  = off;
    float deg = (float)(unsigned int)(dc[i] & 0xffffffffULL) * (1.0f/16777216.0f);
    dis[i] = rsqrtf(deg + 1.0f);   // + self-loop weight
    if (i == N_NODES-1) offsets[N_NODES] = EDGES;
}

__global__ void build_csr(const int* __restrict__ row, const int* __restrict__ col,
                          const float* __restrict__ w, const float* __restrict__ dis,
                          int* __restrict__ cursor, int2* __restrict__ edge_s){
    int e = blockIdx.x*blockDim.x + threadIdx.x;
    if (e >= EDGES) return;
    int r = row[e], c = col[e];
    float nr = dis[r]*w[e]*dis[c];
    int p = atomicAdd(&cursor[c], 1);
    int2 ev; ev.x = r; ev.y = __float_as_int(nr);
    edge_s[p] = ev;
}

// ---------- layer-1 aggregation in 8-wide input space: aggx = A_hat @ x ----------
__global__ __launch_bounds__(256) void aggx_k(
        const int* __restrict__ offsets, const int2* __restrict__ edge_s,
        const float* __restrict__ dis, const float* __restrict__ x,
        float* __restrict__ ax){
    int g   = blockIdx.x*32 + (threadIdx.x >> 3);
    int sub = threadIdx.x & 7;
    float d = dis[g];
    float acc = x[(size_t)g*8 + sub]*d*d;
    int k  = offsets[g];
    int k1 = offsets[g+1];
    for (; k+4 <= k1; k += 4){
        int2 e0 = edge_s[k], e1 = edge_s[k+1], e2 = edge_s[k+2], e3 = edge_s[k+3];
        float v0 = x[(size_t)e0.x*8 + sub];
        float v1 = x[(size_t)e1.x*8 + sub];
        float v2 = x[(size_t)e2.x*8 + sub];
        float v3 = x[(size_t)e3.x*8 + sub];
        acc += v0*__int_as_float(e0.y);
        acc += v1*__int_as_float(e1.y);
        acc += v2*__int_as_float(e2.y);
        acc += v3*__int_as_float(e3.y);
    }
    for (; k < k1; k++){
        int2 e0 = edge_s[k];
        acc += x[(size_t)e0.x*8 + sub]*__int_as_float(e0.y);
    }
    ax[(size_t)g*8 + sub] = acc;
}

// ---------- gcnA1 = relu(aggx @ W1 + b1), fused BN1 stats ----------
__global__ __launch_bounds__(256) void lin1b_stats(
        const float* __restrict__ ax, const float* __restrict__ W1,
        const float* __restrict__ b1, float* __restrict__ out,
        float* __restrict__ gsum, float* __restrict__ gsq){
    __shared__ float Ws[512];
    for (int i = threadIdx.x; i < 512; i += 256) Ws[i] = W1[i];
    __syncthreads();
    int f = threadIdx.x & 63;
    float wc[8];
    #pragma unroll
    for (int q = 0; q < 8; q++) wc[q] = Ws[q*64 + f];
    float bb = b1[f];
    float s = 0.f, s2 = 0.f;
    int stride = gridDim.x*blockDim.x;   // multiple of 64
    for (int idx = blockIdx.x*blockDim.x + threadIdx.x; idx < N_NODES*64; idx += stride){
        int j = idx >> 6;
        const float* ar = ax + (size_t)j*8;
        float acc = bb;
        #pragma unroll
        for (int q = 0; q < 8; q++) acc += ar[q]*wc[q];
        float v = fmaxf(acc, 0.f);
        out[idx] = v;
        s += v; s2 += v*v;
    }
    __shared__ float s1m[256], s2m[256];
    s1m[threadIdx.x] = s; s2m[threadIdx.x] = s2;
    __syncthreads();
    if (threadIdx.x < 64){
        float t1 = s1m[threadIdx.x]+s1m[threadIdx.x+64]+s1m[threadIdx.x+128]+s1m[threadIdx.x+192];
        float t2 = s2m[threadIdx.x]+s2m[threadIdx.x+64]+s2m[threadIdx.x+128]+s2m[threadIdx.x+192];
        atomicAdd(&gsum[threadIdx.x], t1);
        atomicAdd(&gsq[threadIdx.x], t2);
    }
}

// ---------- lin2_bn: h1 = BN(gcnA1); hlinH = pack_f16(h1 @ W2) ----------
#define L2ROWS 128
#define XS2    132
__global__ __launch_bounds__(128) void lin2_bn(
        const float* __restrict__ gcnA, const float* __restrict__ scal,
        const float* __restrict__ shif, const float* __restrict__ W2,
        float* __restrict__ h1_out, float* __restrict__ hlinH){
    __shared__ float Ws[64*64];
    __shared__ float xsT[64*XS2];
    int tid = threadIdx.x;
    int r0 = blockIdx.x * L2ROWS;

    for (int i = tid; i < 1024; i += 128)
        *(float4*)&Ws[i*4] = *(const float4*)&W2[i*4];

    int k4 = tid & 15;
    int rb = tid >> 4;
    float4 sc = *(const float4*)&scal[k4*4];
    float4 sh = *(const float4*)&shif[k4*4];
    for (int it = 0; it < 16; it++){
        int r = it*8 + rb;
        float4 v = *(const float4*)&gcnA[(size_t)(r0+r)*64 + k4*4];
        v.x = v.x*sc.x+sh.x; v.y = v.y*sc.y+sh.y; v.z = v.z*sc.z+sh.z; v.w = v.w*sc.w+sh.w;
        *(float4*)&h1_out[(size_t)(r0+r)*64 + k4*4] = v;
        xsT[(k4*4+0)*XS2 + r] = v.x;
        xsT[(k4*4+1)*XS2 + r] = v.y;
        xsT[(k4*4+2)*XS2 + r] = v.z;
        xsT[(k4*4+3)*XS2 + r] = v.w;
    }
    __syncthreads();

    int cg = tid & 7;
    int rg = tid >> 3;
    float acc[8][8];
    #pragma unroll
    for (int i = 0; i < 8; i++)
        #pragma unroll
        for (int j = 0; j < 8; j++) acc[i][j] = 0.f;

    float4 a0 = *(float4*)&xsT[0*XS2 + rg*8];
    float4 a1 = *(float4*)&xsT[0*XS2 + rg*8 + 4];
    float4 w0 = *(float4*)&Ws[0*64 + cg*8];
    float4 w1 = *(float4*)&Ws[0*64 + cg*8 + 4];
    for (int k = 0; k < 64; k++){
        float4 na0, na1, nw0, nw1;
        if (k < 63){
            na0 = *(float4*)&xsT[(k+1)*XS2 + rg*8];
            na1 = *(float4*)&xsT[(k+1)*XS2 + rg*8 + 4];
            nw0 = *(float4*)&Ws[(k+1)*64 + cg*8];
            nw1 = *(float4*)&Ws[(k+1)*64 + cg*8 + 4];
        }
        float ar[8] = {a0.x,a0.y,a0.z,a0.w,a1.x,a1.y,a1.z,a1.w};
        float wcv[8] = {w0.x,w0.y,w0.z,w0.w,w1.x,w1.y,w1.z,w1.w};
        #pragma unroll
        for (int i = 0; i < 8; i++)
            #pragma unroll
            for (int j = 0; j < 8; j++) acc[i][j] += ar[i]*wcv[j];
        a0=na0; a1=na1; w0=nw0; w1=nw1;
    }
    #pragma unroll
    for (int i = 0; i < 8; i++){
        size_t r = (size_t)(r0 + rg*8 + i);
        float4 pk;
        pk.x = packf16(acc[i][0], acc[i][1]);
        pk.y = packf16(acc[i][2], acc[i][3]);
        pk.z = packf16(acc[i][4], acc[i][5]);
        pk.w = packf16(acc[i][6], acc[i][7]);
        *(float4*)&hlinH[r*32 + cg*4] = pk;
    }
}

// ---------- layer-2 gather over packed f16 rows (128 B/row), fp32 accum ----------
__global__ __launch_bounds__(256) void gather2h(
        const int* __restrict__ offsets, const int2* __restrict__ edge_s,
        const float* __restrict__ dis, const float* __restrict__ hlinH,
        const float* __restrict__ bias, float* __restrict__ outA){
    int j = blockIdx.x*8 + (threadIdx.x >> 5);
    int p = threadIdx.x & 31;
    float d = dis[j];
    float dd = d*d;
    F16x2U u; u.f = hlinH[(size_t)j*32 + p];
    float ax = (float)u.h[0]*dd;
    float ay = (float)u.h[1]*dd;
    int k  = offsets[j];
    int k1 = offsets[j+1];
    for (; k+4 <= k1; k += 4){
        int2 e0 = edge_s[k], e1 = edge_s[k+1], e2 = edge_s[k+2], e3 = edge_s[k+3];
        F16x2U a, b, c, e;
        a.f = hlinH[(size_t)e0.x*32 + p];
        b.f = hlinH[(size_t)e1.x*32 + p];
        c.f = hlinH[(size_t)e2.x*32 + p];
        e.f = hlinH[(size_t)e3.x*32 + p];
        float n0 = __int_as_float(e0.y), n1 = __int_as_float(e1.y);
        float n2 = __int_as_float(e2.y), n3 = __int_as_float(e3.y);
        ax += (float)a.h[0]*n0; ay += (float)a.h[1]*n0;
        ax += (float)b.h[0]*n1; ay += (float)b.h[1]*n1;
        ax += (float)c.h[0]*n2; ay += (float)c.h[1]*n2;
        ax += (float)e.h[0]*n3; ay += (float)e.h[1]*n3;
    }
    for (; k < k1; k++){
        int2 e0 = edge_s[k];
        F16x2U a; a.f = hlinH[(size_t)e0.x*32 + p];
        float n0 = __int_as_float(e0.y);
        ax += (float)a.h[0]*n0; ay += (float)a.h[1]*n0;
    }
    float2 bv = *(const float2*)&bias[2*p];
    float2 ob;
    ob.x = fmaxf(ax + bv.x, 0.f);
    ob.y = fmaxf(ay + bv.y, 0.f);
    *(float2*)&outA[(size_t)j*64 + 2*p] = ob;
}

// ---------- BatchNorm stats / finalize ----------
__global__ void stats_only(const float* __restrict__ a,
                           float* __restrict__ gsum, float* __restrict__ gsq){
    float s = 0.f, s2 = 0.f;
    int stride = gridDim.x*blockDim.x;
    for (int idx = blockIdx.x*blockDim.x + threadIdx.x; idx < N_NODES*64; idx += stride){
        float v = a[idx];
        s += v; s2 += v*v;
    }
    __shared__ float s1m[256], s2m[256];
    s1m[threadIdx.x] = s; s2m[threadIdx.x] = s2;
    __syncthreads();
    if (threadIdx.x < 64){
        float t1 = s1m[threadIdx.x]+s1m[threadIdx.x+64]+s1m[threadIdx.x+128]+s1m[threadIdx.x+192];
        float t2 = s2m[threadIdx.x]+s2m[threadIdx.x+64]+s2m[threadIdx.x+128]+s2m[threadIdx.x+192];
        atomicAdd(&gsum[threadIdx.x], t1);
        atomicAdd(&gsq[threadIdx.x], t2);
    }
}

__global__ void bn_finalize(const float* gsum, const float* gsq, const float* g, const float* be,
                            float* scale, float* shift){
    int f = threadIdx.x;
    if (f < 64){
        float mean = gsum[f] * (1.0f/(float)N_NODES);
        float var  = gsq[f]  * (1.0f/(float)N_NODES) - mean*mean;
        var = fmaxf(var, 0.f);
        float sc = g[f]*rsqrtf(var + BN_EPS);
        scale[f] = sc;
        shift[f] = be[f] - mean*sc;
    }
}

// ---------- LSTM weight prep: B-fragment layout [K/32][256][32] f16 ----------
__global__ void prep_weights(const float* __restrict__ Wih1, const float* __restrict__ Whh1,
                             const float* __restrict__ bih1, const float* __restrict__ bhh1,
                             const float* __restrict__ Wih2, const float* __restrict__ Whh2,
                             const float* __restrict__ bih2, const float* __restrict__ bhh2,
                             _Float16* W1F, _Float16* W2F, float* b1c, float* b2c){
    int idx = blockIdx.x*blockDim.x + threadIdx.x;
    if (idx < 6*256*32){
        int kt = idx >> 13;
        int rem = idx & 8191;
        int n = rem >> 5, kin = rem & 31;
        int k = kt*32 + kin;
        float v = (k < 128) ? Wih1[n*128 + k] : Whh1[n*64 + (k-128)];
        W1F[idx] = (_Float16)v;
    }
    int i2 = idx - 6*256*32;
    if (i2 >= 0 && i2 < 4*256*32){
        int kt = i2 >> 13;
        int rem = i2 & 8191;
        int n = rem >> 5, kin = rem & 31;
        int k = kt*32 + kin;
        float v = (k < 64) ? Wih2[n*64 + k] : Whh2[n*64 + (k-64)];
        W2F[i2] = (_Float16)v;
    }
    int i3 = idx - (6*256*32 + 4*256*32);
    if (i3 >= 0 && i3 < 256) b1c[i3] = bih1[i3] + bhh1[i3];
    int i4 = i3 - 256;
    if (i4 >= 0 && i4 < 256) b2c[i4] = bih2[i4] + bhh2[i4];
}

// ---------- fused LSTM1+LSTM2 one time step, MFMA 16x16x32 f16 ----------
// 64 rows x 256 gate-cols per block (250 blocks, 256 threads = 4 waves).
// Wave w owns gate-units 16w..16w+15 for ALL rows and ALL 4 gates
// -> cell update fully in-register.
// A frag: X[m=lane&15][k=quad*8+j]; B frag: W[k=quad*8+j][n=lane&15];
// C/D: col=lane&15, row=quad*4+reg  [m89/m120 verified mappings].
#define X1S 200   // halves/row, 400 B (2-way bank alias only)
#define X2S 136   // halves/row, 272 B
__global__ __launch_bounds__(256) void lstm_step(
        const float* __restrict__ h1, const float* __restrict__ g2raw,
        const float* __restrict__ scal2, const float* __restrict__ shif2,
        const _Float16* __restrict__ W1F, const _Float16* __restrict__ W2F,
        const float* __restrict__ b1c, const float* __restrict__ b2c,
        float* __restrict__ h1s, float* __restrict__ c1s,
        float* __restrict__ h2s, float* __restrict__ c2s, int t){
    __shared__ _Float16 X1h[64*X1S];
    __shared__ _Float16 X2h[64*X2S];
    int tid = threadIdx.x;
    int j0 = blockIdx.x*64;

    // ---- stage X1 rows: k[0:64)=h1(gcn1) | [64:128)=BN2(g2raw) | [128:192)=h1s prev ----
    // 64 rows x 3 srcs x 16 float4-groups = 3072 (R7 fix: was 768/c4&3 -> only 16/64 staged)
    for (int idx = tid; idx < 3072; idx += 256){
        int c4 = idx & 15;
        int r  = (idx >> 4) & 63;
        int src= idx >> 10;
        int j = j0 + r;
        float4 v;
        if (src < 2){
            int b = j / NN_SZ, n = j - b*NN_SZ;
            size_t rowg = (size_t)((b*T_WIN + t)*NN_SZ + n);
            if (src == 0){
                v = *(const float4*)&h1[rowg*64 + c4*4];
            } else {
                float4 vr = *(const float4*)&g2raw[rowg*64 + c4*4];
                float4 sc = *(const float4*)&scal2[c4*4];
                float4 sh = *(const float4*)&shif2[c4*4];
                v.x = vr.x*sc.x+sh.x; v.y = vr.y*sc.y+sh.y;
                v.z = vr.z*sc.z+sh.z; v.w = vr.w*sc.w+sh.w;
            }
        } else {
            v = *(const float4*)&h1s[(size_t)j*64 + c4*4];
        }
        half4 hv;
        hv[0] = (_Float16)v.x; hv[1] = (_Float16)v.y;
        hv[2] = (_Float16)v.z; hv[3] = (_Float16)v.w;
        *(half4*)&X1h[r*X1S + src*64 + c4*4] = hv;
    }
    __syncthreads();

    int w    = tid >> 6;
    int lane = tid & 63;
    int quad = lane >> 4;
    int l16  = lane & 15;
    int u    = 16*w + l16;           // gate-unit this lane owns in C/D

    f32x4 acc[4][4];                 // [gate][m-tile]
    #pragma unroll
    for (int g = 0; g < 4; g++)
        #pragma unroll
        for (int mt = 0; mt < 4; mt++) acc[g][mt] = (f32x4){0.f,0.f,0.f,0.f};

    // ---- phase 1: gates1 = X1 @ W1^T, K=192 (6 k-tiles) ----
    #pragma unroll
    for (int kt = 0; kt < 6; kt++){
        half8 a[4], b[4];
        #pragma unroll
        for (int mt = 0; mt < 4; mt++)
            a[mt] = *(const half8*)&X1h[(mt*16 + l16)*X1S + kt*32 + quad*8];
        #pragma unroll
        for (int g = 0; g < 4; g++)
            b[g] = *(const half8*)&W1F[(size_t)(kt*256 + 64*g + 16*w + l16)*32 + quad*8];
        #pragma unroll
        for (int g = 0; g < 4; g++)
            #pragma unroll
            for (int mt = 0; mt < 4; mt++)
                acc[g][mt] = __builtin_amdgcn_mfma_f32_16x16x32_f16(a[mt], b[g], acc[g][mt], 0, 0, 0);
    }

    // ---- cell update 1 (in-register) + stage X2 = [y1 | h2prev] ----
    {
        float bi = b1c[u], bf = b1c[64+u], bg = b1c[128+u], bo = b1c[192+u];
        #pragma unroll
        for (int mt = 0; mt < 4; mt++){
            #pragma unroll
            for (int r = 0; r < 4; r++){
                int rowl = mt*16 + quad*4 + r;
                size_t j = (size_t)(j0 + rowl);
                float gi = acc[0][mt][r] + bi;
                float gf = acc[1][mt][r] + bf;
                float gg = acc[2][mt][r] + bg;
                float go = acc[3][mt][r] + bo;
                float cold = c1s[j*64 + u];
                float cn = sigf(gf)*cold + sigf(gi)*tanhf(gg);
                float hn = sigf(go)*tanhf(cn);
                c1s[j*64 + u] = cn;
                h1s[j*64 + u] = hn;
                X2h[rowl*X2S + u]      = (_Float16)hn;
                X2h[rowl*X2S + 64 + u] = (_Float16)h2s[j*64 + u];
            }
        }
    }
    __syncthreads();

    // ---- phase 2: gates2 = X2 @ W2^T, K=128 (4 k-tiles) ----
    #pragma unroll
    for (int g = 0; g < 4; g++)
        #pragma unroll
        for (int mt = 0; mt < 4; mt++) acc[g][mt] = (f32x4){0.f,0.f,0.f,0.f};

    #pragma unroll
    for (int kt = 0; kt < 4; kt++){
        half8 a[4], b[4];
        #pragma unroll
        for (int mt = 0; mt < 4; mt++)
            a[mt] = *(const half8*)&X2h[(mt*16 + l16)*X2S + kt*32 + quad*8];
        #pragma unroll
        for (int g = 0; g < 4; g++)
            b[g] = *(const half8*)&W2F[(size_t)(kt*256 + 64*g + 16*w + l16)*32 + quad*8];
        #pragma unroll
        for (int g = 0; g < 4; g++)
            #pragma unroll
            for (int mt = 0; mt < 4; mt++)
                acc[g][mt] = __builtin_amdgcn_mfma_f32_16x16x32_f16(a[mt], b[g], acc[g][mt], 0, 0, 0);
    }

    // ---- cell update 2 ----
    {
        float bi = b2c[u], bf = b2c[64+u], bg = b2c[128+u], bo = b2c[192+u];
        #pragma unroll
        for (int mt = 0; mt < 4; mt++){
            #pragma unroll
            for (int r = 0; r < 4; r++){
                int rowl = mt*16 + quad*4 + r;
                size_t j = (size_t)(j0 + rowl);
                float gi = acc[0][mt][r] + bi;
                float gf = acc[1][mt][r] + bf;
                float gg = acc[2][mt][r] + bg;
                float go = acc[3][mt][r] + bo;
                float cold = c2s[j*64 + u];
                float cn = sigf(gf)*cold + sigf(gi)*tanhf(gg);
                float hn = sigf(go)*tanhf(cn);
                c2s[j*64 + u] = cn;
                h2s[j*64 + u] = hn;
            }
        }
    }
}

// ---------- FC head ----------
__global__ __launch_bounds__(256) void fc_head(
        const float* __restrict__ h1s, const float* __restrict__ h2s,
        const float* __restrict__ inner, const float* __restrict__ x,
        const float* __restrict__ fc1_w, const float* __restrict__ fc1_b,
        const float* __restrict__ fc3_w, const float* __restrict__ fc3_b,
        float* __restrict__ out){
    __shared__ float zsm[4][226];
    int wv = threadIdx.x >> 6;
    int f  = threadIdx.x & 63;
    int j  = blockIdx.x*4 + wv;
    int b = j / NN_SZ, n = j - b*NN_SZ;
    for (int k = f; k < 225; k += 64){
        float v;
        if (k < 64)        v = h1s[j*64 + k];
        else if (k < 128)  v = h2s[j*64 + (k-64)];
        else if (k == 128) v = inner[j];
        else {
            int kk = k - 129;
            int w_ = kk >> 3, ff = kk & 7;
            v = x[((b*T_WIN + w_)*NN_SZ + n)*FIN + ff];
        }
        zsm[wv][k] = v;
    }
    __syncthreads();
    float acc = fc1_b[f];
    for (int k = 0; k < 225; k++) acc += zsm[wv][k]*fc1_w[k*64 + f];
    float p = fmaxf(acc, 0.f) * fc3_w[f];
    #pragma unroll
    for (int off = 32; off > 0; off >>= 1) p += __shfl_down(p, off, 64);
    if (f == 0) out[j] = fmaxf(p + fc3_b[0], 0.f);
}

extern "C" void kernel_launch(void* const* d_in, const int* in_sizes, int n_in,
                              void* d_out, int out_size, void* d_ws, size_t ws_size,
                              hipStream_t stream){
    const int*   adj  = (const int*)d_in[0];
    const int*   row  = adj;
    const int*   col  = adj + EDGES;
    const float* aw   = (const float*)d_in[1];
    const float* x    = (const float*)d_in[2];
    const float* inner= (const float*)d_in[3];
    const float* W1   = (const float*)d_in[4];
    const float* b1   = (const float*)d_in[5];
    const float* W2   = (const float*)d_in[6];
    const float* b2   = (const float*)d_in[7];
    const float* g1   = (const float*)d_in[8];
    const float* be1  = (const float*)d_in[9];
    const float* g2   = (const float*)d_in[10];
    const float* be2  = (const float*)d_in[11];
    const float* Wih1 = (const float*)d_in[12];
    const float* Whh1 = (const float*)d_in[13];
    const float* bih1 = (const float*)d_in[14];
    const float* bhh1 = (const float*)d_in[15];
    const float* Wih2 = (const float*)d_in[16];
    const float* Whh2 = (const float*)d_in[17];
    const float* bih2 = (const float*)d_in[18];
    const float* bhh2 = (const float*)d_in[19];
    const float* fc1w = (const float*)d_in[20];
    const float* fc1b = (const float*)d_in[21];
    const float* fc3w = (const float*)d_in[22];
    const float* fc3b = (const float*)d_in[23];
    float* out = (float*)d_out;

    float* ws = (float*)d_ws;
    const size_t NB = (size_t)N_NODES*64;            // 12,288,000 floats
    float* bufX = ws;                                 // hlinH + aggx -> LSTM states + W
    float* bufY = ws + NB;                            // gcnA1 -> gcnA2 (live through LSTM)
    float* bufZ = ws + 2*NB;                          // h1 = BN1 out (live through LSTM)
    int2*  edge_s  = (int2*)(ws + 3*NB);              // E int2
    float* degdis  = ws + 3*NB + (size_t)2*EDGES;     // N (dis)
    float* gsum    = degdis + N_NODES;
    float* gsq     = gsum + 64;
    float* scal    = gsq + 64;
    float* shif    = scal + 64;
    float* scal2   = shif + 64;
    float* shif2   = scal2 + 64;
    unsigned long long* dc = (unsigned long long*)(shif2 + 64);   // N ull (8B-aligned)
    int* excl    = (int*)(dc + N_NODES);              // N
    int* bsum    = excl + N_NODES;                    // 1024
    int* bscan   = bsum + 1024;                       // 1024
    int* offsets = bscan + 1024;                      // N+2
    int* cursor  = offsets + (N_NODES+2);             // N

    // phase-1 aliases in bufX
    float* hlinH = bufX;                              // N*32 packed f16
    float* ax    = bufX + (size_t)N_NODES*32 + 64;    // N*8

    // LSTM-phase aliases into bufX (hlinH/ax dead after gather2h)
    float* h1s = bufX;
    float* c1s = bufX + (size_t)BN_ROWS*64;
    float* h2s = bufX + (size_t)2*BN_ROWS*64;
    float* c2s = bufX + (size_t)3*BN_ROWS*64;
    _Float16* W1F = (_Float16*)(bufX + (size_t)4*BN_ROWS*64);   // 6*256*32 halves
    _Float16* W2F = W1F + 6*256*32;                             // 4*256*32 halves
    float* b1c = (float*)(W2F + 4*256*32);
    float* b2c = b1c + 256;

    float* gcnA1 = bufY;
    float* h1    = bufZ;
    float* gcnA2 = bufY;

    // ---- edge preprocessing ----
    hipMemsetAsync(dc, 0, N_NODES*sizeof(unsigned long long), stream);
    edge_pre <<<(EDGES+255)/256, 256, 0, stream>>>(col, aw, dc);
    scanA    <<<750, 256, 0, stream>>>(dc, excl, bsum);
    scanB    <<<1, 1024, 0, stream>>>(bsum, bscan, 750);
    scanC    <<<750, 256, 0, stream>>>(excl, bscan, dc, degdis, offsets, cursor);
    build_csr<<<(EDGES+255)/256, 256, 0, stream>>>(row, col, aw, degdis, cursor, edge_s);

    // ---- GCN layer 1: aggregate in 8-wide space, then transform (+BN1 stats) ----
    aggx_k<<<N_NODES/32, 256, 0, stream>>>(offsets, edge_s, degdis, x, ax);
    hipMemsetAsync(gsum, 0, 128*sizeof(float), stream);
    lin1b_stats<<<1024, 256, 0, stream>>>(ax, W1, b1, gcnA1, gsum, gsq);
    bn_finalize<<<1, 64, 0, stream>>>(gsum, gsq, g1, be1, scal, shif);

    // ---- fused BN1 + layer-2 linear (packed f16 output) ----
    lin2_bn<<<N_NODES/L2ROWS, 128, 0, stream>>>(gcnA1, scal, shif, W2, h1, hlinH);

    // ---- GCN layer 2 (f16 rows, fp32 accumulate) ----
    gather2h<<<N_NODES/8, 256, 0, stream>>>(offsets, edge_s, degdis, hlinH, b2, gcnA2);
    hipMemsetAsync(gsum, 0, 128*sizeof(float), stream);
    stats_only<<<1024, 256, 0, stream>>>(gcnA2, gsum, gsq);
    bn_finalize<<<1, 64, 0, stream>>>(gsum, gsq, g2, be2, scal2, shif2);

    // ---- LSTMs (MFMA path; states/weights alias bufX after gather2h) ----
    prep_weights<<<(6*256*32 + 4*256*32 + 512 + 255)/256, 256, 0, stream>>>(
        Wih1, Whh1, bih1, bhh1, Wih2, Whh2, bih2, bhh2, W1F, W2F, b1c, b2c);
    hipMemsetAsync(h1s, 0, (size_t)4*BN_ROWS*64*sizeof(float), stream);
    for (int t = 0; t < T_WIN; t++)
        lstm_step<<<BN_ROWS/64, 256, 0, stream>>>(h1, gcnA2, scal2, shif2,
                                                  W1F, W2F, b1c, b2c,
                                                  h1s, c1s, h2s, c2s, t);

    // ---- FC head ----
    fc_head<<<BN_ROWS/4, 256, 0, stream>>>(h1s, h2s, inner, x, fc1w, fc1b, fc3w, fc3b, out);
}

// Round 9
// 680.117 us; speedup vs baseline: 3.1501x; 1.2452x over previous
//
#include <hip/hip_runtime.h>
#include <math.h>

#define N_NODES 192000
#define EDGES   2000000
#define HID     64
#define BN_ROWS 16000   // B*NN
#define T_WIN   12
#define B_SZ    8
#define NN_SZ   2000
#define FIN     8
#define BN_EPS  1e-5f

typedef _Float16 f16x2 __attribute__((ext_vector_type(2)));
typedef _Float16 half4 __attribute__((ext_vector_type(4)));
typedef _Float16 half8 __attribute__((ext_vector_type(8)));
typedef float    f32x4 __attribute__((ext_vector_type(4)));
union F16x2U { float f; f16x2 h; };

__device__ __forceinline__ float sigf(float x){ return 1.0f/(1.0f+expf(-x)); }

__device__ __forceinline__ float packf16(float a, float b){
    F16x2U u; u.h[0] = (_Float16)a; u.h[1] = (_Float16)b; return u.f;
}

// ---------- edge preprocessing ----------
// Packed (count<<32 | fixed-point degree); the returned old count IS this
// edge's rank within its destination bucket -> no cursor atomics later.
__global__ void edge_pre(const int* __restrict__ col, const float* __restrict__ w,
                         unsigned long long* __restrict__ dc, int* __restrict__ rank){
    int e = blockIdx.x*blockDim.x + threadIdx.x;
    if (e < EDGES){
        int c = col[e];
        unsigned int fx = (unsigned int)(w[e]*16777216.0f + 0.5f);   // w in [0,1)
        unsigned long long old = atomicAdd(&dc[c], (1ULL << 32) | (unsigned long long)fx);
        rank[e] = (int)(old >> 32);
    }
}

__global__ void scanA(const unsigned long long* __restrict__ dc,
                      int* __restrict__ excl, int* __restrict__ bsum){
    __shared__ int sm[256];
    int i = blockIdx.x*256 + threadIdx.x;
    int v = (int)(dc[i] >> 32);
    sm[threadIdx.x] = v;
    __syncthreads();
    #pragma unroll
    for (int off = 1; off < 256; off <<= 1){
        int t = (threadIdx.x >= off) ? sm[threadIdx.x - off] : 0;
        __syncthreads();
        sm[threadIdx.x] += t;
        __syncthreads();
    }
    excl[i] = sm[threadIdx.x] - v;
    if (threadIdx.x == 255) bsum[blockIdx.x] = sm[255];
}

__global__ void scanB(const int* __restrict__ bsum, int* __restrict__ bscan, int nb){
    __shared__ int sm[1024];
    int tid = threadIdx.x;
    int v = (tid < nb) ? bsum[tid] : 0;
    sm[tid] = v;
    __syncthreads();
    #pragma unroll
    for (int off = 1; off < 1024; off <<= 1){
        int t = (tid >= off) ? sm[tid - off] : 0;
        __syncthreads();
        sm[tid] += t;
        __syncthreads();
    }
    bscan[tid] = sm[tid] - v;
}

__global__ void scanC(const int* __restrict__ excl, const int* __restrict__ bscan,
                      const unsigned long long* __restrict__ dc,
                      float* __restrict__ dis, int* __restrict__ offsets){
    int i = blockIdx.x*256 + threadIdx.x;
    offsets[i] = excl[i] + bscan[i >> 8];
    float deg = (float)(unsigned int)(dc[i] & 0xffffffffULL) * (1.0f/16777216.0f);
    dis[i] = rsqrtf(deg + 1.0f);   // + self-loop weight
    if (i == N_NODES-1) offsets[N_NODES] = EDGES;
}

// atomic-free CSR placement: p = offsets[c] + rank[e]
__global__ void build_csr(const int* __restrict__ row, const int* __restrict__ col,
                          const float* __restrict__ w, const int* __restrict__ rank,
                          const float* __restrict__ dis, const int* __restrict__ offsets,
                          int2* __restrict__ edge_s){
    int e = blockIdx.x*blockDim.x + threadIdx.x;
    if (e >= EDGES) return;
    int r = row[e], c = col[e];
    float nr = dis[r]*w[e]*dis[c];
    int p = offsets[c] + rank[e];
    int2 ev; ev.x = r; ev.y = __float_as_int(nr);
    edge_s[p] = ev;
}

// ---------- layer-1 aggregation in 8-wide input space: aggx = A_hat @ x ----------
__global__ __launch_bounds__(256) void aggx_k(
        const int* __restrict__ offsets, const int2* __restrict__ edge_s,
        const float* __restrict__ dis, const float* __restrict__ x,
        float* __restrict__ ax){
    int g   = blockIdx.x*32 + (threadIdx.x >> 3);
    int sub = threadIdx.x & 7;
    float d = dis[g];
    float acc = x[(size_t)g*8 + sub]*d*d;
    int k  = offsets[g];
    int k1 = offsets[g+1];
    for (; k+4 <= k1; k += 4){
        int2 e0 = edge_s[k], e1 = edge_s[k+1], e2 = edge_s[k+2], e3 = edge_s[k+3];
        float v0 = x[(size_t)e0.x*8 + sub];
        float v1 = x[(size_t)e1.x*8 + sub];
        float v2 = x[(size_t)e2.x*8 + sub];
        float v3 = x[(size_t)e3.x*8 + sub];
        acc += v0*__int_as_float(e0.y);
        acc += v1*__int_as_float(e1.y);
        acc += v2*__int_as_float(e2.y);
        acc += v3*__int_as_float(e3.y);
    }
    for (; k < k1; k++){
        int2 e0 = edge_s[k];
        acc += x[(size_t)e0.x*8 + sub]*__int_as_float(e0.y);
    }
    ax[(size_t)g*8 + sub] = acc;
}

// ---------- gcnA1 = relu(aggx @ W1 + b1), fused BN1 stats ----------
__global__ __launch_bounds__(256) void lin1b_stats(
        const float* __restrict__ ax, const float* __restrict__ W1,
        const float* __restrict__ b1, float* __restrict__ out,
        float* __restrict__ gsum, float* __restrict__ gsq){
    __shared__ float Ws[512];
    for (int i = threadIdx.x; i < 512; i += 256) Ws[i] = W1[i];
    __syncthreads();
    int f = threadIdx.x & 63;
    float wc[8];
    #pragma unroll
    for (int q = 0; q < 8; q++) wc[q] = Ws[q*64 + f];
    float bb = b1[f];
    float s = 0.f, s2 = 0.f;
    int stride = gridDim.x*blockDim.x;   // multiple of 64
    for (int idx = blockIdx.x*blockDim.x + threadIdx.x; idx < N_NODES*64; idx += stride){
        int j = idx >> 6;
        const float* ar = ax + (size_t)j*8;
        float acc = bb;
        #pragma unroll
        for (int q = 0; q < 8; q++) acc += ar[q]*wc[q];
        float v = fmaxf(acc, 0.f);
        out[idx] = v;
        s += v; s2 += v*v;
    }
    __shared__ float s1m[256], s2m[256];
    s1m[threadIdx.x] = s; s2m[threadIdx.x] = s2;
    __syncthreads();
    if (threadIdx.x < 64){
        float t1 = s1m[threadIdx.x]+s1m[threadIdx.x+64]+s1m[threadIdx.x+128]+s1m[threadIdx.x+192];
        float t2 = s2m[threadIdx.x]+s2m[threadIdx.x+64]+s2m[threadIdx.x+128]+s2m[threadIdx.x+192];
        atomicAdd(&gsum[threadIdx.x], t1);
        atomicAdd(&gsq[threadIdx.x], t2);
    }
}

// ---------- lin2_bn: h1 = BN(gcnA1); hlinH = pack_f16(h1 @ W2) ----------
#define L2ROWS 128
#define XS2    132
__global__ __launch_bounds__(128) void lin2_bn(
        const float* __restrict__ gcnA, const float* __restrict__ scal,
        const float* __restrict__ shif, const float* __restrict__ W2,
        float* __restrict__ h1_out, float* __restrict__ hlinH){
    __shared__ float Ws[64*64];
    __shared__ float xsT[64*XS2];
    int tid = threadIdx.x;
    int r0 = blockIdx.x * L2ROWS;

    for (int i = tid; i < 1024; i += 128)
        *(float4*)&Ws[i*4] = *(const float4*)&W2[i*4];

    int k4 = tid & 15;
    int rb = tid >> 4;
    float4 sc = *(const float4*)&scal[k4*4];
    float4 sh = *(const float4*)&shif[k4*4];
    for (int it = 0; it < 16; it++){
        int r = it*8 + rb;
        float4 v = *(const float4*)&gcnA[(size_t)(r0+r)*64 + k4*4];
        v.x = v.x*sc.x+sh.x; v.y = v.y*sc.y+sh.y; v.z = v.z*sc.z+sh.z; v.w = v.w*sc.w+sh.w;
        *(float4*)&h1_out[(size_t)(r0+r)*64 + k4*4] = v;
        xsT[(k4*4+0)*XS2 + r] = v.x;
        xsT[(k4*4+1)*XS2 + r] = v.y;
        xsT[(k4*4+2)*XS2 + r] = v.z;
        xsT[(k4*4+3)*XS2 + r] = v.w;
    }
    __syncthreads();

    int cg = tid & 7;
    int rg = tid >> 3;
    float acc[8][8];
    #pragma unroll
    for (int i = 0; i < 8; i++)
        #pragma unroll
        for (int j = 0; j < 8; j++) acc[i][j] = 0.f;

    float4 a0 = *(float4*)&xsT[0*XS2 + rg*8];
    float4 a1 = *(float4*)&xsT[0*XS2 + rg*8 + 4];
    float4 w0 = *(float4*)&Ws[0*64 + cg*8];
    float4 w1 = *(float4*)&Ws[0*64 + cg*8 + 4];
    for (int k = 0; k < 64; k++){
        float4 na0, na1, nw0, nw1;
        if (k < 63){
            na0 = *(float4*)&xsT[(k+1)*XS2 + rg*8];
            na1 = *(float4*)&xsT[(k+1)*XS2 + rg*8 + 4];
            nw0 = *(float4*)&Ws[(k+1)*64 + cg*8];
            nw1 = *(float4*)&Ws[(k+1)*64 + cg*8 + 4];
        }
        float ar[8] = {a0.x,a0.y,a0.z,a0.w,a1.x,a1.y,a1.z,a1.w};
        float wcv[8] = {w0.x,w0.y,w0.z,w0.w,w1.x,w1.y,w1.z,w1.w};
        #pragma unroll
        for (int i = 0; i < 8; i++)
            #pragma unroll
            for (int j = 0; j < 8; j++) acc[i][j] += ar[i]*wcv[j];
        a0=na0; a1=na1; w0=nw0; w1=nw1;
    }
    #pragma unroll
    for (int i = 0; i < 8; i++){
        size_t r = (size_t)(r0 + rg*8 + i);
        float4 pk;
        pk.x = packf16(acc[i][0], acc[i][1]);
        pk.y = packf16(acc[i][2], acc[i][3]);
        pk.z = packf16(acc[i][4], acc[i][5]);
        pk.w = packf16(acc[i][6], acc[i][7]);
        *(float4*)&hlinH[r*32 + cg*4] = pk;
    }
}

// ---------- layer-2 gather over packed f16 rows (128 B/row), fp32 accum ----------
__global__ __launch_bounds__(256) void gather2h(
        const int* __restrict__ offsets, const int2* __restrict__ edge_s,
        const float* __restrict__ dis, const float* __restrict__ hlinH,
        const float* __restrict__ bias, float* __restrict__ outA){
    int j = blockIdx.x*8 + (threadIdx.x >> 5);
    int p = threadIdx.x & 31;
    float d = dis[j];
    float dd = d*d;
    F16x2U u; u.f = hlinH[(size_t)j*32 + p];
    float ax = (float)u.h[0]*dd;
    float ay = (float)u.h[1]*dd;
    int k  = offsets[j];
    int k1 = offsets[j+1];
    for (; k+4 <= k1; k += 4){
        int2 e0 = edge_s[k], e1 = edge_s[k+1], e2 = edge_s[k+2], e3 = edge_s[k+3];
        F16x2U a, b, c, e;
        a.f = hlinH[(size_t)e0.x*32 + p];
        b.f = hlinH[(size_t)e1.x*32 + p];
        c.f = hlinH[(size_t)e2.x*32 + p];
        e.f = hlinH[(size_t)e3.x*32 + p];
        float n0 = __int_as_float(e0.y), n1 = __int_as_float(e1.y);
        float n2 = __int_as_float(e2.y), n3 = __int_as_float(e3.y);
        ax += (float)a.h[0]*n0; ay += (float)a.h[1]*n0;
        ax += (float)b.h[0]*n1; ay += (float)b.h[1]*n1;
        ax += (float)c.h[0]*n2; ay += (float)c.h[1]*n2;
        ax += (float)e.h[0]*n3; ay += (float)e.h[1]*n3;
    }
    for (; k < k1; k++){
        int2 e0 = edge_s[k];
        F16x2U a; a.f = hlinH[(size_t)e0.x*32 + p];
        float n0 = __int_as_float(e0.y);
        ax += (float)a.h[0]*n0; ay += (float)a.h[1]*n0;
    }
    float2 bv = *(const float2*)&bias[2*p];
    float2 ob;
    ob.x = fmaxf(ax + bv.x, 0.f);
    ob.y = fmaxf(ay + bv.y, 0.f);
    *(float2*)&outA[(size_t)j*64 + 2*p] = ob;
}

// ---------- BatchNorm stats / finalize ----------
__global__ void stats_only(const float* __restrict__ a,
                           float* __restrict__ gsum, float* __restrict__ gsq){
    float s = 0.f, s2 = 0.f;
    int stride = gridDim.x*blockDim.x;
    for (int idx = blockIdx.x*blockDim.x + threadIdx.x; idx < N_NODES*64; idx += stride){
        float v = a[idx];
        s += v; s2 += v*v;
    }
    __shared__ float s1m[256], s2m[256];
    s1m[threadIdx.x] = s; s2m[threadIdx.x] = s2;
    __syncthreads();
    if (threadIdx.x < 64){
        float t1 = s1m[threadIdx.x]+s1m[threadIdx.x+64]+s1m[threadIdx.x+128]+s1m[threadIdx.x+192];
        float t2 = s2m[threadIdx.x]+s2m[threadIdx.x+64]+s2m[threadIdx.x+128]+s2m[threadIdx.x+192];
        atomicAdd(&gsum[threadIdx.x], t1);
        atomicAdd(&gsq[threadIdx.x], t2);
    }
}

__global__ void bn_finalize(const float* gsum, const float* gsq, const float* g, const float* be,
                            float* scale, float* shift){
    int f = threadIdx.x;
    if (f < 64){
        float mean = gsum[f] * (1.0f/(float)N_NODES);
        float var  = gsq[f]  * (1.0f/(float)N_NODES) - mean*mean;
        var = fmaxf(var, 0.f);
        float sc = g[f]*rsqrtf(var + BN_EPS);
        scale[f] = sc;
        shift[f] = be[f] - mean*sc;
    }
}

// ---------- LSTM weight prep: B-fragment layout [K/32][256][32] f16 ----------
__global__ void prep_weights(const float* __restrict__ Wih1, const float* __restrict__ Whh1,
                             const float* __restrict__ bih1, const float* __restrict__ bhh1,
                             const float* __restrict__ Wih2, const float* __restrict__ Whh2,
                             const float* __restrict__ bih2, const float* __restrict__ bhh2,
                             _Float16* W1F, _Float16* W2F, float* b1c, float* b2c){
    int idx = blockIdx.x*blockDim.x + threadIdx.x;
    if (idx < 6*256*32){
        int kt = idx >> 13;
        int rem = idx & 8191;
        int n = rem >> 5, kin = rem & 31;
        int k = kt*32 + kin;
        float v = (k < 128) ? Wih1[n*128 + k] : Whh1[n*64 + (k-128)];
        W1F[idx] = (_Float16)v;
    }
    int i2 = idx - 6*256*32;
    if (i2 >= 0 && i2 < 4*256*32){
        int kt = i2 >> 13;
        int rem = i2 & 8191;
        int n = rem >> 5, kin = rem & 31;
        int k = kt*32 + kin;
        float v = (k < 64) ? Wih2[n*64 + k] : Whh2[n*64 + (k-64)];
        W2F[i2] = (_Float16)v;
    }
    int i3 = idx - (6*256*32 + 4*256*32);
    if (i3 >= 0 && i3 < 256) b1c[i3] = bih1[i3] + bhh1[i3];
    int i4 = i3 - 256;
    if (i4 >= 0 && i4 < 256) b2c[i4] = bih2[i4] + bhh2[i4];
}

// ---------- fused 12-step LSTM1+LSTM2, MFMA 16x16x32 f16, single launch ----------
// 64 rows x 256 gate-cols per block (250 blocks, 4 waves). The recurrence for
// rows j0..j0+63 is block-local: c1/c2/h2 live in REGISTERS (owner lane =
// (row,unit) is identical every step); h1(t-1) is written into next step's X1
// region during cell-update-1. Global writes only at t=11 (h1s/h2s for FC).
#define X1S 200   // halves/row, 400 B (2-way bank alias only)
#define X2S 136   // halves/row, 272 B
__global__ __launch_bounds__(256) void lstm_fused(
        const float* __restrict__ h1, const float* __restrict__ g2raw,
        const float* __restrict__ scal2, const float* __restrict__ shif2,
        const _Float16* __restrict__ W1F, const _Float16* __restrict__ W2F,
        const float* __restrict__ b1c, const float* __restrict__ b2c,
        float* __restrict__ h1s, float* __restrict__ h2s){
    __shared__ _Float16 X1h[64*X1S];
    __shared__ _Float16 X2h[64*X2S];
    int tid = threadIdx.x;
    int j0 = blockIdx.x*64;
    int w    = tid >> 6;
    int lane = tid & 63;
    int quad = lane >> 4;
    int l16  = lane & 15;
    int u    = 16*w + l16;

    // per-lane recurrent state: index i = mt*4 + r  ->  rowl = mt*16 + quad*4 + r
    float c1r[16], c2r[16], h2r[16];
    #pragma unroll
    for (int i = 0; i < 16; i++){ c1r[i] = 0.f; c2r[i] = 0.f; h2r[i] = 0.f; }

    float bi1 = b1c[u], bf1 = b1c[64+u], bg1 = b1c[128+u], bo1 = b1c[192+u];
    float bi2 = b2c[u], bf2 = b2c[64+u], bg2 = b2c[128+u], bo2 = b2c[192+u];

    // zero X1h k[128:192) (h1s prev) for t=0
    for (int idx = tid; idx < 1024; idx += 256){
        int c4 = idx & 15, r = idx >> 4;
        *(half4*)&X1h[r*X1S + 128 + c4*4] = (half4){0,0,0,0};
    }

    for (int t = 0; t < T_WIN; t++){
        // ---- stage X1 k[0:64)=h1(gcn1), k[64:128)=BN2(g2raw) from global ----
        for (int idx = tid; idx < 2048; idx += 256){
            int c4 = idx & 15;
            int r  = (idx >> 4) & 63;
            int src= idx >> 10;
            int j = j0 + r;
            int b = j / NN_SZ, n = j - b*NN_SZ;
            size_t rowg = (size_t)((b*T_WIN + t)*NN_SZ + n);
            float4 v;
            if (src == 0){
                v = *(const float4*)&h1[rowg*64 + c4*4];
            } else {
                float4 vr = *(const float4*)&g2raw[rowg*64 + c4*4];
                float4 sc = *(const float4*)&scal2[c4*4];
                float4 sh = *(const float4*)&shif2[c4*4];
                v.x = vr.x*sc.x+sh.x; v.y = vr.y*sc.y+sh.y;
                v.z = vr.z*sc.z+sh.z; v.w = vr.w*sc.w+sh.w;
            }
            half4 hv;
            hv[0] = (_Float16)v.x; hv[1] = (_Float16)v.y;
            hv[2] = (_Float16)v.z; hv[3] = (_Float16)v.w;
            *(half4*)&X1h[r*X1S + src*64 + c4*4] = hv;
        }
        __syncthreads();

        f32x4 acc[4][4];
        #pragma unroll
        for (int g = 0; g < 4; g++)
            #pragma unroll
            for (int mt = 0; mt < 4; mt++) acc[g][mt] = (f32x4){0.f,0.f,0.f,0.f};

        // ---- phase 1: gates1 = X1 @ W1^T, K=192 ----
        #pragma unroll
        for (int kt = 0; kt < 6; kt++){
            half8 a[4], b[4];
            #pragma unroll
            for (int mt = 0; mt < 4; mt++)
                a[mt] = *(const half8*)&X1h[(mt*16 + l16)*X1S + kt*32 + quad*8];
            #pragma unroll
            for (int g = 0; g < 4; g++)
                b[g] = *(const half8*)&W1F[(size_t)(kt*256 + 64*g + 16*w + l16)*32 + quad*8];
            #pragma unroll
            for (int g = 0; g < 4; g++)
                #pragma unroll
                for (int mt = 0; mt < 4; mt++)
                    acc[g][mt] = __builtin_amdgcn_mfma_f32_16x16x32_f16(a[mt], b[g], acc[g][mt], 0, 0, 0);
        }
        __syncthreads();   // X1h reads done -> safe to overwrite X1h[128:192) and X2h

        // ---- cell update 1 (registers) + stage X2 + next-step X1 region ----
        #pragma unroll
        for (int mt = 0; mt < 4; mt++){
            #pragma unroll
            for (int r = 0; r < 4; r++){
                int rowl = mt*16 + quad*4 + r;
                int i = mt*4 + r;
                float gi = acc[0][mt][r] + bi1;
                float gf = acc[1][mt][r] + bf1;
                float gg = acc[2][mt][r] + bg1;
                float go = acc[3][mt][r] + bo1;
                float cn = sigf(gf)*c1r[i] + sigf(gi)*tanhf(gg);
                float hn = sigf(go)*tanhf(cn);
                c1r[i] = cn;
                X2h[rowl*X2S + u]      = (_Float16)hn;
                X2h[rowl*X2S + 64 + u] = (_Float16)h2r[i];
                X1h[rowl*X1S + 128 + u] = (_Float16)hn;   // h1 prev for t+1
                if (t == T_WIN-1) h1s[(size_t)(j0 + rowl)*64 + u] = hn;
            }
        }
        __syncthreads();   // X2h ready

        // ---- phase 2: gates2 = X2 @ W2^T, K=128 ----
        #pragma unroll
        for (int g = 0; g < 4; g++)
            #pragma unroll
            for (int mt = 0; mt < 4; mt++) acc[g][mt] = (f32x4){0.f,0.f,0.f,0.f};
        #pragma unroll
        for (int kt = 0; kt < 4; kt++){
            half8 a[4], b[4];
            #pragma unroll
            for (int mt = 0; mt < 4; mt++)
                a[mt] = *(const half8*)&X2h[(mt*16 + l16)*X2S + kt*32 + quad*8];
            #pragma unroll
            for (int g = 0; g < 4; g++)
                b[g] = *(const half8*)&W2F[(size_t)(kt*256 + 64*g + 16*w + l16)*32 + quad*8];
            #pragma unroll
            for (int g = 0; g < 4; g++)
                #pragma unroll
                for (int mt = 0; mt < 4; mt++)
                    acc[g][mt] = __builtin_amdgcn_mfma_f32_16x16x32_f16(a[mt], b[g], acc[g][mt], 0, 0, 0);
        }

        // ---- cell update 2 (registers) ----
        #pragma unroll
        for (int mt = 0; mt < 4; mt++){
            #pragma unroll
            for (int r = 0; r < 4; r++){
                int rowl = mt*16 + quad*4 + r;
                int i = mt*4 + r;
                float gi = acc[0][mt][r] + bi2;
                float gf = acc[1][mt][r] + bf2;
                float gg = acc[2][mt][r] + bg2;
                float go = acc[3][mt][r] + bo2;
                float cn = sigf(gf)*c2r[i] + sigf(gi)*tanhf(gg);
                float hn = sigf(go)*tanhf(cn);
                c2r[i] = cn;
                h2r[i] = hn;
                if (t == T_WIN-1) h2s[(size_t)(j0 + rowl)*64 + u] = hn;
            }
        }
        // loop-top staging writes X1h[0:128) only; X2h readers all passed the
        // X2h-ready barrier before any wave can reach next staging sync.
    }
}

// ---------- FC head ----------
__global__ __launch_bounds__(256) void fc_head(
        const float* __restrict__ h1s, const float* __restrict__ h2s,
        const float* __restrict__ inner, const float* __restrict__ x,
        const float* __restrict__ fc1_w, const float* __restrict__ fc1_b,
        const float* __restrict__ fc3_w, const float* __restrict__ fc3_b,
        float* __restrict__ out){
    __shared__ float zsm[4][226];
    int wv = threadIdx.x >> 6;
    int f  = threadIdx.x & 63;
    int j  = blockIdx.x*4 + wv;
    int b = j / NN_SZ, n = j - b*NN_SZ;
    for (int k = f; k < 225; k += 64){
        float v;
        if (k < 64)        v = h1s[j*64 + k];
        else if (k < 128)  v = h2s[j*64 + (k-64)];
        else if (k == 128) v = inner[j];
        else {
            int kk = k - 129;
            int w_ = kk >> 3, ff = kk & 7;
            v = x[((b*T_WIN + w_)*NN_SZ + n)*FIN + ff];
        }
        zsm[wv][k] = v;
    }
    __syncthreads();
    float acc = fc1_b[f];
    for (int k = 0; k < 225; k++) acc += zsm[wv][k]*fc1_w[k*64 + f];
    float p = fmaxf(acc, 0.f) * fc3_w[f];
    #pragma unroll
    for (int off = 32; off > 0; off >>= 1) p += __shfl_down(p, off, 64);
    if (f == 0) out[j] = fmaxf(p + fc3_b[0], 0.f);
}

extern "C" void kernel_launch(void* const* d_in, const int* in_sizes, int n_in,
                              void* d_out, int out_size, void* d_ws, size_t ws_size,
                              hipStream_t stream){
    const int*   adj  = (const int*)d_in[0];
    const int*   row  = adj;
    const int*   col  = adj + EDGES;
    const float* aw   = (const float*)d_in[1];
    const float* x    = (const float*)d_in[2];
    const float* inner= (const float*)d_in[3];
    const float* W1   = (const float*)d_in[4];
    const float* b1   = (const float*)d_in[5];
    const float* W2   = (const float*)d_in[6];
    const float* b2   = (const float*)d_in[7];
    const float* g1   = (const float*)d_in[8];
    const float* be1  = (const float*)d_in[9];
    const float* g2   = (const float*)d_in[10];
    const float* be2  = (const float*)d_in[11];
    const float* Wih1 = (const float*)d_in[12];
    const float* Whh1 = (const float*)d_in[13];
    const float* bih1 = (const float*)d_in[14];
    const float* bhh1 = (const float*)d_in[15];
    const float* Wih2 = (const float*)d_in[16];
    const float* Whh2 = (const float*)d_in[17];
    const float* bih2 = (const float*)d_in[18];
    const float* bhh2 = (const float*)d_in[19];
    const float* fc1w = (const float*)d_in[20];
    const float* fc1b = (const float*)d_in[21];
    const float* fc3w = (const float*)d_in[22];
    const float* fc3b = (const float*)d_in[23];
    float* out = (float*)d_out;

    float* ws = (float*)d_ws;
    const size_t NB = (size_t)N_NODES*64;            // 12,288,000 floats
    float* bufX = ws;                                 // hlinH + aggx -> LSTM outs + W
    float* bufY = ws + NB;                            // gcnA1 -> gcnA2 (live through LSTM)
    float* bufZ = ws + 2*NB;                          // h1 = BN1 out (live through LSTM)
    int2*  edge_s  = (int2*)(ws + 3*NB);              // E int2
    float* degdis  = ws + 3*NB + (size_t)2*EDGES;     // N (dis)
    float* gsum    = degdis + N_NODES;
    float* gsq     = gsum + 64;
    float* scal    = gsq + 64;
    float* shif    = scal + 64;
    float* scal2   = shif + 64;
    float* shif2   = scal2 + 64;
    unsigned long long* dc = (unsigned long long*)(shif2 + 64);   // N ull (8B-aligned)
    int* excl    = (int*)(dc + N_NODES);              // N
    int* bsum    = excl + N_NODES;                    // 1024
    int* bscan   = bsum + 1024;                       // 1024
    int* offsets = bscan + 1024;                      // N+2
    int* rank    = offsets + (N_NODES+2);             // E

    // phase-1 aliases in bufX
    float* hlinH = bufX;                              // N*32 packed f16
    float* ax    = bufX + (size_t)N_NODES*32 + 64;    // N*8

    // LSTM-phase aliases into bufX (hlinH/ax dead after gather2h)
    float* h1s = bufX;
    float* h2s = bufX + (size_t)BN_ROWS*64;
    _Float16* W1F = (_Float16*)(bufX + (size_t)4*BN_ROWS*64);   // 6*256*32 halves
    _Float16* W2F = W1F + 6*256*32;                             // 4*256*32 halves
    float* b1c = (float*)(W2F + 4*256*32);
    float* b2c = b1c + 256;

    float* gcnA1 = bufY;
    float* h1    = bufZ;
    float* gcnA2 = bufY;

    // ---- edge preprocessing (rank captured from the packed atomic) ----
    hipMemsetAsync(dc, 0, N_NODES*sizeof(unsigned long long), stream);
    edge_pre <<<(EDGES+255)/256, 256, 0, stream>>>(col, aw, dc, rank);
    scanA    <<<750, 256, 0, stream>>>(dc, excl, bsum);
    scanB    <<<1, 1024, 0, stream>>>(bsum, bscan, 750);
    scanC    <<<750, 256, 0, stream>>>(excl, bscan, dc, degdis, offsets);
    build_csr<<<(EDGES+255)/256, 256, 0, stream>>>(row, col, aw, rank, degdis, offsets, edge_s);

    // ---- GCN layer 1: aggregate in 8-wide space, then transform (+BN1 stats) ----
    aggx_k<<<N_NODES/32, 256, 0, stream>>>(offsets, edge_s, degdis, x, ax);
    hipMemsetAsync(gsum, 0, 128*sizeof(float), stream);
    lin1b_stats<<<1024, 256, 0, stream>>>(ax, W1, b1, gcnA1, gsum, gsq);
    bn_finalize<<<1, 64, 0, stream>>>(gsum, gsq, g1, be1, scal, shif);

    // ---- fused BN1 + layer-2 linear (packed f16 output) ----
    lin2_bn<<<N_NODES/L2ROWS, 128, 0, stream>>>(gcnA1, scal, shif, W2, h1, hlinH);

    // ---- GCN layer 2 (f16 rows, fp32 accumulate) ----
    gather2h<<<N_NODES/8, 256, 0, stream>>>(offsets, edge_s, degdis, hlinH, b2, gcnA2);
    hipMemsetAsync(gsum, 0, 128*sizeof(float), stream);
    stats_only<<<1024, 256, 0, stream>>>(gcnA2, gsum, gsq);
    bn_finalize<<<1, 64, 0, stream>>>(gsum, gsq, g2, be2, scal2, shif2);

    // ---- fused 12-step LSTM (single launch; states in registers) ----
    prep_weights<<<(6*256*32 + 4*256*32 + 512 + 255)/256, 256, 0, stream>>>(
        Wih1, Whh1, bih1, bhh1, Wih2, Whh2, bih2, bhh2, W1F, W2F, b1c, b2c);
    lstm_fused<<<BN_ROWS/64, 256, 0, stream>>>(h1, gcnA2, scal2, shif2,
                                               W1F, W2F, b1c, b2c, h1s, h2s);

    // ---- FC head ----
    fc_head<<<BN_ROWS/4, 256, 0, stream>>>(h1s, h2s, inner, x, fc1w, fc1b, fc3w, fc3b, out);
}

// Round 10
// 613.551 us; speedup vs baseline: 3.4919x; 1.1085x over previous
//
#include <hip/hip_runtime.h>
#include <math.h>

#define N_NODES 192000
#define EDGES   2000000
#define HID     64
#define BN_ROWS 16000   // B*NN
#define T_WIN   12
#define B_SZ    8
#define NN_SZ   2000
#define FIN     8
#define BN_EPS  1e-5f

typedef _Float16 f16x2 __attribute__((ext_vector_type(2)));
typedef _Float16 half4 __attribute__((ext_vector_type(4)));
typedef _Float16 half8 __attribute__((ext_vector_type(8)));
typedef float    f32x4 __attribute__((ext_vector_type(4)));
union F16x2U { float f; f16x2 h; };

__device__ __forceinline__ float sigf(float x){ return 1.0f/(1.0f+expf(-x)); }

// fast sigmoid/tanh: v_exp_f32 + v_rcp_f32 (~1 ulp; f16 inputs dominate error)
__device__ __forceinline__ float frcp(float x){
#if __has_builtin(__builtin_amdgcn_rcpf)
    return __builtin_amdgcn_rcpf(x);
#else
    return 1.0f/x;
#endif
}
__device__ __forceinline__ float fsig(float x){ return frcp(1.0f + __expf(-x)); }
__device__ __forceinline__ float ftanh(float x){ return fmaf(2.0f, fsig(2.0f*x), -1.0f); }

__device__ __forceinline__ float packf16(float a, float b){
    F16x2U u; u.h[0] = (_Float16)a; u.h[1] = (_Float16)b; return u.f;
}

// ---------- edge preprocessing ----------
// Packed (count<<32 | fixed-point degree); the returned old count IS this
// edge's rank within its destination bucket -> no cursor atomics later.
__global__ void edge_pre(const int* __restrict__ col, const float* __restrict__ w,
                         unsigned long long* __restrict__ dc, int* __restrict__ rank){
    int e = blockIdx.x*blockDim.x + threadIdx.x;
    if (e < EDGES){
        int c = col[e];
        unsigned int fx = (unsigned int)(w[e]*16777216.0f + 0.5f);   // w in [0,1)
        unsigned long long old = atomicAdd(&dc[c], (1ULL << 32) | (unsigned long long)fx);
        rank[e] = (int)(old >> 32);
    }
}

__global__ void scanA(const unsigned long long* __restrict__ dc,
                      int* __restrict__ excl, int* __restrict__ bsum){
    __shared__ int sm[256];
    int i = blockIdx.x*256 + threadIdx.x;
    int v = (int)(dc[i] >> 32);
    sm[threadIdx.x] = v;
    __syncthreads();
    #pragma unroll
    for (int off = 1; off < 256; off <<= 1){
        int t = (threadIdx.x >= off) ? sm[threadIdx.x - off] : 0;
        __syncthreads();
        sm[threadIdx.x] += t;
        __syncthreads();
    }
    excl[i] = sm[threadIdx.x] - v;
    if (threadIdx.x == 255) bsum[blockIdx.x] = sm[255];
}

__global__ void scanB(const int* __restrict__ bsum, int* __restrict__ bscan, int nb){
    __shared__ int sm[1024];
    int tid = threadIdx.x;
    int v = (tid < nb) ? bsum[tid] : 0;
    sm[tid] = v;
    __syncthreads();
    #pragma unroll
    for (int off = 1; off < 1024; off <<= 1){
        int t = (tid >= off) ? sm[tid - off] : 0;
        __syncthreads();
        sm[tid] += t;
        __syncthreads();
    }
    bscan[tid] = sm[tid] - v;
}

__global__ void scanC(const int* __restrict__ excl, const int* __restrict__ bscan,
                      const unsigned long long* __restrict__ dc,
                      float* __restrict__ dis, int* __restrict__ offsets){
    int i = blockIdx.x*256 + threadIdx.x;
    offsets[i] = excl[i] + bscan[i >> 8];
    float deg = (float)(unsigned int)(dc[i] & 0xffffffffULL) * (1.0f/16777216.0f);
    dis[i] = rsqrtf(deg + 1.0f);   // + self-loop weight
    if (i == N_NODES-1) offsets[N_NODES] = EDGES;
}

// atomic-free CSR placement: p = offsets[c] + rank[e]
__global__ void build_csr(const int* __restrict__ row, const int* __restrict__ col,
                          const float* __restrict__ w, const int* __restrict__ rank,
                          const float* __restrict__ dis, const int* __restrict__ offsets,
                          int2* __restrict__ edge_s){
    int e = blockIdx.x*blockDim.x + threadIdx.x;
    if (e >= EDGES) return;
    int r = row[e], c = col[e];
    float nr = dis[r]*w[e]*dis[c];
    int p = offsets[c] + rank[e];
    int2 ev; ev.x = r; ev.y = __float_as_int(nr);
    edge_s[p] = ev;
}

// ---------- layer-1 aggregation in 8-wide input space: aggx = A_hat @ x ----------
__global__ __launch_bounds__(256) void aggx_k(
        const int* __restrict__ offsets, const int2* __restrict__ edge_s,
        const float* __restrict__ dis, const float* __restrict__ x,
        float* __restrict__ ax){
    int g   = blockIdx.x*32 + (threadIdx.x >> 3);
    int sub = threadIdx.x & 7;
    float d = dis[g];
    float acc = x[(size_t)g*8 + sub]*d*d;
    int k  = offsets[g];
    int k1 = offsets[g+1];
    for (; k+4 <= k1; k += 4){
        int2 e0 = edge_s[k], e1 = edge_s[k+1], e2 = edge_s[k+2], e3 = edge_s[k+3];
        float v0 = x[(size_t)e0.x*8 + sub];
        float v1 = x[(size_t)e1.x*8 + sub];
        float v2 = x[(size_t)e2.x*8 + sub];
        float v3 = x[(size_t)e3.x*8 + sub];
        acc += v0*__int_as_float(e0.y);
        acc += v1*__int_as_float(e1.y);
        acc += v2*__int_as_float(e2.y);
        acc += v3*__int_as_float(e3.y);
    }
    for (; k < k1; k++){
        int2 e0 = edge_s[k];
        acc += x[(size_t)e0.x*8 + sub]*__int_as_float(e0.y);
    }
    ax[(size_t)g*8 + sub] = acc;
}

// ---------- gcnA1 = relu(aggx @ W1 + b1), fused BN1 stats ----------
__global__ __launch_bounds__(256) void lin1b_stats(
        const float* __restrict__ ax, const float* __restrict__ W1,
        const float* __restrict__ b1, float* __restrict__ out,
        float* __restrict__ gsum, float* __restrict__ gsq){
    __shared__ float Ws[512];
    for (int i = threadIdx.x; i < 512; i += 256) Ws[i] = W1[i];
    __syncthreads();
    int f = threadIdx.x & 63;
    float wc[8];
    #pragma unroll
    for (int q = 0; q < 8; q++) wc[q] = Ws[q*64 + f];
    float bb = b1[f];
    float s = 0.f, s2 = 0.f;
    int stride = gridDim.x*blockDim.x;   // multiple of 64
    for (int idx = blockIdx.x*blockDim.x + threadIdx.x; idx < N_NODES*64; idx += stride){
        int j = idx >> 6;
        const float* ar = ax + (size_t)j*8;
        float acc = bb;
        #pragma unroll
        for (int q = 0; q < 8; q++) acc += ar[q]*wc[q];
        float v = fmaxf(acc, 0.f);
        out[idx] = v;
        s += v; s2 += v*v;
    }
    __shared__ float s1m[256], s2m[256];
    s1m[threadIdx.x] = s; s2m[threadIdx.x] = s2;
    __syncthreads();
    if (threadIdx.x < 64){
        float t1 = s1m[threadIdx.x]+s1m[threadIdx.x+64]+s1m[threadIdx.x+128]+s1m[threadIdx.x+192];
        float t2 = s2m[threadIdx.x]+s2m[threadIdx.x+64]+s2m[threadIdx.x+128]+s2m[threadIdx.x+192];
        atomicAdd(&gsum[threadIdx.x], t1);
        atomicAdd(&gsq[threadIdx.x], t2);
    }
}

// ---------- lin2_bn: h1 = BN(gcnA1); hlinH = pack_f16(h1 @ W2) ----------
#define L2ROWS 128
#define XS2    132
__global__ __launch_bounds__(128) void lin2_bn(
        const float* __restrict__ gcnA, const float* __restrict__ scal,
        const float* __restrict__ shif, const float* __restrict__ W2,
        float* __restrict__ h1_out, float* __restrict__ hlinH){
    __shared__ float Ws[64*64];
    __shared__ float xsT[64*XS2];
    int tid = threadIdx.x;
    int r0 = blockIdx.x * L2ROWS;

    for (int i = tid; i < 1024; i += 128)
        *(float4*)&Ws[i*4] = *(const float4*)&W2[i*4];

    int k4 = tid & 15;
    int rb = tid >> 4;
    float4 sc = *(const float4*)&scal[k4*4];
    float4 sh = *(const float4*)&shif[k4*4];
    for (int it = 0; it < 16; it++){
        int r = it*8 + rb;
        float4 v = *(const float4*)&gcnA[(size_t)(r0+r)*64 + k4*4];
        v.x = v.x*sc.x+sh.x; v.y = v.y*sc.y+sh.y; v.z = v.z*sc.z+sh.z; v.w = v.w*sc.w+sh.w;
        *(float4*)&h1_out[(size_t)(r0+r)*64 + k4*4] = v;
        xsT[(k4*4+0)*XS2 + r] = v.x;
        xsT[(k4*4+1)*XS2 + r] = v.y;
        xsT[(k4*4+2)*XS2 + r] = v.z;
        xsT[(k4*4+3)*XS2 + r] = v.w;
    }
    __syncthreads();

    int cg = tid & 7;
    int rg = tid >> 3;
    float acc[8][8];
    #pragma unroll
    for (int i = 0; i < 8; i++)
        #pragma unroll
        for (int j = 0; j < 8; j++) acc[i][j] = 0.f;

    float4 a0 = *(float4*)&xsT[0*XS2 + rg*8];
    float4 a1 = *(float4*)&xsT[0*XS2 + rg*8 + 4];
    float4 w0 = *(float4*)&Ws[0*64 + cg*8];
    float4 w1 = *(float4*)&Ws[0*64 + cg*8 + 4];
    for (int k = 0; k < 64; k++){
        float4 na0, na1, nw0, nw1;
        if (k < 63){
            na0 = *(float4*)&xsT[(k+1)*XS2 + rg*8];
            na1 = *(float4*)&xsT[(k+1)*XS2 + rg*8 + 4];
            nw0 = *(float4*)&Ws[(k+1)*64 + cg*8];
            nw1 = *(float4*)&Ws[(k+1)*64 + cg*8 + 4];
        }
        float ar[8] = {a0.x,a0.y,a0.z,a0.w,a1.x,a1.y,a1.z,a1.w};
        float wcv[8] = {w0.x,w0.y,w0.z,w0.w,w1.x,w1.y,w1.z,w1.w};
        #pragma unroll
        for (int i = 0; i < 8; i++)
            #pragma unroll
            for (int j = 0; j < 8; j++) acc[i][j] += ar[i]*wcv[j];
        a0=na0; a1=na1; w0=nw0; w1=nw1;
    }
    #pragma unroll
    for (int i = 0; i < 8; i++){
        size_t r = (size_t)(r0 + rg*8 + i);
        float4 pk;
        pk.x = packf16(acc[i][0], acc[i][1]);
        pk.y = packf16(acc[i][2], acc[i][3]);
        pk.z = packf16(acc[i][4], acc[i][5]);
        pk.w = packf16(acc[i][6], acc[i][7]);
        *(float4*)&hlinH[r*32 + cg*4] = pk;
    }
}

// ---------- layer-2 gather over packed f16 rows (128 B/row), fp32 accum ----------
__global__ __launch_bounds__(256) void gather2h(
        const int* __restrict__ offsets, const int2* __restrict__ edge_s,
        const float* __restrict__ dis, const float* __restrict__ hlinH,
        const float* __restrict__ bias, float* __restrict__ outA){
    int j = blockIdx.x*8 + (threadIdx.x >> 5);
    int p = threadIdx.x & 31;
    float d = dis[j];
    float dd = d*d;
    F16x2U u; u.f = hlinH[(size_t)j*32 + p];
    float ax = (float)u.h[0]*dd;
    float ay = (float)u.h[1]*dd;
    int k  = offsets[j];
    int k1 = offsets[j+1];
    for (; k+4 <= k1; k += 4){
        int2 e0 = edge_s[k], e1 = edge_s[k+1], e2 = edge_s[k+2], e3 = edge_s[k+3];
        F16x2U a, b, c, e;
        a.f = hlinH[(size_t)e0.x*32 + p];
        b.f = hlinH[(size_t)e1.x*32 + p];
        c.f = hlinH[(size_t)e2.x*32 + p];
        e.f = hlinH[(size_t)e3.x*32 + p];
        float n0 = __int_as_float(e0.y), n1 = __int_as_float(e1.y);
        float n2 = __int_as_float(e2.y), n3 = __int_as_float(e3.y);
        ax += (float)a.h[0]*n0; ay += (float)a.h[1]*n0;
        ax += (float)b.h[0]*n1; ay += (float)b.h[1]*n1;
        ax += (float)c.h[0]*n2; ay += (float)c.h[1]*n2;
        ax += (float)e.h[0]*n3; ay += (float)e.h[1]*n3;
    }
    for (; k < k1; k++){
        int2 e0 = edge_s[k];
        F16x2U a; a.f = hlinH[(size_t)e0.x*32 + p];
        float n0 = __int_as_float(e0.y);
        ax += (float)a.h[0]*n0; ay += (float)a.h[1]*n0;
    }
    float2 bv = *(const float2*)&bias[2*p];
    float2 ob;
    ob.x = fmaxf(ax + bv.x, 0.f);
    ob.y = fmaxf(ay + bv.y, 0.f);
    *(float2*)&outA[(size_t)j*64 + 2*p] = ob;
}

// ---------- BatchNorm stats / finalize ----------
__global__ void stats_only(const float* __restrict__ a,
                           float* __restrict__ gsum, float* __restrict__ gsq){
    float s = 0.f, s2 = 0.f;
    int stride = gridDim.x*blockDim.x;
    for (int idx = blockIdx.x*blockDim.x + threadIdx.x; idx < N_NODES*64; idx += stride){
        float v = a[idx];
        s += v; s2 += v*v;
    }
    __shared__ float s1m[256], s2m[256];
    s1m[threadIdx.x] = s; s2m[threadIdx.x] = s2;
    __syncthreads();
    if (threadIdx.x < 64){
        float t1 = s1m[threadIdx.x]+s1m[threadIdx.x+64]+s1m[threadIdx.x+128]+s1m[threadIdx.x+192];
        float t2 = s2m[threadIdx.x]+s2m[threadIdx.x+64]+s2m[threadIdx.x+128]+s2m[threadIdx.x+192];
        atomicAdd(&gsum[threadIdx.x], t1);
        atomicAdd(&gsq[threadIdx.x], t2);
    }
}

__global__ void bn_finalize(const float* gsum, const float* gsq, const float* g, const float* be,
                            float* scale, float* shift){
    int f = threadIdx.x;
    if (f < 64){
        float mean = gsum[f] * (1.0f/(float)N_NODES);
        float var  = gsq[f]  * (1.0f/(float)N_NODES) - mean*mean;
        var = fmaxf(var, 0.f);
        float sc = g[f]*rsqrtf(var + BN_EPS);
        scale[f] = sc;
        shift[f] = be[f] - mean*sc;
    }
}

// ---------- LSTM weight prep: B-fragment layout [K/32][256][32] f16 ----------
__global__ void prep_weights(const float* __restrict__ Wih1, const float* __restrict__ Whh1,
                             const float* __restrict__ bih1, const float* __restrict__ bhh1,
                             const float* __restrict__ Wih2, const float* __restrict__ Whh2,
                             const float* __restrict__ bih2, const float* __restrict__ bhh2,
                             _Float16* W1F, _Float16* W2F, float* b1c, float* b2c){
    int idx = blockIdx.x*blockDim.x + threadIdx.x;
    if (idx < 6*256*32){
        int kt = idx >> 13;
        int rem = idx & 8191;
        int n = rem >> 5, kin = rem & 31;
        int k = kt*32 + kin;
        float v = (k < 128) ? Wih1[n*128 + k] : Whh1[n*64 + (k-128)];
        W1F[idx] = (_Float16)v;
    }
    int i2 = idx - 6*256*32;
    if (i2 >= 0 && i2 < 4*256*32){
        int kt = i2 >> 13;
        int rem = i2 & 8191;
        int n = rem >> 5, kin = rem & 31;
        int k = kt*32 + kin;
        float v = (k < 64) ? Wih2[n*64 + k] : Whh2[n*64 + (k-64)];
        W2F[i2] = (_Float16)v;
    }
    int i3 = idx - (6*256*32 + 4*256*32);
    if (i3 >= 0 && i3 < 256) b1c[i3] = bih1[i3] + bhh1[i3];
    int i4 = i3 - 256;
    if (i4 >= 0 && i4 < 256) b2c[i4] = bih2[i4] + bhh2[i4];
}

// ---------- fused 12-step LSTM1+LSTM2, MFMA 16x16x32 f16, single launch ----------
// 32 rows x 256 gate-cols per block (500 blocks, 4 waves) -> 2+ blocks/CU for
// VALU-chain overlap (R9: 250x64 gave 1 block/CU, Occupancy 11%, 191 us).
// States c1/c2/h2 in registers (8/lane); h1(t-1) written into next X1 region.
#define X1S 200   // halves/row, 400 B (2-way bank alias only)
#define X2S 136   // halves/row, 272 B
__global__ __launch_bounds__(256) void lstm_fused(
        const float* __restrict__ h1, const float* __restrict__ g2raw,
        const float* __restrict__ scal2, const float* __restrict__ shif2,
        const _Float16* __restrict__ W1F, const _Float16* __restrict__ W2F,
        const float* __restrict__ b1c, const float* __restrict__ b2c,
        float* __restrict__ h1s, float* __restrict__ h2s){
    __shared__ _Float16 X1h[32*X1S];
    __shared__ _Float16 X2h[32*X2S];
    int tid = threadIdx.x;
    int j0 = blockIdx.x*32;
    int w    = tid >> 6;
    int lane = tid & 63;
    int quad = lane >> 4;
    int l16  = lane & 15;
    int u    = 16*w + l16;

    // per-lane recurrent state: i = mt*4 + r -> rowl = mt*16 + quad*4 + r (rows 0..31)
    float c1r[8], c2r[8], h2r[8];
    #pragma unroll
    for (int i = 0; i < 8; i++){ c1r[i] = 0.f; c2r[i] = 0.f; h2r[i] = 0.f; }

    float bi1 = b1c[u], bf1 = b1c[64+u], bg1 = b1c[128+u], bo1 = b1c[192+u];
    float bi2 = b2c[u], bf2 = b2c[64+u], bg2 = b2c[128+u], bo2 = b2c[192+u];

    // zero X1h k[128:192) (h1s prev) for t=0
    for (int idx = tid; idx < 512; idx += 256){
        int c4 = idx & 15, r = idx >> 4;
        *(half4*)&X1h[r*X1S + 128 + c4*4] = (half4){0,0,0,0};
    }

    for (int t = 0; t < T_WIN; t++){
        // ---- stage X1 k[0:64)=h1(gcn1), k[64:128)=BN2(g2raw) from global ----
        for (int idx = tid; idx < 1024; idx += 256){
            int c4 = idx & 15;
            int r  = (idx >> 4) & 31;
            int src= idx >> 9;
            int j = j0 + r;
            int b = j / NN_SZ, n = j - b*NN_SZ;
            size_t rowg = (size_t)((b*T_WIN + t)*NN_SZ + n);
            float4 v;
            if (src == 0){
                v = *(const float4*)&h1[rowg*64 + c4*4];
            } else {
                float4 vr = *(const float4*)&g2raw[rowg*64 + c4*4];
                float4 sc = *(const float4*)&scal2[c4*4];
                float4 sh = *(const float4*)&shif2[c4*4];
                v.x = vr.x*sc.x+sh.x; v.y = vr.y*sc.y+sh.y;
                v.z = vr.z*sc.z+sh.z; v.w = vr.w*sc.w+sh.w;
            }
            half4 hv;
            hv[0] = (_Float16)v.x; hv[1] = (_Float16)v.y;
            hv[2] = (_Float16)v.z; hv[3] = (_Float16)v.w;
            *(half4*)&X1h[r*X1S + src*64 + c4*4] = hv;
        }
        __syncthreads();

        f32x4 acc[4][2];
        #pragma unroll
        for (int g = 0; g < 4; g++)
            #pragma unroll
            for (int mt = 0; mt < 2; mt++) acc[g][mt] = (f32x4){0.f,0.f,0.f,0.f};

        // ---- phase 1: gates1 = X1 @ W1^T, K=192 ----
        #pragma unroll
        for (int kt = 0; kt < 6; kt++){
            half8 a[2], b[4];
            #pragma unroll
            for (int mt = 0; mt < 2; mt++)
                a[mt] = *(const half8*)&X1h[(mt*16 + l16)*X1S + kt*32 + quad*8];
            #pragma unroll
            for (int g = 0; g < 4; g++)
                b[g] = *(const half8*)&W1F[(size_t)(kt*256 + 64*g + 16*w + l16)*32 + quad*8];
            #pragma unroll
            for (int g = 0; g < 4; g++)
                #pragma unroll
                for (int mt = 0; mt < 2; mt++)
                    acc[g][mt] = __builtin_amdgcn_mfma_f32_16x16x32_f16(a[mt], b[g], acc[g][mt], 0, 0, 0);
        }
        __syncthreads();   // X1h reads done -> safe to overwrite X1h[128:192) and X2h

        // ---- cell update 1 (registers) + stage X2 + next-step X1 region ----
        #pragma unroll
        for (int mt = 0; mt < 2; mt++){
            #pragma unroll
            for (int r = 0; r < 4; r++){
                int rowl = mt*16 + quad*4 + r;
                int i = mt*4 + r;
                float gi = acc[0][mt][r] + bi1;
                float gf = acc[1][mt][r] + bf1;
                float gg = acc[2][mt][r] + bg1;
                float go = acc[3][mt][r] + bo1;
                float cn = fsig(gf)*c1r[i] + fsig(gi)*ftanh(gg);
                float hn = fsig(go)*ftanh(cn);
                c1r[i] = cn;
                X2h[rowl*X2S + u]      = (_Float16)hn;
                X2h[rowl*X2S + 64 + u] = (_Float16)h2r[i];
                X1h[rowl*X1S + 128 + u] = (_Float16)hn;   // h1 prev for t+1
                if (t == T_WIN-1) h1s[(size_t)(j0 + rowl)*64 + u] = hn;
            }
        }
        __syncthreads();   // X2h ready

        // ---- phase 2: gates2 = X2 @ W2^T, K=128 ----
        #pragma unroll
        for (int g = 0; g < 4; g++)
            #pragma unroll
            for (int mt = 0; mt < 2; mt++) acc[g][mt] = (f32x4){0.f,0.f,0.f,0.f};
        #pragma unroll
        for (int kt = 0; kt < 4; kt++){
            half8 a[2], b[4];
            #pragma unroll
            for (int mt = 0; mt < 2; mt++)
                a[mt] = *(const half8*)&X2h[(mt*16 + l16)*X2S + kt*32 + quad*8];
            #pragma unroll
            for (int g = 0; g < 4; g++)
                b[g] = *(const half8*)&W2F[(size_t)(kt*256 + 64*g + 16*w + l16)*32 + quad*8];
            #pragma unroll
            for (int g = 0; g < 4; g++)
                #pragma unroll
                for (int mt = 0; mt < 2; mt++)
                    acc[g][mt] = __builtin_amdgcn_mfma_f32_16x16x32_f16(a[mt], b[g], acc[g][mt], 0, 0, 0);
        }

        // ---- cell update 2 (registers) ----
        #pragma unroll
        for (int mt = 0; mt < 2; mt++){
            #pragma unroll
            for (int r = 0; r < 4; r++){
                int rowl = mt*16 + quad*4 + r;
                int i = mt*4 + r;
                float gi = acc[0][mt][r] + bi2;
                float gf = acc[1][mt][r] + bf2;
                float gg = acc[2][mt][r] + bg2;
                float go = acc[3][mt][r] + bo2;
                float cn = fsig(gf)*c2r[i] + fsig(gi)*ftanh(gg);
                float hn = fsig(go)*ftanh(cn);
                c2r[i] = cn;
                h2r[i] = hn;
                if (t == T_WIN-1) h2s[(size_t)(j0 + rowl)*64 + u] = hn;
            }
        }
    }
}

// ---------- FC head ----------
__global__ __launch_bounds__(256) void fc_head(
        const float* __restrict__ h1s, const float* __restrict__ h2s,
        const float* __restrict__ inner, const float* __restrict__ x,
        const float* __restrict__ fc1_w, const float* __restrict__ fc1_b,
        const float* __restrict__ fc3_w, const float* __restrict__ fc3_b,
        float* __restrict__ out){
    __shared__ float zsm[4][226];
    int wv = threadIdx.x >> 6;
    int f  = threadIdx.x & 63;
    int j  = blockIdx.x*4 + wv;
    int b = j / NN_SZ, n = j - b*NN_SZ;
    for (int k = f; k < 225; k += 64){
        float v;
        if (k < 64)        v = h1s[j*64 + k];
        else if (k < 128)  v = h2s[j*64 + (k-64)];
        else if (k == 128) v = inner[j];
        else {
            int kk = k - 129;
            int w_ = kk >> 3, ff = kk & 7;
            v = x[((b*T_WIN + w_)*NN_SZ + n)*FIN + ff];
        }
        zsm[wv][k] = v;
    }
    __syncthreads();
    float acc = fc1_b[f];
    for (int k = 0; k < 225; k++) acc += zsm[wv][k]*fc1_w[k*64 + f];
    float p = fmaxf(acc, 0.f) * fc3_w[f];
    #pragma unroll
    for (int off = 32; off > 0; off >>= 1) p += __shfl_down(p, off, 64);
    if (f == 0) out[j] = fmaxf(p + fc3_b[0], 0.f);
}

extern "C" void kernel_launch(void* const* d_in, const int* in_sizes, int n_in,
                              void* d_out, int out_size, void* d_ws, size_t ws_size,
                              hipStream_t stream){
    const int*   adj  = (const int*)d_in[0];
    const int*   row  = adj;
    const int*   col  = adj + EDGES;
    const float* aw   = (const float*)d_in[1];
    const float* x    = (const float*)d_in[2];
    const float* inner= (const float*)d_in[3];
    const float* W1   = (const float*)d_in[4];
    const float* b1   = (const float*)d_in[5];
    const float* W2   = (const float*)d_in[6];
    const float* b2   = (const float*)d_in[7];
    const float* g1   = (const float*)d_in[8];
    const float* be1  = (const float*)d_in[9];
    const float* g2   = (const float*)d_in[10];
    const float* be2  = (const float*)d_in[11];
    const float* Wih1 = (const float*)d_in[12];
    const float* Whh1 = (const float*)d_in[13];
    const float* bih1 = (const float*)d_in[14];
    const float* bhh1 = (const float*)d_in[15];
    const float* Wih2 = (const float*)d_in[16];
    const float* Whh2 = (const float*)d_in[17];
    const float* bih2 = (const float*)d_in[18];
    const float* bhh2 = (const float*)d_in[19];
    const float* fc1w = (const float*)d_in[20];
    const float* fc1b = (const float*)d_in[21];
    const float* fc3w = (const float*)d_in[22];
    const float* fc3b = (const float*)d_in[23];
    float* out = (float*)d_out;

    float* ws = (float*)d_ws;
    const size_t NB = (size_t)N_NODES*64;            // 12,288,000 floats
    float* bufX = ws;                                 // hlinH + aggx -> LSTM outs + W
    float* bufY = ws + NB;                            // gcnA1 -> gcnA2 (live through LSTM)
    float* bufZ = ws + 2*NB;                          // h1 = BN1 out (live through LSTM)
    int2*  edge_s  = (int2*)(ws + 3*NB);              // E int2
    float* degdis  = ws + 3*NB + (size_t)2*EDGES;     // N (dis)
    float* gsum    = degdis + N_NODES;
    float* gsq     = gsum + 64;
    float* scal    = gsq + 64;
    float* shif    = scal + 64;
    float* scal2   = shif + 64;
    float* shif2   = scal2 + 64;
    unsigned long long* dc = (unsigned long long*)(shif2 + 64);   // N ull (8B-aligned)
    int* excl    = (int*)(dc + N_NODES);              // N
    int* bsum    = excl + N_NODES;                    // 1024
    int* bscan   = bsum + 1024;                       // 1024
    int* offsets = bscan + 1024;                      // N+2
    int* rank    = offsets + (N_NODES+2);             // E

    // phase-1 aliases in bufX
    float* hlinH = bufX;                              // N*32 packed f16
    float* ax    = bufX + (size_t)N_NODES*32 + 64;    // N*8

    // LSTM-phase aliases into bufX (hlinH/ax dead after gather2h)
    float* h1s = bufX;
    float* h2s = bufX + (size_t)BN_ROWS*64;
    _Float16* W1F = (_Float16*)(bufX + (size_t)4*BN_ROWS*64);   // 6*256*32 halves
    _Float16* W2F = W1F + 6*256*32;                             // 4*256*32 halves
    float* b1c = (float*)(W2F + 4*256*32);
    float* b2c = b1c + 256;

    float* gcnA1 = bufY;
    float* h1    = bufZ;
    float* gcnA2 = bufY;

    // ---- edge preprocessing (rank captured from the packed atomic) ----
    hipMemsetAsync(dc, 0, N_NODES*sizeof(unsigned long long), stream);
    edge_pre <<<(EDGES+255)/256, 256, 0, stream>>>(col, aw, dc, rank);
    scanA    <<<750, 256, 0, stream>>>(dc, excl, bsum);
    scanB    <<<1, 1024, 0, stream>>>(bsum, bscan, 750);
    scanC    <<<750, 256, 0, stream>>>(excl, bscan, dc, degdis, offsets);
    build_csr<<<(EDGES+255)/256, 256, 0, stream>>>(row, col, aw, rank, degdis, offsets, edge_s);

    // ---- GCN layer 1: aggregate in 8-wide space, then transform (+BN1 stats) ----
    aggx_k<<<N_NODES/32, 256, 0, stream>>>(offsets, edge_s, degdis, x, ax);
    hipMemsetAsync(gsum, 0, 128*sizeof(float), stream);
    lin1b_stats<<<1024, 256, 0, stream>>>(ax, W1, b1, gcnA1, gsum, gsq);
    bn_finalize<<<1, 64, 0, stream>>>(gsum, gsq, g1, be1, scal, shif);

    // ---- fused BN1 + layer-2 linear (packed f16 output) ----
    lin2_bn<<<N_NODES/L2ROWS, 128, 0, stream>>>(gcnA1, scal, shif, W2, h1, hlinH);

    // ---- GCN layer 2 (f16 rows, fp32 accumulate) ----
    gather2h<<<N_NODES/8, 256, 0, stream>>>(offsets, edge_s, degdis, hlinH, b2, gcnA2);
    hipMemsetAsync(gsum, 0, 128*sizeof(float), stream);
    stats_only<<<1024, 256, 0, stream>>>(gcnA2, gsum, gsq);
    bn_finalize<<<1, 64, 0, stream>>>(gsum, gsq, g2, be2, scal2, shif2);

    // ---- fused 12-step LSTM (single launch; states in registers) ----
    prep_weights<<<(6*256*32 + 4*256*32 + 512 + 255)/256, 256, 0, stream>>>(
        Wih1, Whh1, bih1, bhh1, Wih2, Whh2, bih2, bhh2, W1F, W2F, b1c, b2c);
    lstm_fused<<<BN_ROWS/32, 256, 0, stream>>>(h1, gcnA2, scal2, shif2,
                                               W1F, W2F, b1c, b2c, h1s, h2s);

    // ---- FC head ----
    fc_head<<<BN_ROWS/4, 256, 0, stream>>>(h1s, h2s, inner, x, fc1w, fc1b, fc3w, fc3b, out);
}

// Round 11
// 610.136 us; speedup vs baseline: 3.5114x; 1.0056x over previous
//
#include <hip/hip_runtime.h>
#include <math.h>

#define N_NODES 192000
#define EDGES   2000000
#define HID     64
#define BN_ROWS 16000   // B*NN
#define T_WIN   12
#define B_SZ    8
#define NN_SZ   2000
#define FIN     8
#define BN_EPS  1e-5f

typedef _Float16 f16x2 __attribute__((ext_vector_type(2)));
typedef _Float16 half4 __attribute__((ext_vector_type(4)));
typedef _Float16 half8 __attribute__((ext_vector_type(8)));
typedef float    f32x4 __attribute__((ext_vector_type(4)));
union F16x2U { float f; f16x2 h; };

// fast sigmoid/tanh: v_exp_f32 + v_rcp_f32 (~1 ulp; f16 inputs dominate error)
__device__ __forceinline__ float frcp(float x){
#if __has_builtin(__builtin_amdgcn_rcpf)
    return __builtin_amdgcn_rcpf(x);
#else
    return 1.0f/x;
#endif
}
__device__ __forceinline__ float fsig(float x){ return frcp(1.0f + __expf(-x)); }
__device__ __forceinline__ float ftanh(float x){ return fmaf(2.0f, fsig(2.0f*x), -1.0f); }

__device__ __forceinline__ float packf16(float a, float b){
    F16x2U u; u.h[0] = (_Float16)a; u.h[1] = (_Float16)b; return u.f;
}
__device__ __forceinline__ half4 cvt4(float4 v){
    half4 h; h[0]=(_Float16)v.x; h[1]=(_Float16)v.y; h[2]=(_Float16)v.z; h[3]=(_Float16)v.w; return h;
}

// ---------- edge preprocessing ----------
// Packed (count<<32 | fixed-point degree); the returned old count IS this
// edge's rank within its destination bucket -> no cursor atomics later.
__global__ void edge_pre(const int* __restrict__ col, const float* __restrict__ w,
                         unsigned long long* __restrict__ dc, int* __restrict__ rank){
    int e = blockIdx.x*blockDim.x + threadIdx.x;
    if (e < EDGES){
        int c = col[e];
        unsigned int fx = (unsigned int)(w[e]*16777216.0f + 0.5f);   // w in [0,1)
        unsigned long long old = atomicAdd(&dc[c], (1ULL << 32) | (unsigned long long)fx);
        rank[e] = (int)(old >> 32);
    }
}

__global__ void scanA(const unsigned long long* __restrict__ dc,
                      int* __restrict__ excl, int* __restrict__ bsum){
    __shared__ int sm[256];
    int i = blockIdx.x*256 + threadIdx.x;
    int v = (int)(dc[i] >> 32);
    sm[threadIdx.x] = v;
    __syncthreads();
    #pragma unroll
    for (int off = 1; off < 256; off <<= 1){
        int t = (threadIdx.x >= off) ? sm[threadIdx.x - off] : 0;
        __syncthreads();
        sm[threadIdx.x] += t;
        __syncthreads();
    }
    excl[i] = sm[threadIdx.x] - v;
    if (threadIdx.x == 255) bsum[blockIdx.x] = sm[255];
}

__global__ void scanB(const int* __restrict__ bsum, int* __restrict__ bscan, int nb){
    __shared__ int sm[1024];
    int tid = threadIdx.x;
    int v = (tid < nb) ? bsum[tid] : 0;
    sm[tid] = v;
    __syncthreads();
    #pragma unroll
    for (int off = 1; off < 1024; off <<= 1){
        int t = (tid >= off) ? sm[tid - off] : 0;
        __syncthreads();
        sm[tid] += t;
        __syncthreads();
    }
    bscan[tid] = sm[tid] - v;
}

__global__ void scanC(const int* __restrict__ excl, const int* __restrict__ bscan,
                      const unsigned long long* __restrict__ dc,
                      float* __restrict__ dis, int* __restrict__ offsets){
    int i = blockIdx.x*256 + threadIdx.x;
    offsets[i] = excl[i] + bscan[i >> 8];
    float deg = (float)(unsigned int)(dc[i] & 0xffffffffULL) * (1.0f/16777216.0f);
    dis[i] = rsqrtf(deg + 1.0f);   // + self-loop weight
    if (i == N_NODES-1) offsets[N_NODES] = EDGES;
}

// atomic-free CSR placement: p = offsets[c] + rank[e]
__global__ void build_csr(const int* __restrict__ row, const int* __restrict__ col,
                          const float* __restrict__ w, const int* __restrict__ rank,
                          const float* __restrict__ dis, const int* __restrict__ offsets,
                          int2* __restrict__ edge_s){
    int e = blockIdx.x*blockDim.x + threadIdx.x;
    if (e >= EDGES) return;
    int r = row[e], c = col[e];
    float nr = dis[r]*w[e]*dis[c];
    int p = offsets[c] + rank[e];
    int2 ev; ev.x = r; ev.y = __float_as_int(nr);
    edge_s[p] = ev;
}

// ---------- layer-1 aggregation in 8-wide input space: aggx = A_hat @ x ----------
__global__ __launch_bounds__(256) void aggx_k(
        const int* __restrict__ offsets, const int2* __restrict__ edge_s,
        const float* __restrict__ dis, const float* __restrict__ x,
        float* __restrict__ ax){
    int g   = blockIdx.x*32 + (threadIdx.x >> 3);
    int sub = threadIdx.x & 7;
    float d = dis[g];
    float acc = x[(size_t)g*8 + sub]*d*d;
    int k  = offsets[g];
    int k1 = offsets[g+1];
    for (; k+4 <= k1; k += 4){
        int2 e0 = edge_s[k], e1 = edge_s[k+1], e2 = edge_s[k+2], e3 = edge_s[k+3];
        float v0 = x[(size_t)e0.x*8 + sub];
        float v1 = x[(size_t)e1.x*8 + sub];
        float v2 = x[(size_t)e2.x*8 + sub];
        float v3 = x[(size_t)e3.x*8 + sub];
        acc += v0*__int_as_float(e0.y);
        acc += v1*__int_as_float(e1.y);
        acc += v2*__int_as_float(e2.y);
        acc += v3*__int_as_float(e3.y);
    }
    for (; k < k1; k++){
        int2 e0 = edge_s[k];
        acc += x[(size_t)e0.x*8 + sub]*__int_as_float(e0.y);
    }
    ax[(size_t)g*8 + sub] = acc;
}

// ---------- gcnA1 = relu(aggx @ W1 + b1), fused BN1 stats ----------
__global__ __launch_bounds__(256) void lin1b_stats(
        const float* __restrict__ ax, const float* __restrict__ W1,
        const float* __restrict__ b1, float* __restrict__ out,
        float* __restrict__ gsum, float* __restrict__ gsq){
    __shared__ float Ws[512];
    for (int i = threadIdx.x; i < 512; i += 256) Ws[i] = W1[i];
    __syncthreads();
    int f = threadIdx.x & 63;
    float wc[8];
    #pragma unroll
    for (int q = 0; q < 8; q++) wc[q] = Ws[q*64 + f];
    float bb = b1[f];
    float s = 0.f, s2 = 0.f;
    int stride = gridDim.x*blockDim.x;   // multiple of 64
    for (int idx = blockIdx.x*blockDim.x + threadIdx.x; idx < N_NODES*64; idx += stride){
        int j = idx >> 6;
        const float* ar = ax + (size_t)j*8;
        float acc = bb;
        #pragma unroll
        for (int q = 0; q < 8; q++) acc += ar[q]*wc[q];
        float v = fmaxf(acc, 0.f);
        out[idx] = v;
        s += v; s2 += v*v;
    }
    __shared__ float s1m[256], s2m[256];
    s1m[threadIdx.x] = s; s2m[threadIdx.x] = s2;
    __syncthreads();
    if (threadIdx.x < 64){
        float t1 = s1m[threadIdx.x]+s1m[threadIdx.x+64]+s1m[threadIdx.x+128]+s1m[threadIdx.x+192];
        float t2 = s2m[threadIdx.x]+s2m[threadIdx.x+64]+s2m[threadIdx.x+128]+s2m[threadIdx.x+192];
        atomicAdd(&gsum[threadIdx.x], t1);
        atomicAdd(&gsq[threadIdx.x], t2);
    }
}

// ---------- lin2_bn: h1 = BN(gcnA1); hlinH = pack_f16(h1 @ W2) ----------
#define L2ROWS 128
#define XS2    132
__global__ __launch_bounds__(128) void lin2_bn(
        const float* __restrict__ gcnA, const float* __restrict__ scal,
        const float* __restrict__ shif, const float* __restrict__ W2,
        float* __restrict__ h1_out, float* __restrict__ hlinH){
    __shared__ float Ws[64*64];
    __shared__ float xsT[64*XS2];
    int tid = threadIdx.x;
    int r0 = blockIdx.x * L2ROWS;

    for (int i = tid; i < 1024; i += 128)
        *(float4*)&Ws[i*4] = *(const float4*)&W2[i*4];

    int k4 = tid & 15;
    int rb = tid >> 4;
    float4 sc = *(const float4*)&scal[k4*4];
    float4 sh = *(const float4*)&shif[k4*4];
    for (int it = 0; it < 16; it++){
        int r = it*8 + rb;
        float4 v = *(const float4*)&gcnA[(size_t)(r0+r)*64 + k4*4];
        v.x = v.x*sc.x+sh.x; v.y = v.y*sc.y+sh.y; v.z = v.z*sc.z+sh.z; v.w = v.w*sc.w+sh.w;
        *(float4*)&h1_out[(size_t)(r0+r)*64 + k4*4] = v;
        xsT[(k4*4+0)*XS2 + r] = v.x;
        xsT[(k4*4+1)*XS2 + r] = v.y;
        xsT[(k4*4+2)*XS2 + r] = v.z;
        xsT[(k4*4+3)*XS2 + r] = v.w;
    }
    __syncthreads();

    int cg = tid & 7;
    int rg = tid >> 3;
    float acc[8][8];
    #pragma unroll
    for (int i = 0; i < 8; i++)
        #pragma unroll
        for (int j = 0; j < 8; j++) acc[i][j] = 0.f;

    float4 a0 = *(float4*)&xsT[0*XS2 + rg*8];
    float4 a1 = *(float4*)&xsT[0*XS2 + rg*8 + 4];
    float4 w0 = *(float4*)&Ws[0*64 + cg*8];
    float4 w1 = *(float4*)&Ws[0*64 + cg*8 + 4];
    for (int k = 0; k < 64; k++){
        float4 na0, na1, nw0, nw1;
        if (k < 63){
            na0 = *(float4*)&xsT[(k+1)*XS2 + rg*8];
            na1 = *(float4*)&xsT[(k+1)*XS2 + rg*8 + 4];
            nw0 = *(float4*)&Ws[(k+1)*64 + cg*8];
            nw1 = *(float4*)&Ws[(k+1)*64 + cg*8 + 4];
        }
        float ar[8] = {a0.x,a0.y,a0.z,a0.w,a1.x,a1.y,a1.z,a1.w};
        float wcv[8] = {w0.x,w0.y,w0.z,w0.w,w1.x,w1.y,w1.z,w1.w};
        #pragma unroll
        for (int i = 0; i < 8; i++)
            #pragma unroll
            for (int j = 0; j < 8; j++) acc[i][j] += ar[i]*wcv[j];
        a0=na0; a1=na1; w0=nw0; w1=nw1;
    }
    #pragma unroll
    for (int i = 0; i < 8; i++){
        size_t r = (size_t)(r0 + rg*8 + i);
        float4 pk;
        pk.x = packf16(acc[i][0], acc[i][1]);
        pk.y = packf16(acc[i][2], acc[i][3]);
        pk.z = packf16(acc[i][4], acc[i][5]);
        pk.w = packf16(acc[i][6], acc[i][7]);
        *(float4*)&hlinH[r*32 + cg*4] = pk;
    }
}

// ---------- layer-2 gather over packed f16 rows (128 B/row), fp32 accum ----------
__global__ __launch_bounds__(256) void gather2h(
        const int* __restrict__ offsets, const int2* __restrict__ edge_s,
        const float* __restrict__ dis, const float* __restrict__ hlinH,
        const float* __restrict__ bias, float* __restrict__ outA){
    int j = blockIdx.x*8 + (threadIdx.x >> 5);
    int p = threadIdx.x & 31;
    float d = dis[j];
    float dd = d*d;
    F16x2U u; u.f = hlinH[(size_t)j*32 + p];
    float ax = (float)u.h[0]*dd;
    float ay = (float)u.h[1]*dd;
    int k  = offsets[j];
    int k1 = offsets[j+1];
    for (; k+4 <= k1; k += 4){
        int2 e0 = edge_s[k], e1 = edge_s[k+1], e2 = edge_s[k+2], e3 = edge_s[k+3];
        F16x2U a, b, c, e;
        a.f = hlinH[(size_t)e0.x*32 + p];
        b.f = hlinH[(size_t)e1.x*32 + p];
        c.f = hlinH[(size_t)e2.x*32 + p];
        e.f = hlinH[(size_t)e3.x*32 + p];
        float n0 = __int_as_float(e0.y), n1 = __int_as_float(e1.y);
        float n2 = __int_as_float(e2.y), n3 = __int_as_float(e3.y);
        ax += (float)a.h[0]*n0; ay += (float)a.h[1]*n0;
        ax += (float)b.h[0]*n1; ay += (float)b.h[1]*n1;
        ax += (float)c.h[0]*n2; ay += (float)c.h[1]*n2;
        ax += (float)e.h[0]*n3; ay += (float)e.h[1]*n3;
    }
    for (; k < k1; k++){
        int2 e0 = edge_s[k];
        F16x2U a; a.f = hlinH[(size_t)e0.x*32 + p];
        float n0 = __int_as_float(e0.y);
        ax += (float)a.h[0]*n0; ay += (float)a.h[1]*n0;
    }
    float2 bv = *(const float2*)&bias[2*p];
    float2 ob;
    ob.x = fmaxf(ax + bv.x, 0.f);
    ob.y = fmaxf(ay + bv.y, 0.f);
    *(float2*)&outA[(size_t)j*64 + 2*p] = ob;
}

// ---------- BatchNorm stats / finalize ----------
__global__ void stats_only(const float* __restrict__ a,
                           float* __restrict__ gsum, float* __restrict__ gsq){
    float s = 0.f, s2 = 0.f;
    int stride = gridDim.x*blockDim.x;
    for (int idx = blockIdx.x*blockDim.x + threadIdx.x; idx < N_NODES*64; idx += stride){
        float v = a[idx];
        s += v; s2 += v*v;
    }
    __shared__ float s1m[256], s2m[256];
    s1m[threadIdx.x] = s; s2m[threadIdx.x] = s2;
    __syncthreads();
    if (threadIdx.x < 64){
        float t1 = s1m[threadIdx.x]+s1m[threadIdx.x+64]+s1m[threadIdx.x+128]+s1m[threadIdx.x+192];
        float t2 = s2m[threadIdx.x]+s2m[threadIdx.x+64]+s2m[threadIdx.x+128]+s2m[threadIdx.x+192];
        atomicAdd(&gsum[threadIdx.x], t1);
        atomicAdd(&gsq[threadIdx.x], t2);
    }
}

__global__ void bn_finalize(const float* gsum, const float* gsq, const float* g, const float* be,
                            float* scale, float* shift){
    int f = threadIdx.x;
    if (f < 64){
        float mean = gsum[f] * (1.0f/(float)N_NODES);
        float var  = gsq[f]  * (1.0f/(float)N_NODES) - mean*mean;
        var = fmaxf(var, 0.f);
        float sc = g[f]*rsqrtf(var + BN_EPS);
        scale[f] = sc;
        shift[f] = be[f] - mean*sc;
    }
}

// ---------- LSTM weight prep: B-fragment layout [K/32][256][32] f16 ----------
__global__ void prep_weights(const float* __restrict__ Wih1, const float* __restrict__ Whh1,
                             const float* __restrict__ bih1, const float* __restrict__ bhh1,
                             const float* __restrict__ Wih2, const float* __restrict__ Whh2,
                             const float* __restrict__ bih2, const float* __restrict__ bhh2,
                             _Float16* W1F, _Float16* W2F, float* b1c, float* b2c){
    int idx = blockIdx.x*blockDim.x + threadIdx.x;
    if (idx < 6*256*32){
        int kt = idx >> 13;
        int rem = idx & 8191;
        int n = rem >> 5, kin = rem & 31;
        int k = kt*32 + kin;
        float v = (k < 128) ? Wih1[n*128 + k] : Whh1[n*64 + (k-128)];
        W1F[idx] = (_Float16)v;
    }
    int i2 = idx - 6*256*32;
    if (i2 >= 0 && i2 < 4*256*32){
        int kt = i2 >> 13;
        int rem = i2 & 8191;
        int n = rem >> 5, kin = rem & 31;
        int k = kt*32 + kin;
        float v = (k < 64) ? Wih2[n*64 + k] : Whh2[n*64 + (k-64)];
        W2F[i2] = (_Float16)v;
    }
    int i3 = idx - (6*256*32 + 4*256*32);
    if (i3 >= 0 && i3 < 256) b1c[i3] = bih1[i3] + bhh1[i3];
    int i4 = i3 - 256;
    if (i4 >= 0 && i4 < 256) b2c[i4] = bih2[i4] + bhh2[i4];
}

// ---------- fused 12-step LSTM1+LSTM2, MFMA 16x16x32 f16, single launch ----------
// 16 rows x 256 gate-cols per block (1000 blocks, 4 waves). R10 was 109 us at
// Occupancy 11% (2 blocks/CU) with 3 barriers/step and unhidden staging loads.
// This version: register-prefetch of t+1 inputs (committed to LDS in the
// cell-1 window), 2 barriers/step, smaller tile -> 3-4 blocks/CU.
#define X1S 200   // halves/row, 400 B
#define X2S 136   // halves/row, 272 B
__global__ __launch_bounds__(256) void lstm_fused(
        const float* __restrict__ h1, const float* __restrict__ g2raw,
        const float* __restrict__ scal2, const float* __restrict__ shif2,
        const _Float16* __restrict__ W1F, const _Float16* __restrict__ W2F,
        const float* __restrict__ b1c, const float* __restrict__ b2c,
        float* __restrict__ h1s, float* __restrict__ h2s){
    __shared__ _Float16 X1h[16*X1S];
    __shared__ _Float16 X2h[16*X2S];
    int tid = threadIdx.x;
    int j0 = blockIdx.x*16;
    int w    = tid >> 6;
    int lane = tid & 63;
    int quad = lane >> 4;
    int l16  = lane & 15;
    int u    = 16*w + l16;

    // staging geometry (fixed per thread): row sr, float4-group c4
    int c4 = tid & 15;
    int sr = (tid >> 4) & 15;
    int sj = j0 + sr;
    int sb = sj / NN_SZ, sn = sj - sb*NN_SZ;
    size_t rbase = ((size_t)(sb*T_WIN)*NN_SZ + sn)*64 + c4*4;   // + t*NN_SZ*64
    float4 sc2v = *(const float4*)&scal2[c4*4];
    float4 sh2v = *(const float4*)&shif2[c4*4];

    // per-lane recurrent state for rows quad*4+r
    float c1r[4], c2r[4], h2r[4];
    #pragma unroll
    for (int i = 0; i < 4; i++){ c1r[i] = 0.f; c2r[i] = 0.f; h2r[i] = 0.f; }

    float bi1 = b1c[u], bf1 = b1c[64+u], bg1 = b1c[128+u], bo1 = b1c[192+u];
    float bi2 = b2c[u], bf2 = b2c[64+u], bg2 = b2c[128+u], bo2 = b2c[192+u];

    // t=0 staging: load, zero h1-prev region, commit
    {
        float4 v0 = *(const float4*)&h1[rbase];
        float4 v1 = *(const float4*)&g2raw[rbase];
        v1.x = v1.x*sc2v.x+sh2v.x; v1.y = v1.y*sc2v.y+sh2v.y;
        v1.z = v1.z*sc2v.z+sh2v.z; v1.w = v1.w*sc2v.w+sh2v.w;
        *(half4*)&X1h[sr*X1S + c4*4]      = cvt4(v0);
        *(half4*)&X1h[sr*X1S + 64 + c4*4] = cvt4(v1);
        *(half4*)&X1h[sr*X1S + 128 + c4*4] = (half4){0,0,0,0};
    }
    __syncthreads();

    for (int t = 0; t < T_WIN; t++){
        // ---- issue t+1 prefetch (latency hidden under phase 1) ----
        float4 nv0, nv1;
        if (t < T_WIN-1){
            size_t rb = rbase + (size_t)(t+1)*NN_SZ*64;
            nv0 = *(const float4*)&h1[rb];
            nv1 = *(const float4*)&g2raw[rb];
        }

        // ---- phase 1: gates1 = X1 @ W1^T, K=192 ----
        f32x4 acc[4];
        #pragma unroll
        for (int g = 0; g < 4; g++) acc[g] = (f32x4){0.f,0.f,0.f,0.f};
        #pragma unroll
        for (int kt = 0; kt < 6; kt++){
            half8 a = *(const half8*)&X1h[l16*X1S + kt*32 + quad*8];
            #pragma unroll
            for (int g = 0; g < 4; g++){
                half8 b = *(const half8*)&W1F[(size_t)(kt*256 + 64*g + u)*32 + quad*8];
                acc[g] = __builtin_amdgcn_mfma_f32_16x16x32_f16(a, b, acc[g], 0, 0, 0);
            }
        }
        __syncthreads();   // B: all X1h/X2h readers done -> write window opens

        // ---- cell update 1 (registers) + stage X2 + commit t+1 X1 ----
        #pragma unroll
        for (int r = 0; r < 4; r++){
            int rowl = quad*4 + r;
            float gi = acc[0][r] + bi1;
            float gf = acc[1][r] + bf1;
            float gg = acc[2][r] + bg1;
            float go = acc[3][r] + bo1;
            float cn = fsig(gf)*c1r[r] + fsig(gi)*ftanh(gg);
            float hn = fsig(go)*ftanh(cn);
            c1r[r] = cn;
            X2h[rowl*X2S + u]      = (_Float16)hn;
            X2h[rowl*X2S + 64 + u] = (_Float16)h2r[r];
            X1h[rowl*X1S + 128 + u] = (_Float16)hn;   // h1 prev for t+1
            if (t == T_WIN-1) h1s[(size_t)(j0 + rowl)*64 + u] = hn;
        }
        if (t < T_WIN-1){
            nv1.x = nv1.x*sc2v.x+sh2v.x; nv1.y = nv1.y*sc2v.y+sh2v.y;
            nv1.z = nv1.z*sc2v.z+sh2v.z; nv1.w = nv1.w*sc2v.w+sh2v.w;
            *(half4*)&X1h[sr*X1S + c4*4]      = cvt4(nv0);
            *(half4*)&X1h[sr*X1S + 64 + c4*4] = cvt4(nv1);
        }
        __syncthreads();   // C: X2h + next X1h ready

        // ---- phase 2: gates2 = X2 @ W2^T, K=128 ----
        f32x4 acc2[4];
        #pragma unroll
        for (int g = 0; g < 4; g++) acc2[g] = (f32x4){0.f,0.f,0.f,0.f};
        #pragma unroll
        for (int kt = 0; kt < 4; kt++){
            half8 a = *(const half8*)&X2h[l16*X2S + kt*32 + quad*8];
            #pragma unroll
            for (int g = 0; g < 4; g++){
                half8 b = *(const half8*)&W2F[(size_t)(kt*256 + 64*g + u)*32 + quad*8];
                acc2[g] = __builtin_amdgcn_mfma_f32_16x16x32_f16(a, b, acc2[g], 0, 0, 0);
            }
        }

        // ---- cell update 2 (registers only) ----
        #pragma unroll
        for (int r = 0; r < 4; r++){
            int rowl = quad*4 + r;
            float gi = acc2[0][r] + bi2;
            float gf = acc2[1][r] + bf2;
            float gg = acc2[2][r] + bg2;
            float go = acc2[3][r] + bo2;
            float cn = fsig(gf)*c2r[r] + fsig(gi)*ftanh(gg);
            float hn = fsig(go)*ftanh(cn);
            c2r[r] = cn;
            h2r[r] = hn;
            if (t == T_WIN-1) h2s[(size_t)(j0 + rowl)*64 + u] = hn;
        }
        // no barrier here: next phase-1 reads X1h written before C; next
        // LDS writes happen only after next B.
    }
}

// ---------- FC head ----------
__global__ __launch_bounds__(256) void fc_head(
        const float* __restrict__ h1s, const float* __restrict__ h2s,
        const float* __restrict__ inner, const float* __restrict__ x,
        const float* __restrict__ fc1_w, const float* __restrict__ fc1_b,
        const float* __restrict__ fc3_w, const float* __restrict__ fc3_b,
        float* __restrict__ out){
    __shared__ float zsm[4][226];
    int wv = threadIdx.x >> 6;
    int f  = threadIdx.x & 63;
    int j  = blockIdx.x*4 + wv;
    int b = j / NN_SZ, n = j - b*NN_SZ;
    for (int k = f; k < 225; k += 64){
        float v;
        if (k < 64)        v = h1s[j*64 + k];
        else if (k < 128)  v = h2s[j*64 + (k-64)];
        else if (k == 128) v = inner[j];
        else {
            int kk = k - 129;
            int w_ = kk >> 3, ff = kk & 7;
            v = x[((b*T_WIN + w_)*NN_SZ + n)*FIN + ff];
        }
        zsm[wv][k] = v;
    }
    __syncthreads();
    float acc = fc1_b[f];
    for (int k = 0; k < 225; k++) acc += zsm[wv][k]*fc1_w[k*64 + f];
    float p = fmaxf(acc, 0.f) * fc3_w[f];
    #pragma unroll
    for (int off = 32; off > 0; off >>= 1) p += __shfl_down(p, off, 64);
    if (f == 0) out[j] = fmaxf(p + fc3_b[0], 0.f);
}

extern "C" void kernel_launch(void* const* d_in, const int* in_sizes, int n_in,
                              void* d_out, int out_size, void* d_ws, size_t ws_size,
                              hipStream_t stream){
    const int*   adj  = (const int*)d_in[0];
    const int*   row  = adj;
    const int*   col  = adj + EDGES;
    const float* aw   = (const float*)d_in[1];
    const float* x    = (const float*)d_in[2];
    const float* inner= (const float*)d_in[3];
    const float* W1   = (const float*)d_in[4];
    const float* b1   = (const float*)d_in[5];
    const float* W2   = (const float*)d_in[6];
    const float* b2   = (const float*)d_in[7];
    const float* g1   = (const float*)d_in[8];
    const float* be1  = (const float*)d_in[9];
    const float* g2   = (const float*)d_in[10];
    const float* be2  = (const float*)d_in[11];
    const float* Wih1 = (const float*)d_in[12];
    const float* Whh1 = (const float*)d_in[13];
    const float* bih1 = (const float*)d_in[14];
    const float* bhh1 = (const float*)d_in[15];
    const float* Wih2 = (const float*)d_in[16];
    const float* Whh2 = (const float*)d_in[17];
    const float* bih2 = (const float*)d_in[18];
    const float* bhh2 = (const float*)d_in[19];
    const float* fc1w = (const float*)d_in[20];
    const float* fc1b = (const float*)d_in[21];
    const float* fc3w = (const float*)d_in[22];
    const float* fc3b = (const float*)d_in[23];
    float* out = (float*)d_out;

    float* ws = (float*)d_ws;
    const size_t NB = (size_t)N_NODES*64;            // 12,288,000 floats
    float* bufX = ws;                                 // hlinH + aggx -> LSTM outs + W
    float* bufY = ws + NB;                            // gcnA1 -> gcnA2 (live through LSTM)
    float* bufZ = ws + 2*NB;                          // h1 = BN1 out (live through LSTM)
    int2*  edge_s  = (int2*)(ws + 3*NB);              // E int2
    float* degdis  = ws + 3*NB + (size_t)2*EDGES;     // N (dis)
    float* gsum    = degdis + N_NODES;
    float* gsq     = gsum + 64;
    float* scal    = gsq + 64;
    float* shif    = scal + 64;
    float* scal2   = shif + 64;
    float* shif2   = scal2 + 64;
    unsigned long long* dc = (unsigned long long*)(shif2 + 64);   // N ull (8B-aligned)
    int* excl    = (int*)(dc + N_NODES);              // N
    int* bsum    = excl + N_NODES;                    // 1024
    int* bscan   = bsum + 1024;                       // 1024
    int* offsets = bscan + 1024;                      // N+2
    int* rank    = offsets + (N_NODES+2);             // E

    // phase-1 aliases in bufX
    float* hlinH = bufX;                              // N*32 packed f16
    float* ax    = bufX + (size_t)N_NODES*32 + 64;    // N*8

    // LSTM-phase aliases into bufX (hlinH/ax dead after gather2h)
    float* h1s = bufX;
    float* h2s = bufX + (size_t)BN_ROWS*64;
    _Float16* W1F = (_Float16*)(bufX + (size_t)4*BN_ROWS*64);   // 6*256*32 halves
    _Float16* W2F = W1F + 6*256*32;                             // 4*256*32 halves
    float* b1c = (float*)(W2F + 4*256*32);
    float* b2c = b1c + 256;

    float* gcnA1 = bufY;
    float* h1    = bufZ;
    float* gcnA2 = bufY;

    // ---- edge preprocessing (rank captured from the packed atomic) ----
    hipMemsetAsync(dc, 0, N_NODES*sizeof(unsigned long long), stream);
    edge_pre <<<(EDGES+255)/256, 256, 0, stream>>>(col, aw, dc, rank);
    scanA    <<<750, 256, 0, stream>>>(dc, excl, bsum);
    scanB    <<<1, 1024, 0, stream>>>(bsum, bscan, 750);
    scanC    <<<750, 256, 0, stream>>>(excl, bscan, dc, degdis, offsets);
    build_csr<<<(EDGES+255)/256, 256, 0, stream>>>(row, col, aw, rank, degdis, offsets, edge_s);

    // ---- GCN layer 1: aggregate in 8-wide space, then transform (+BN1 stats) ----
    aggx_k<<<N_NODES/32, 256, 0, stream>>>(offsets, edge_s, degdis, x, ax);
    hipMemsetAsync(gsum, 0, 128*sizeof(float), stream);
    lin1b_stats<<<1024, 256, 0, stream>>>(ax, W1, b1, gcnA1, gsum, gsq);
    bn_finalize<<<1, 64, 0, stream>>>(gsum, gsq, g1, be1, scal, shif);

    // ---- fused BN1 + layer-2 linear (packed f16 output) ----
    lin2_bn<<<N_NODES/L2ROWS, 128, 0, stream>>>(gcnA1, scal, shif, W2, h1, hlinH);

    // ---- GCN layer 2 (f16 rows, fp32 accumulate) ----
    gather2h<<<N_NODES/8, 256, 0, stream>>>(offsets, edge_s, degdis, hlinH, b2, gcnA2);
    hipMemsetAsync(gsum, 0, 128*sizeof(float), stream);
    stats_only<<<1024, 256, 0, stream>>>(gcnA2, gsum, gsq);
    bn_finalize<<<1, 64, 0, stream>>>(gsum, gsq, g2, be2, scal2, shif2);

    // ---- fused 12-step LSTM (single launch; states in registers) ----
    prep_weights<<<(6*256*32 + 4*256*32 + 512 + 255)/256, 256, 0, stream>>>(
        Wih1, Whh1, bih1, bhh1, Wih2, Whh2, bih2, bhh2, W1F, W2F, b1c, b2c);
    lstm_fused<<<BN_ROWS/16, 256, 0, stream>>>(h1, gcnA2, scal2, shif2,
                                               W1F, W2F, b1c, b2c, h1s, h2s);

    // ---- FC head ----
    fc_head<<<BN_ROWS/4, 256, 0, stream>>>(h1s, h2s, inner, x, fc1w, fc1b, fc3w, fc3b, out);
}

// Round 12
// 594.369 us; speedup vs baseline: 3.6046x; 1.0265x over previous
//
#include <hip/hip_runtime.h>
#include <math.h>

#define N_NODES 192000
#define EDGES   2000000
#define HID     64
#define BN_ROWS 16000   // B*NN
#define T_WIN   12
#define B_SZ    8
#define NN_SZ   2000
#define FIN     8
#define BN_EPS  1e-5f

typedef _Float16 f16x2 __attribute__((ext_vector_type(2)));
typedef _Float16 half4 __attribute__((ext_vector_type(4)));
typedef _Float16 half8 __attribute__((ext_vector_type(8)));
typedef float    f32x4 __attribute__((ext_vector_type(4)));
union F16x2U { float f; f16x2 h; };

// fast sigmoid/tanh: v_exp_f32 + v_rcp_f32 (~1 ulp; f16 inputs dominate error)
__device__ __forceinline__ float frcp(float x){
#if __has_builtin(__builtin_amdgcn_rcpf)
    return __builtin_amdgcn_rcpf(x);
#else
    return 1.0f/x;
#endif
}
__device__ __forceinline__ float fsig(float x){ return frcp(1.0f + __expf(-x)); }
__device__ __forceinline__ float ftanh(float x){ return fmaf(2.0f, fsig(2.0f*x), -1.0f); }

__device__ __forceinline__ float packf16(float a, float b){
    F16x2U u; u.h[0] = (_Float16)a; u.h[1] = (_Float16)b; return u.f;
}

// ---------- edge preprocessing ----------
// Packed (count<<32 | fixed-point degree); the returned old count IS this
// edge's rank within its destination bucket -> no cursor atomics later.
__global__ void edge_pre(const int* __restrict__ col, const float* __restrict__ w,
                         unsigned long long* __restrict__ dc, int* __restrict__ rank){
    int e = blockIdx.x*blockDim.x + threadIdx.x;
    if (e < EDGES){
        int c = col[e];
        unsigned int fx = (unsigned int)(w[e]*16777216.0f + 0.5f);   // w in [0,1)
        unsigned long long old = atomicAdd(&dc[c], (1ULL << 32) | (unsigned long long)fx);
        rank[e] = (int)(old >> 32);
    }
}

__global__ void scanA(const unsigned long long* __restrict__ dc,
                      int* __restrict__ excl, int* __restrict__ bsum){
    __shared__ int sm[256];
    int i = blockIdx.x*256 + threadIdx.x;
    int v = (int)(dc[i] >> 32);
    sm[threadIdx.x] = v;
    __syncthreads();
    #pragma unroll
    for (int off = 1; off < 256; off <<= 1){
        int t = (threadIdx.x >= off) ? sm[threadIdx.x - off] : 0;
        __syncthreads();
        sm[threadIdx.x] += t;
        __syncthreads();
    }
    excl[i] = sm[threadIdx.x] - v;
    if (threadIdx.x == 255) bsum[blockIdx.x] = sm[255];
}

__global__ void scanB(const int* __restrict__ bsum, int* __restrict__ bscan, int nb){
    __shared__ int sm[1024];
    int tid = threadIdx.x;
    int v = (tid < nb) ? bsum[tid] : 0;
    sm[tid] = v;
    __syncthreads();
    #pragma unroll
    for (int off = 1; off < 1024; off <<= 1){
        int t = (tid >= off) ? sm[tid - off] : 0;
        __syncthreads();
        sm[tid] += t;
        __syncthreads();
    }
    bscan[tid] = sm[tid] - v;
}

__global__ void scanC(const int* __restrict__ excl, const int* __restrict__ bscan,
                      const unsigned long long* __restrict__ dc,
                      float* __restrict__ dis, int* __restrict__ offsets){
    int i = blockIdx.x*256 + threadIdx.x;
    offsets[i] = excl[i] + bscan[i >> 8];
    float deg = (float)(unsigned int)(dc[i] & 0xffffffffULL) * (1.0f/16777216.0f);
    dis[i] = rsqrtf(deg + 1.0f);   // + self-loop weight
    if (i == N_NODES-1) offsets[N_NODES] = EDGES;
}

// atomic-free CSR placement: p = offsets[c] + rank[e]
__global__ void build_csr(const int* __restrict__ row, const int* __restrict__ col,
                          const float* __restrict__ w, const int* __restrict__ rank,
                          const float* __restrict__ dis, const int* __restrict__ offsets,
                          int2* __restrict__ edge_s){
    int e = blockIdx.x*blockDim.x + threadIdx.x;
    if (e >= EDGES) return;
    int r = row[e], c = col[e];
    float nr = dis[r]*w[e]*dis[c];
    int p = offsets[c] + rank[e];
    int2 ev; ev.x = r; ev.y = __float_as_int(nr);
    edge_s[p] = ev;
}

// ---------- layer-1 aggregation in 8-wide input space: aggx = A_hat @ x ----------
__global__ __launch_bounds__(256) void aggx_k(
        const int* __restrict__ offsets, const int2* __restrict__ edge_s,
        const float* __restrict__ dis, const float* __restrict__ x,
        float* __restrict__ ax){
    int g   = blockIdx.x*32 + (threadIdx.x >> 3);
    int sub = threadIdx.x & 7;
    float d = dis[g];
    float acc = x[(size_t)g*8 + sub]*d*d;
    int k  = offsets[g];
    int k1 = offsets[g+1];
    for (; k+4 <= k1; k += 4){
        int2 e0 = edge_s[k], e1 = edge_s[k+1], e2 = edge_s[k+2], e3 = edge_s[k+3];
        float v0 = x[(size_t)e0.x*8 + sub];
        float v1 = x[(size_t)e1.x*8 + sub];
        float v2 = x[(size_t)e2.x*8 + sub];
        float v3 = x[(size_t)e3.x*8 + sub];
        acc += v0*__int_as_float(e0.y);
        acc += v1*__int_as_float(e1.y);
        acc += v2*__int_as_float(e2.y);
        acc += v3*__int_as_float(e3.y);
    }
    for (; k < k1; k++){
        int2 e0 = edge_s[k];
        acc += x[(size_t)e0.x*8 + sub]*__int_as_float(e0.y);
    }
    ax[(size_t)g*8 + sub] = acc;
}

// ---------- gcnA1 = relu(aggx @ W1 + b1), fused BN1 stats ----------
__global__ __launch_bounds__(256) void lin1b_stats(
        const float* __restrict__ ax, const float* __restrict__ W1,
        const float* __restrict__ b1, float* __restrict__ out,
        float* __restrict__ gsum, float* __restrict__ gsq){
    __shared__ float Ws[512];
    for (int i = threadIdx.x; i < 512; i += 256) Ws[i] = W1[i];
    __syncthreads();
    int f = threadIdx.x & 63;
    float wc[8];
    #pragma unroll
    for (int q = 0; q < 8; q++) wc[q] = Ws[q*64 + f];
    float bb = b1[f];
    float s = 0.f, s2 = 0.f;
    int stride = gridDim.x*blockDim.x;   // multiple of 64
    for (int idx = blockIdx.x*blockDim.x + threadIdx.x; idx < N_NODES*64; idx += stride){
        int j = idx >> 6;
        const float* ar = ax + (size_t)j*8;
        float acc = bb;
        #pragma unroll
        for (int q = 0; q < 8; q++) acc += ar[q]*wc[q];
        float v = fmaxf(acc, 0.f);
        out[idx] = v;
        s += v; s2 += v*v;
    }
    __shared__ float s1m[256], s2m[256];
    s1m[threadIdx.x] = s; s2m[threadIdx.x] = s2;
    __syncthreads();
    if (threadIdx.x < 64){
        float t1 = s1m[threadIdx.x]+s1m[threadIdx.x+64]+s1m[threadIdx.x+128]+s1m[threadIdx.x+192];
        float t2 = s2m[threadIdx.x]+s2m[threadIdx.x+64]+s2m[threadIdx.x+128]+s2m[threadIdx.x+192];
        atomicAdd(&gsum[threadIdx.x], t1);
        atomicAdd(&gsq[threadIdx.x], t2);
    }
}

// ---------- lin2_bn: h1H = f16(BN(gcnA1)); hlinH = pack_f16(BN(gcnA1) @ W2) ----------
// BN scale/shift computed inline from gsum/gsq (bn_finalize kernel removed).
#define L2ROWS 128
#define XS2    132
__global__ __launch_bounds__(128) void lin2_bn(
        const float* __restrict__ gcnA, const float* __restrict__ gsum,
        const float* __restrict__ gsq, const float* __restrict__ g1,
        const float* __restrict__ be1, const float* __restrict__ W2,
        _Float16* __restrict__ h1H, float* __restrict__ hlinH){
    __shared__ float Ws[64*64];
    __shared__ float xsT[64*XS2];
    int tid = threadIdx.x;
    int r0 = blockIdx.x * L2ROWS;

    for (int i = tid; i < 1024; i += 128)
        *(float4*)&Ws[i*4] = *(const float4*)&W2[i*4];

    int k4 = tid & 15;
    int rb = tid >> 4;
    float scv[4], shv[4];
    #pragma unroll
    for (int q = 0; q < 4; q++){
        int f = k4*4 + q;
        float mean = gsum[f]*(1.0f/(float)N_NODES);
        float var  = fmaxf(gsq[f]*(1.0f/(float)N_NODES) - mean*mean, 0.f);
        float sc_  = g1[f]*rsqrtf(var + BN_EPS);
        scv[q] = sc_; shv[q] = be1[f] - mean*sc_;
    }
    for (int it = 0; it < 16; it++){
        int r = it*8 + rb;
        float4 v = *(const float4*)&gcnA[(size_t)(r0+r)*64 + k4*4];
        v.x = v.x*scv[0]+shv[0]; v.y = v.y*scv[1]+shv[1];
        v.z = v.z*scv[2]+shv[2]; v.w = v.w*scv[3]+shv[3];
        half4 hh;
        hh[0]=(_Float16)v.x; hh[1]=(_Float16)v.y; hh[2]=(_Float16)v.z; hh[3]=(_Float16)v.w;
        *(half4*)&h1H[(size_t)(r0+r)*64 + k4*4] = hh;
        xsT[(k4*4+0)*XS2 + r] = v.x;
        xsT[(k4*4+1)*XS2 + r] = v.y;
        xsT[(k4*4+2)*XS2 + r] = v.z;
        xsT[(k4*4+3)*XS2 + r] = v.w;
    }
    __syncthreads();

    int cg = tid & 7;
    int rg = tid >> 3;
    float acc[8][8];
    #pragma unroll
    for (int i = 0; i < 8; i++)
        #pragma unroll
        for (int j = 0; j < 8; j++) acc[i][j] = 0.f;

    float4 a0 = *(float4*)&xsT[0*XS2 + rg*8];
    float4 a1 = *(float4*)&xsT[0*XS2 + rg*8 + 4];
    float4 w0 = *(float4*)&Ws[0*64 + cg*8];
    float4 w1 = *(float4*)&Ws[0*64 + cg*8 + 4];
    for (int k = 0; k < 64; k++){
        float4 na0, na1, nw0, nw1;
        if (k < 63){
            na0 = *(float4*)&xsT[(k+1)*XS2 + rg*8];
            na1 = *(float4*)&xsT[(k+1)*XS2 + rg*8 + 4];
            nw0 = *(float4*)&Ws[(k+1)*64 + cg*8];
            nw1 = *(float4*)&Ws[(k+1)*64 + cg*8 + 4];
        }
        float ar[8] = {a0.x,a0.y,a0.z,a0.w,a1.x,a1.y,a1.z,a1.w};
        float wcv[8] = {w0.x,w0.y,w0.z,w0.w,w1.x,w1.y,w1.z,w1.w};
        #pragma unroll
        for (int i = 0; i < 8; i++)
            #pragma unroll
            for (int j = 0; j < 8; j++) acc[i][j] += ar[i]*wcv[j];
        a0=na0; a1=na1; w0=nw0; w1=nw1;
    }
    #pragma unroll
    for (int i = 0; i < 8; i++){
        size_t r = (size_t)(r0 + rg*8 + i);
        float4 pk;
        pk.x = packf16(acc[i][0], acc[i][1]);
        pk.y = packf16(acc[i][2], acc[i][3]);
        pk.z = packf16(acc[i][4], acc[i][5]);
        pk.w = packf16(acc[i][6], acc[i][7]);
        *(float4*)&hlinH[r*32 + cg*4] = pk;
    }
}

// ---------- layer-2 gather (f16 rows) + fused BN2 stats + f16 output ----------
// Grid-stride over node groups; per-block LDS reduce -> 128 global atomics.
__global__ __launch_bounds__(256) void gather2h(
        const int* __restrict__ offsets, const int2* __restrict__ edge_s,
        const float* __restrict__ dis, const float* __restrict__ hlinH,
        const float* __restrict__ bias, float* __restrict__ g2Hf,
        float* __restrict__ gsum2, float* __restrict__ gsq2){
    int wv = threadIdx.x >> 5;
    int p  = threadIdx.x & 31;
    float2 bv = *(const float2*)&bias[2*p];
    float s0 = 0.f, s1 = 0.f, q0 = 0.f, q1 = 0.f;
    for (int grp = blockIdx.x; grp < N_NODES/8; grp += gridDim.x){
        int j = grp*8 + wv;
        float d = dis[j];
        float dd = d*d;
        F16x2U u; u.f = hlinH[(size_t)j*32 + p];
        float ax = (float)u.h[0]*dd;
        float ay = (float)u.h[1]*dd;
        int k  = offsets[j];
        int k1 = offsets[j+1];
        for (; k+4 <= k1; k += 4){
            int2 e0 = edge_s[k], e1 = edge_s[k+1], e2 = edge_s[k+2], e3 = edge_s[k+3];
            F16x2U a, b, c, e;
            a.f = hlinH[(size_t)e0.x*32 + p];
            b.f = hlinH[(size_t)e1.x*32 + p];
            c.f = hlinH[(size_t)e2.x*32 + p];
            e.f = hlinH[(size_t)e3.x*32 + p];
            float n0 = __int_as_float(e0.y), n1 = __int_as_float(e1.y);
            float n2 = __int_as_float(e2.y), n3 = __int_as_float(e3.y);
            ax += (float)a.h[0]*n0; ay += (float)a.h[1]*n0;
            ax += (float)b.h[0]*n1; ay += (float)b.h[1]*n1;
            ax += (float)c.h[0]*n2; ay += (float)c.h[1]*n2;
            ax += (float)e.h[0]*n3; ay += (float)e.h[1]*n3;
        }
        for (; k < k1; k++){
            int2 e0 = edge_s[k];
            F16x2U a; a.f = hlinH[(size_t)e0.x*32 + p];
            float n0 = __int_as_float(e0.y);
            ax += (float)a.h[0]*n0; ay += (float)a.h[1]*n0;
        }
        float vx = fmaxf(ax + bv.x, 0.f);
        float vy = fmaxf(ay + bv.y, 0.f);
        s0 += vx; q0 += vx*vx;
        s1 += vy; q1 += vy*vy;
        F16x2U o; o.h[0] = (_Float16)vx; o.h[1] = (_Float16)vy;
        g2Hf[(size_t)j*32 + p] = o.f;
    }
    __shared__ float sb[128];
    if (threadIdx.x < 128) sb[threadIdx.x] = 0.f;
    __syncthreads();
    atomicAdd(&sb[2*p],      s0);
    atomicAdd(&sb[2*p+1],    s1);
    atomicAdd(&sb[64+2*p],   q0);
    atomicAdd(&sb[64+2*p+1], q1);
    __syncthreads();
    if (threadIdx.x < 64){
        atomicAdd(&gsum2[threadIdx.x], sb[threadIdx.x]);
        atomicAdd(&gsq2[threadIdx.x],  sb[64+threadIdx.x]);
    }
}

// ---------- LSTM weight prep: B-fragment layout [K/32][256][32] f16 ----------
__global__ void prep_weights(const float* __restrict__ Wih1, const float* __restrict__ Whh1,
                             const float* __restrict__ bih1, const float* __restrict__ bhh1,
                             const float* __restrict__ Wih2, const float* __restrict__ Whh2,
                             const float* __restrict__ bih2, const float* __restrict__ bhh2,
                             _Float16* W1F, _Float16* W2F, float* b1c, float* b2c){
    int idx = blockIdx.x*blockDim.x + threadIdx.x;
    if (idx < 6*256*32){
        int kt = idx >> 13;
        int rem = idx & 8191;
        int n = rem >> 5, kin = rem & 31;
        int k = kt*32 + kin;
        float v = (k < 128) ? Wih1[n*128 + k] : Whh1[n*64 + (k-128)];
        W1F[idx] = (_Float16)v;
    }
    int i2 = idx - 6*256*32;
    if (i2 >= 0 && i2 < 4*256*32){
        int kt = i2 >> 13;
        int rem = i2 & 8191;
        int n = rem >> 5, kin = rem & 31;
        int k = kt*32 + kin;
        float v = (k < 64) ? Wih2[n*64 + k] : Whh2[n*64 + (k-64)];
        W2F[i2] = (_Float16)v;
    }
    int i3 = idx - (6*256*32 + 4*256*32);
    if (i3 >= 0 && i3 < 256) b1c[i3] = bih1[i3] + bhh1[i3];
    int i4 = i3 - 256;
    if (i4 >= 0 && i4 < 256) b2c[i4] = bih2[i4] + bhh2[i4];
}

// ---------- fused 12-step LSTM1+LSTM2, MFMA 16x16x32 f16, single launch ----------
// 16 rows/block, f16 inputs (h1H, g2H), BN2 applied inline (scale/shift
// computed from gsum2/gsq2 at kernel start). Register prefetch of t+1.
#define X1S 200   // halves/row, 400 B
#define X2S 136   // halves/row, 272 B
__global__ __launch_bounds__(256) void lstm_fused(
        const _Float16* __restrict__ h1H, const _Float16* __restrict__ g2H,
        const float* __restrict__ gsum2, const float* __restrict__ gsq2,
        const float* __restrict__ g2bn, const float* __restrict__ be2,
        const _Float16* __restrict__ W1F, const _Float16* __restrict__ W2F,
        const float* __restrict__ b1c, const float* __restrict__ b2c,
        float* __restrict__ h1s, float* __restrict__ h2s){
    __shared__ _Float16 X1h[16*X1S];
    __shared__ _Float16 X2h[16*X2S];
    int tid = threadIdx.x;
    int j0 = blockIdx.x*16;
    int w    = tid >> 6;
    int lane = tid & 63;
    int quad = lane >> 4;
    int l16  = lane & 15;
    int u    = 16*w + l16;

    // staging geometry: row sr, f16-quad c4
    int c4 = tid & 15;
    int sr = (tid >> 4) & 15;
    int sj = j0 + sr;
    int sb = sj / NN_SZ, sn = sj - sb*NN_SZ;
    size_t rbase = ((size_t)(sb*T_WIN)*NN_SZ + sn)*64 + c4*4;   // f16 elements; + t*NN_SZ*64
    float sc2v[4], sh2v[4];
    #pragma unroll
    for (int q = 0; q < 4; q++){
        int f = c4*4 + q;
        float mean = gsum2[f]*(1.0f/(float)N_NODES);
        float var  = fmaxf(gsq2[f]*(1.0f/(float)N_NODES) - mean*mean, 0.f);
        float sc_  = g2bn[f]*rsqrtf(var + BN_EPS);
        sc2v[q] = sc_; sh2v[q] = be2[f] - mean*sc_;
    }

    float c1r[4], c2r[4], h2r[4];
    #pragma unroll
    for (int i = 0; i < 4; i++){ c1r[i] = 0.f; c2r[i] = 0.f; h2r[i] = 0.f; }

    float bi1 = b1c[u], bf1 = b1c[64+u], bg1 = b1c[128+u], bo1 = b1c[192+u];
    float bi2 = b2c[u], bf2 = b2c[64+u], bg2 = b2c[128+u], bo2 = b2c[192+u];

    // t=0 staging
    {
        half4 v0 = *(const half4*)&h1H[rbase];
        half4 g4 = *(const half4*)&g2H[rbase];
        half4 v1;
        #pragma unroll
        for (int q = 0; q < 4; q++) v1[q] = (_Float16)((float)g4[q]*sc2v[q] + sh2v[q]);
        *(half4*)&X1h[sr*X1S + c4*4]       = v0;
        *(half4*)&X1h[sr*X1S + 64 + c4*4]  = v1;
        *(half4*)&X1h[sr*X1S + 128 + c4*4] = (half4){0,0,0,0};
    }
    __syncthreads();

    for (int t = 0; t < T_WIN; t++){
        // ---- issue t+1 prefetch (latency hidden under phase 1) ----
        half4 nv0, ng4;
        if (t < T_WIN-1){
            size_t rb = rbase + (size_t)(t+1)*NN_SZ*64;
            nv0 = *(const half4*)&h1H[rb];
            ng4 = *(const half4*)&g2H[rb];
        }

        // ---- phase 1: gates1 = X1 @ W1^T, K=192 ----
        f32x4 acc[4];
        #pragma unroll
        for (int g = 0; g < 4; g++) acc[g] = (f32x4){0.f,0.f,0.f,0.f};
        #pragma unroll
        for (int kt = 0; kt < 6; kt++){
            half8 a = *(const half8*)&X1h[l16*X1S + kt*32 + quad*8];
            #pragma unroll
            for (int g = 0; g < 4; g++){
                half8 b = *(const half8*)&W1F[(size_t)(kt*256 + 64*g + u)*32 + quad*8];
                acc[g] = __builtin_amdgcn_mfma_f32_16x16x32_f16(a, b, acc[g], 0, 0, 0);
            }
        }
        __syncthreads();   // B: X1h/X2h readers done -> write window opens

        // ---- cell update 1 (registers) + stage X2 + commit t+1 X1 ----
        #pragma unroll
        for (int r = 0; r < 4; r++){
            int rowl = quad*4 + r;
            float gi = acc[0][r] + bi1;
            float gf = acc[1][r] + bf1;
            float gg = acc[2][r] + bg1;
            float go = acc[3][r] + bo1;
            float cn = fsig(gf)*c1r[r] + fsig(gi)*ftanh(gg);
            float hn = fsig(go)*ftanh(cn);
            c1r[r] = cn;
            X2h[rowl*X2S + u]      = (_Float16)hn;
            X2h[rowl*X2S + 64 + u] = (_Float16)h2r[r];
            X1h[rowl*X1S + 128 + u] = (_Float16)hn;   // h1 prev for t+1
            if (t == T_WIN-1) h1s[(size_t)(j0 + rowl)*64 + u] = hn;
        }
        if (t < T_WIN-1){
            half4 v1;
            #pragma unroll
            for (int q = 0; q < 4; q++) v1[q] = (_Float16)((float)ng4[q]*sc2v[q] + sh2v[q]);
            *(half4*)&X1h[sr*X1S + c4*4]      = nv0;
            *(half4*)&X1h[sr*X1S + 64 + c4*4] = v1;
        }
        __syncthreads();   // C: X2h + next X1h ready

        // ---- phase 2: gates2 = X2 @ W2^T, K=128 ----
        f32x4 acc2[4];
        #pragma unroll
        for (int g = 0; g < 4; g++) acc2[g] = (f32x4){0.f,0.f,0.f,0.f};
        #pragma unroll
        for (int kt = 0; kt < 4; kt++){
            half8 a = *(const half8*)&X2h[l16*X2S + kt*32 + quad*8];
            #pragma unroll
            for (int g = 0; g < 4; g++){
                half8 b = *(const half8*)&W2F[(size_t)(kt*256 + 64*g + u)*32 + quad*8];
                acc2[g] = __builtin_amdgcn_mfma_f32_16x16x32_f16(a, b, acc2[g], 0, 0, 0);
            }
        }

        // ---- cell update 2 (registers only) ----
        #pragma unroll
        for (int r = 0; r < 4; r++){
            int rowl = quad*4 + r;
            float gi = acc2[0][r] + bi2;
            float gf = acc2[1][r] + bf2;
            float gg = acc2[2][r] + bg2;
            float go = acc2[3][r] + bo2;
            float cn = fsig(gf)*c2r[r] + fsig(gi)*ftanh(gg);
            float hn = fsig(go)*ftanh(cn);
            c2r[r] = cn;
            h2r[r] = hn;
            if (t == T_WIN-1) h2s[(size_t)(j0 + rowl)*64 + u] = hn;
        }
    }
}

// ---------- FC head ----------
__global__ __launch_bounds__(256) void fc_head(
        const float* __restrict__ h1s, const float* __restrict__ h2s,
        const float* __restrict__ inner, const float* __restrict__ x,
        const float* __restrict__ fc1_w, const float* __restrict__ fc1_b,
        const float* __restrict__ fc3_w, const float* __restrict__ fc3_b,
        float* __restrict__ out){
    __shared__ float zsm[4][226];
    int wv = threadIdx.x >> 6;
    int f  = threadIdx.x & 63;
    int j  = blockIdx.x*4 + wv;
    int b = j / NN_SZ, n = j - b*NN_SZ;
    for (int k = f; k < 225; k += 64){
        float v;
        if (k < 64)        v = h1s[j*64 + k];
        else if (k < 128)  v = h2s[j*64 + (k-64)];
        else if (k == 128) v = inner[j];
        else {
            int kk = k - 129;
            int w_ = kk >> 3, ff = kk & 7;
            v = x[((b*T_WIN + w_)*NN_SZ + n)*FIN + ff];
        }
        zsm[wv][k] = v;
    }
    __syncthreads();
    float acc = fc1_b[f];
    for (int k = 0; k < 225; k++) acc += zsm[wv][k]*fc1_w[k*64 + f];
    float p = fmaxf(acc, 0.f) * fc3_w[f];
    #pragma unroll
    for (int off = 32; off > 0; off >>= 1) p += __shfl_down(p, off, 64);
    if (f == 0) out[j] = fmaxf(p + fc3_b[0], 0.f);
}

extern "C" void kernel_launch(void* const* d_in, const int* in_sizes, int n_in,
                              void* d_out, int out_size, void* d_ws, size_t ws_size,
                              hipStream_t stream){
    const int*   adj  = (const int*)d_in[0];
    const int*   row  = adj;
    const int*   col  = adj + EDGES;
    const float* aw   = (const float*)d_in[1];
    const float* x    = (const float*)d_in[2];
    const float* inner= (const float*)d_in[3];
    const float* W1   = (const float*)d_in[4];
    const float* b1   = (const float*)d_in[5];
    const float* W2   = (const float*)d_in[6];
    const float* b2   = (const float*)d_in[7];
    const float* g1   = (const float*)d_in[8];
    const float* be1  = (const float*)d_in[9];
    const float* g2   = (const float*)d_in[10];
    const float* be2  = (const float*)d_in[11];
    const float* Wih1 = (const float*)d_in[12];
    const float* Whh1 = (const float*)d_in[13];
    const float* bih1 = (const float*)d_in[14];
    const float* bhh1 = (const float*)d_in[15];
    const float* Wih2 = (const float*)d_in[16];
    const float* Whh2 = (const float*)d_in[17];
    const float* bih2 = (const float*)d_in[18];
    const float* bhh2 = (const float*)d_in[19];
    const float* fc1w = (const float*)d_in[20];
    const float* fc1b = (const float*)d_in[21];
    const float* fc3w = (const float*)d_in[22];
    const float* fc3b = (const float*)d_in[23];
    float* out = (float*)d_out;

    float* ws = (float*)d_ws;
    const size_t NB = (size_t)N_NODES*64;            // 12,288,000 floats
    float* bufX = ws;                                 // hlinH -> LSTM outs + W
    float* bufY = ws + NB;                            // gcnA1 (fp32) -> g2H (f16)
    float* bufZ = ws + 2*NB;                          // h1H (f16) + ax
    int2*  edge_s  = (int2*)(ws + 3*NB);              // E int2
    float* degdis  = ws + 3*NB + (size_t)2*EDGES;     // N (dis)
    float* gsum    = degdis + N_NODES;                // 64
    float* gsq     = gsum + 64;                       // 64
    float* gsum2   = gsq + 64;                        // 64
    float* gsq2    = gsum2 + 64;                      // 64
    unsigned long long* dc = (unsigned long long*)(gsq2 + 64);   // N ull (8B-aligned)
    int* excl    = (int*)(dc + N_NODES);              // N
    int* bsum    = excl + N_NODES;                    // 1024
    int* bscan   = bsum + 1024;                       // 1024
    int* offsets = bscan + 1024;                      // N+2
    int* rank    = offsets + (N_NODES+2);             // E

    // phase-1 aliases
    float* hlinH = bufX;                              // N*32 floats (f16 pairs)
    _Float16* h1H = (_Float16*)bufZ;                  // N*64 f16
    float* ax    = bufZ + (size_t)N_NODES*32 + 64;    // N*8 fp32 (after h1H region)
    float* gcnA1 = bufY;                              // N*64 fp32
    float* g2Hf  = bufY;                              // N*32 floats (f16 pairs), after gcnA1 dead

    // LSTM-phase aliases into bufX (hlinH dead after gather2h)
    float* h1s = bufX;
    float* h2s = bufX + (size_t)BN_ROWS*64;
    _Float16* W1F = (_Float16*)(bufX + (size_t)4*BN_ROWS*64);   // 6*256*32 halves
    _Float16* W2F = W1F + 6*256*32;                             // 4*256*32 halves
    float* b1c = (float*)(W2F + 4*256*32);
    float* b2c = b1c + 256;

    // ---- edge preprocessing (rank captured from the packed atomic) ----
    hipMemsetAsync(dc, 0, N_NODES*sizeof(unsigned long long), stream);
    hipMemsetAsync(gsum, 0, 256*sizeof(float), stream);   // gsum/gsq/gsum2/gsq2
    edge_pre <<<(EDGES+255)/256, 256, 0, stream>>>(col, aw, dc, rank);
    scanA    <<<750, 256, 0, stream>>>(dc, excl, bsum);
    scanB    <<<1, 1024, 0, stream>>>(bsum, bscan, 750);
    scanC    <<<750, 256, 0, stream>>>(excl, bscan, dc, degdis, offsets);
    build_csr<<<(EDGES+255)/256, 256, 0, stream>>>(row, col, aw, rank, degdis, offsets, edge_s);

    // ---- GCN layer 1: aggregate in 8-wide space, then transform (+BN1 stats) ----
    aggx_k<<<N_NODES/32, 256, 0, stream>>>(offsets, edge_s, degdis, x, ax);
    lin1b_stats<<<1024, 256, 0, stream>>>(ax, W1, b1, gcnA1, gsum, gsq);

    // ---- fused BN1(inline finalize) + layer-2 linear (f16 h1 + f16 hlin) ----
    lin2_bn<<<N_NODES/L2ROWS, 128, 0, stream>>>(gcnA1, gsum, gsq, g1, be1, W2, h1H, hlinH);

    // ---- GCN layer 2 (f16 rows) + fused BN2 stats + f16 output ----
    gather2h<<<1024, 256, 0, stream>>>(offsets, edge_s, degdis, hlinH, b2, g2Hf, gsum2, gsq2);

    // ---- fused 12-step LSTM (BN2 inline; states in registers) ----
    prep_weights<<<(6*256*32 + 4*256*32 + 512 + 255)/256, 256, 0, stream>>>(
        Wih1, Whh1, bih1, bhh1, Wih2, Whh2, bih2, bhh2, W1F, W2F, b1c, b2c);
    lstm_fused<<<BN_ROWS/16, 256, 0, stream>>>(h1H, (const _Float16*)g2Hf,
                                               gsum2, gsq2, g2, be2,
                                               W1F, W2F, b1c, b2c, h1s, h2s);

    // ---- FC head ----
    fc_head<<<BN_ROWS/4, 256, 0, stream>>>(h1s, h2s, inner, x, fc1w, fc1b, fc3w, fc3b, out);
}

// Round 13
// 587.904 us; speedup vs baseline: 3.6442x; 1.0110x over previous
//
#include <hip/hip_runtime.h>
#include <math.h>

#define N_NODES 192000
#define EDGES   2000000
#define HID     64
#define BN_ROWS 16000   // B*NN
#define T_WIN   12
#define B_SZ    8
#define NN_SZ   2000
#define FIN     8
#define BN_EPS  1e-5f

typedef _Float16 f16x2 __attribute__((ext_vector_type(2)));
typedef _Float16 half4 __attribute__((ext_vector_type(4)));
typedef _Float16 half8 __attribute__((ext_vector_type(8)));
typedef float    f32x4 __attribute__((ext_vector_type(4)));
union F16x2U { float f; f16x2 h; };

// fast sigmoid/tanh: v_exp_f32 + v_rcp_f32 (~1 ulp; f16 inputs dominate error)
__device__ __forceinline__ float frcp(float x){
#if __has_builtin(__builtin_amdgcn_rcpf)
    return __builtin_amdgcn_rcpf(x);
#else
    return 1.0f/x;
#endif
}
__device__ __forceinline__ float fsig(float x){ return frcp(1.0f + __expf(-x)); }
__device__ __forceinline__ float ftanh(float x){ return fmaf(2.0f, fsig(2.0f*x), -1.0f); }

__device__ __forceinline__ float packf16(float a, float b){
    F16x2U u; u.h[0] = (_Float16)a; u.h[1] = (_Float16)b; return u.f;
}

// ---------- edge preprocessing ----------
__global__ void edge_pre(const int* __restrict__ col, const float* __restrict__ w,
                         unsigned long long* __restrict__ dc, int* __restrict__ rank){
    int e = blockIdx.x*blockDim.x + threadIdx.x;
    if (e < EDGES){
        int c = col[e];
        unsigned int fx = (unsigned int)(w[e]*16777216.0f + 0.5f);   // w in [0,1)
        unsigned long long old = atomicAdd(&dc[c], (1ULL << 32) | (unsigned long long)fx);
        rank[e] = (int)(old >> 32);
    }
}

__global__ void scanA(const unsigned long long* __restrict__ dc,
                      int* __restrict__ excl, int* __restrict__ bsum){
    __shared__ int sm[256];
    int i = blockIdx.x*256 + threadIdx.x;
    int v = (int)(dc[i] >> 32);
    sm[threadIdx.x] = v;
    __syncthreads();
    #pragma unroll
    for (int off = 1; off < 256; off <<= 1){
        int t = (threadIdx.x >= off) ? sm[threadIdx.x - off] : 0;
        __syncthreads();
        sm[threadIdx.x] += t;
        __syncthreads();
    }
    excl[i] = sm[threadIdx.x] - v;
    if (threadIdx.x == 255) bsum[blockIdx.x] = sm[255];
}

__global__ void scanB(const int* __restrict__ bsum, int* __restrict__ bscan, int nb){
    __shared__ int sm[1024];
    int tid = threadIdx.x;
    int v = (tid < nb) ? bsum[tid] : 0;
    sm[tid] = v;
    __syncthreads();
    #pragma unroll
    for (int off = 1; off < 1024; off <<= 1){
        int t = (tid >= off) ? sm[tid - off] : 0;
        __syncthreads();
        sm[tid] += t;
        __syncthreads();
    }
    bscan[tid] = sm[tid] - v;
}

__global__ void scanC(const int* __restrict__ excl, const int* __restrict__ bscan,
                      const unsigned long long* __restrict__ dc,
                      float* __restrict__ dis, int* __restrict__ offsets){
    int i = blockIdx.x*256 + threadIdx.x;
    offsets[i] = excl[i] + bscan[i >> 8];
    float deg = (float)(unsigned int)(dc[i] & 0xffffffffULL) * (1.0f/16777216.0f);
    dis[i] = rsqrtf(deg + 1.0f);   // + self-loop weight
    if (i == N_NODES-1) offsets[N_NODES] = EDGES;
}

// atomic-free CSR placement: p = offsets[c] + rank[e]
__global__ void build_csr(const int* __restrict__ row, const int* __restrict__ col,
                          const float* __restrict__ w, const int* __restrict__ rank,
                          const float* __restrict__ dis, const int* __restrict__ offsets,
                          int2* __restrict__ edge_s){
    int e = blockIdx.x*blockDim.x + threadIdx.x;
    if (e >= EDGES) return;
    int r = row[e], c = col[e];
    float nr = dis[r]*w[e]*dis[c];
    int p = offsets[c] + rank[e];
    int2 ev; ev.x = r; ev.y = __float_as_int(nr);
    edge_s[p] = ev;
}

// ---------- layer-1 aggregation in 8-wide input space: aggx = A_hat @ x ----------
__global__ __launch_bounds__(256) void aggx_k(
        const int* __restrict__ offsets, const int2* __restrict__ edge_s,
        const float* __restrict__ dis, const float* __restrict__ x,
        float* __restrict__ ax){
    int g   = blockIdx.x*32 + (threadIdx.x >> 3);
    int sub = threadIdx.x & 7;
    float d = dis[g];
    float acc = x[(size_t)g*8 + sub]*d*d;
    int k  = offsets[g];
    int k1 = offsets[g+1];
    for (; k+4 <= k1; k += 4){
        int2 e0 = edge_s[k], e1 = edge_s[k+1], e2 = edge_s[k+2], e3 = edge_s[k+3];
        float v0 = x[(size_t)e0.x*8 + sub];
        float v1 = x[(size_t)e1.x*8 + sub];
        float v2 = x[(size_t)e2.x*8 + sub];
        float v3 = x[(size_t)e3.x*8 + sub];
        acc += v0*__int_as_float(e0.y);
        acc += v1*__int_as_float(e1.y);
        acc += v2*__int_as_float(e2.y);
        acc += v3*__int_as_float(e3.y);
    }
    for (; k < k1; k++){
        int2 e0 = edge_s[k];
        acc += x[(size_t)e0.x*8 + sub]*__int_as_float(e0.y);
    }
    ax[(size_t)g*8 + sub] = acc;
}

// ---------- gcnA1 = relu(aggx @ W1 + b1), fused BN1 stats ----------
__global__ __launch_bounds__(256) void lin1b_stats(
        const float* __restrict__ ax, const float* __restrict__ W1,
        const float* __restrict__ b1, float* __restrict__ out,
        float* __restrict__ gsum, float* __restrict__ gsq){
    __shared__ float Ws[512];
    for (int i = threadIdx.x; i < 512; i += 256) Ws[i] = W1[i];
    __syncthreads();
    int f = threadIdx.x & 63;
    float wc[8];
    #pragma unroll
    for (int q = 0; q < 8; q++) wc[q] = Ws[q*64 + f];
    float bb = b1[f];
    float s = 0.f, s2 = 0.f;
    int stride = gridDim.x*blockDim.x;   // multiple of 64
    for (int idx = blockIdx.x*blockDim.x + threadIdx.x; idx < N_NODES*64; idx += stride){
        int j = idx >> 6;
        const float* ar = ax + (size_t)j*8;
        float acc = bb;
        #pragma unroll
        for (int q = 0; q < 8; q++) acc += ar[q]*wc[q];
        float v = fmaxf(acc, 0.f);
        out[idx] = v;
        s += v; s2 += v*v;
    }
    __shared__ float s1m[256], s2m[256];
    s1m[threadIdx.x] = s; s2m[threadIdx.x] = s2;
    __syncthreads();
    if (threadIdx.x < 64){
        float t1 = s1m[threadIdx.x]+s1m[threadIdx.x+64]+s1m[threadIdx.x+128]+s1m[threadIdx.x+192];
        float t2 = s2m[threadIdx.x]+s2m[threadIdx.x+64]+s2m[threadIdx.x+128]+s2m[threadIdx.x+192];
        atomicAdd(&gsum[threadIdx.x], t1);
        atomicAdd(&gsq[threadIdx.x], t2);
    }
}

// ---------- lin2_bn: h1H = f16(BN(gcnA1)); hlinH = pack_f16(BN(gcnA1) @ W2) ----------
#define L2ROWS 128
#define XS2    132
__global__ __launch_bounds__(128) void lin2_bn(
        const float* __restrict__ gcnA, const float* __restrict__ gsum,
        const float* __restrict__ gsq, const float* __restrict__ g1,
        const float* __restrict__ be1, const float* __restrict__ W2,
        _Float16* __restrict__ h1H, float* __restrict__ hlinH){
    __shared__ float Ws[64*64];
    __shared__ float xsT[64*XS2];
    int tid = threadIdx.x;
    int r0 = blockIdx.x * L2ROWS;

    for (int i = tid; i < 1024; i += 128)
        *(float4*)&Ws[i*4] = *(const float4*)&W2[i*4];

    int k4 = tid & 15;
    int rb = tid >> 4;
    float scv[4], shv[4];
    #pragma unroll
    for (int q = 0; q < 4; q++){
        int f = k4*4 + q;
        float mean = gsum[f]*(1.0f/(float)N_NODES);
        float var  = fmaxf(gsq[f]*(1.0f/(float)N_NODES) - mean*mean, 0.f);
        float sc_  = g1[f]*rsqrtf(var + BN_EPS);
        scv[q] = sc_; shv[q] = be1[f] - mean*sc_;
    }
    for (int it = 0; it < 16; it++){
        int r = it*8 + rb;
        float4 v = *(const float4*)&gcnA[(size_t)(r0+r)*64 + k4*4];
        v.x = v.x*scv[0]+shv[0]; v.y = v.y*scv[1]+shv[1];
        v.z = v.z*scv[2]+shv[2]; v.w = v.w*scv[3]+shv[3];
        half4 hh;
        hh[0]=(_Float16)v.x; hh[1]=(_Float16)v.y; hh[2]=(_Float16)v.z; hh[3]=(_Float16)v.w;
        *(half4*)&h1H[(size_t)(r0+r)*64 + k4*4] = hh;
        xsT[(k4*4+0)*XS2 + r] = v.x;
        xsT[(k4*4+1)*XS2 + r] = v.y;
        xsT[(k4*4+2)*XS2 + r] = v.z;
        xsT[(k4*4+3)*XS2 + r] = v.w;
    }
    __syncthreads();

    int cg = tid & 7;
    int rg = tid >> 3;
    float acc[8][8];
    #pragma unroll
    for (int i = 0; i < 8; i++)
        #pragma unroll
        for (int j = 0; j < 8; j++) acc[i][j] = 0.f;

    float4 a0 = *(float4*)&xsT[0*XS2 + rg*8];
    float4 a1 = *(float4*)&xsT[0*XS2 + rg*8 + 4];
    float4 w0 = *(float4*)&Ws[0*64 + cg*8];
    float4 w1 = *(float4*)&Ws[0*64 + cg*8 + 4];
    for (int k = 0; k < 64; k++){
        float4 na0, na1, nw0, nw1;
        if (k < 63){
            na0 = *(float4*)&xsT[(k+1)*XS2 + rg*8];
            na1 = *(float4*)&xsT[(k+1)*XS2 + rg*8 + 4];
            nw0 = *(float4*)&Ws[(k+1)*64 + cg*8];
            nw1 = *(float4*)&Ws[(k+1)*64 + cg*8 + 4];
        }
        float ar[8] = {a0.x,a0.y,a0.z,a0.w,a1.x,a1.y,a1.z,a1.w};
        float wcv[8] = {w0.x,w0.y,w0.z,w0.w,w1.x,w1.y,w1.z,w1.w};
        #pragma unroll
        for (int i = 0; i < 8; i++)
            #pragma unroll
            for (int j = 0; j < 8; j++) acc[i][j] += ar[i]*wcv[j];
        a0=na0; a1=na1; w0=nw0; w1=nw1;
    }
    #pragma unroll
    for (int i = 0; i < 8; i++){
        size_t r = (size_t)(r0 + rg*8 + i);
        float4 pk;
        pk.x = packf16(acc[i][0], acc[i][1]);
        pk.y = packf16(acc[i][2], acc[i][3]);
        pk.z = packf16(acc[i][4], acc[i][5]);
        pk.w = packf16(acc[i][6], acc[i][7]);
        *(float4*)&hlinH[r*32 + cg*4] = pk;
    }
}

// ---------- layer-2 gather over packed f16 rows, one-shot grid (max MLP) ----------
// R12 post-mortem: 1024-block grid-stride capped occupancy at 37% -> 112 us
// latency-bound. One block per 8 nodes (24000 blocks), stats moved out.
__global__ __launch_bounds__(256) void gather2h(
        const int* __restrict__ offsets, const int2* __restrict__ edge_s,
        const float* __restrict__ dis, const float* __restrict__ hlinH,
        const float* __restrict__ bias, float* __restrict__ g2Hf){
    int j = blockIdx.x*8 + (threadIdx.x >> 5);
    int p = threadIdx.x & 31;
    float d = dis[j];
    float dd = d*d;
    F16x2U u; u.f = hlinH[(size_t)j*32 + p];
    float ax = (float)u.h[0]*dd;
    float ay = (float)u.h[1]*dd;
    int k  = offsets[j];
    int k1 = offsets[j+1];
    for (; k+4 <= k1; k += 4){
        int2 e0 = edge_s[k], e1 = edge_s[k+1], e2 = edge_s[k+2], e3 = edge_s[k+3];
        F16x2U a, b, c, e;
        a.f = hlinH[(size_t)e0.x*32 + p];
        b.f = hlinH[(size_t)e1.x*32 + p];
        c.f = hlinH[(size_t)e2.x*32 + p];
        e.f = hlinH[(size_t)e3.x*32 + p];
        float n0 = __int_as_float(e0.y), n1 = __int_as_float(e1.y);
        float n2 = __int_as_float(e2.y), n3 = __int_as_float(e3.y);
        ax += (float)a.h[0]*n0; ay += (float)a.h[1]*n0;
        ax += (float)b.h[0]*n1; ay += (float)b.h[1]*n1;
        ax += (float)c.h[0]*n2; ay += (float)c.h[1]*n2;
        ax += (float)e.h[0]*n3; ay += (float)e.h[1]*n3;
    }
    for (; k < k1; k++){
        int2 e0 = edge_s[k];
        F16x2U a; a.f = hlinH[(size_t)e0.x*32 + p];
        float n0 = __int_as_float(e0.y);
        ax += (float)a.h[0]*n0; ay += (float)a.h[1]*n0;
    }
    float2 bv = *(const float2*)&bias[2*p];
    float vx = fmaxf(ax + bv.x, 0.f);
    float vy = fmaxf(ay + bv.y, 0.f);
    F16x2U o; o.h[0] = (_Float16)vx; o.h[1] = (_Float16)vy;
    g2Hf[(size_t)j*32 + p] = o.f;
}

// ---------- BN2 stats over f16 output (12.3 MB pass) ----------
__global__ __launch_bounds__(256) void stats2h(
        const float* __restrict__ g2Hf, float* __restrict__ gsum2, float* __restrict__ gsq2){
    int p = threadIdx.x & 31;
    float s0 = 0.f, s1 = 0.f, q0 = 0.f, q1 = 0.f;
    int stride = gridDim.x*blockDim.x;   // multiple of 32 -> p constant
    for (int idx = blockIdx.x*blockDim.x + threadIdx.x; idx < N_NODES*32; idx += stride){
        F16x2U u; u.f = g2Hf[idx];
        float vx = (float)u.h[0], vy = (float)u.h[1];
        s0 += vx; q0 += vx*vx;
        s1 += vy; q1 += vy*vy;
    }
    __shared__ float sb[128];
    if (threadIdx.x < 128) sb[threadIdx.x] = 0.f;
    __syncthreads();
    atomicAdd(&sb[2*p],      s0);
    atomicAdd(&sb[2*p+1],    s1);
    atomicAdd(&sb[64+2*p],   q0);
    atomicAdd(&sb[64+2*p+1], q1);
    __syncthreads();
    if (threadIdx.x < 64){
        atomicAdd(&gsum2[threadIdx.x], sb[threadIdx.x]);
        atomicAdd(&gsq2[threadIdx.x],  sb[64+threadIdx.x]);
    }
}

// ---------- LSTM weight prep: B-fragment layout [K/32][256][32] f16 ----------
__global__ void prep_weights(const float* __restrict__ Wih1, const float* __restrict__ Whh1,
                             const float* __restrict__ bih1, const float* __restrict__ bhh1,
                             const float* __restrict__ Wih2, const float* __restrict__ Whh2,
                             const float* __restrict__ bih2, const float* __restrict__ bhh2,
                             _Float16* W1F, _Float16* W2F, float* b1c, float* b2c){
    int idx = blockIdx.x*blockDim.x + threadIdx.x;
    if (idx < 6*256*32){
        int kt = idx >> 13;
        int rem = idx & 8191;
        int n = rem >> 5, kin = rem & 31;
        int k = kt*32 + kin;
        float v = (k < 128) ? Wih1[n*128 + k] : Whh1[n*64 + (k-128)];
        W1F[idx] = (_Float16)v;
    }
    int i2 = idx - 6*256*32;
    if (i2 >= 0 && i2 < 4*256*32){
        int kt = i2 >> 13;
        int rem = i2 & 8191;
        int n = rem >> 5, kin = rem & 31;
        int k = kt*32 + kin;
        float v = (k < 64) ? Wih2[n*64 + k] : Whh2[n*64 + (k-64)];
        W2F[i2] = (_Float16)v;
    }
    int i3 = idx - (6*256*32 + 4*256*32);
    if (i3 >= 0 && i3 < 256) b1c[i3] = bih1[i3] + bhh1[i3];
    int i4 = i3 - 256;
    if (i4 >= 0 && i4 < 256) b2c[i4] = bih2[i4] + bhh2[i4];
}

// ---------- fused 12-step LSTM1+LSTM2, MFMA 16x16x32 f16, single launch ----------
#define X1S 200   // halves/row, 400 B
#define X2S 136   // halves/row, 272 B
__global__ __launch_bounds__(256) void lstm_fused(
        const _Float16* __restrict__ h1H, const _Float16* __restrict__ g2H,
        const float* __restrict__ gsum2, const float* __restrict__ gsq2,
        const float* __restrict__ g2bn, const float* __restrict__ be2,
        const _Float16* __restrict__ W1F, const _Float16* __restrict__ W2F,
        const float* __restrict__ b1c, const float* __restrict__ b2c,
        float* __restrict__ h1s, float* __restrict__ h2s){
    __shared__ _Float16 X1h[16*X1S];
    __shared__ _Float16 X2h[16*X2S];
    int tid = threadIdx.x;
    int j0 = blockIdx.x*16;
    int w    = tid >> 6;
    int lane = tid & 63;
    int quad = lane >> 4;
    int l16  = lane & 15;
    int u    = 16*w + l16;

    int c4 = tid & 15;
    int sr = (tid >> 4) & 15;
    int sj = j0 + sr;
    int sb = sj / NN_SZ, sn = sj - sb*NN_SZ;
    size_t rbase = ((size_t)(sb*T_WIN)*NN_SZ + sn)*64 + c4*4;
    float sc2v[4], sh2v[4];
    #pragma unroll
    for (int q = 0; q < 4; q++){
        int f = c4*4 + q;
        float mean = gsum2[f]*(1.0f/(float)N_NODES);
        float var  = fmaxf(gsq2[f]*(1.0f/(float)N_NODES) - mean*mean, 0.f);
        float sc_  = g2bn[f]*rsqrtf(var + BN_EPS);
        sc2v[q] = sc_; sh2v[q] = be2[f] - mean*sc_;
    }

    float c1r[4], c2r[4], h2r[4];
    #pragma unroll
    for (int i = 0; i < 4; i++){ c1r[i] = 0.f; c2r[i] = 0.f; h2r[i] = 0.f; }

    float bi1 = b1c[u], bf1 = b1c[64+u], bg1 = b1c[128+u], bo1 = b1c[192+u];
    float bi2 = b2c[u], bf2 = b2c[64+u], bg2 = b2c[128+u], bo2 = b2c[192+u];

    {
        half4 v0 = *(const half4*)&h1H[rbase];
        half4 g4 = *(const half4*)&g2H[rbase];
        half4 v1;
        #pragma unroll
        for (int q = 0; q < 4; q++) v1[q] = (_Float16)((float)g4[q]*sc2v[q] + sh2v[q]);
        *(half4*)&X1h[sr*X1S + c4*4]       = v0;
        *(half4*)&X1h[sr*X1S + 64 + c4*4]  = v1;
        *(half4*)&X1h[sr*X1S + 128 + c4*4] = (half4){0,0,0,0};
    }
    __syncthreads();

    for (int t = 0; t < T_WIN; t++){
        half4 nv0, ng4;
        if (t < T_WIN-1){
            size_t rb = rbase + (size_t)(t+1)*NN_SZ*64;
            nv0 = *(const half4*)&h1H[rb];
            ng4 = *(const half4*)&g2H[rb];
        }

        // ---- phase 1: gates1 = X1 @ W1^T, K=192 ----
        f32x4 acc[4];
        #pragma unroll
        for (int g = 0; g < 4; g++) acc[g] = (f32x4){0.f,0.f,0.f,0.f};
        #pragma unroll
        for (int kt = 0; kt < 6; kt++){
            half8 a = *(const half8*)&X1h[l16*X1S + kt*32 + quad*8];
            #pragma unroll
            for (int g = 0; g < 4; g++){
                half8 b = *(const half8*)&W1F[(size_t)(kt*256 + 64*g + u)*32 + quad*8];
                acc[g] = __builtin_amdgcn_mfma_f32_16x16x32_f16(a, b, acc[g], 0, 0, 0);
            }
        }
        __syncthreads();

        // ---- cell update 1 + stage X2 + commit t+1 X1 ----
        #pragma unroll
        for (int r = 0; r < 4; r++){
            int rowl = quad*4 + r;
            float gi = acc[0][r] + bi1;
            float gf = acc[1][r] + bf1;
            float gg = acc[2][r] + bg1;
            float go = acc[3][r] + bo1;
            float cn = fsig(gf)*c1r[r] + fsig(gi)*ftanh(gg);
            float hn = fsig(go)*ftanh(cn);
            c1r[r] = cn;
            X2h[rowl*X2S + u]      = (_Float16)hn;
            X2h[rowl*X2S + 64 + u] = (_Float16)h2r[r];
            X1h[rowl*X1S + 128 + u] = (_Float16)hn;
            if (t == T_WIN-1) h1s[(size_t)(j0 + rowl)*64 + u] = hn;
        }
        if (t < T_WIN-1){
            half4 v1;
            #pragma unroll
            for (int q = 0; q < 4; q++) v1[q] = (_Float16)((float)ng4[q]*sc2v[q] + sh2v[q]);
            *(half4*)&X1h[sr*X1S + c4*4]      = nv0;
            *(half4*)&X1h[sr*X1S + 64 + c4*4] = v1;
        }
        __syncthreads();

        // ---- phase 2: gates2 = X2 @ W2^T, K=128 ----
        f32x4 acc2[4];
        #pragma unroll
        for (int g = 0; g < 4; g++) acc2[g] = (f32x4){0.f,0.f,0.f,0.f};
        #pragma unroll
        for (int kt = 0; kt < 4; kt++){
            half8 a = *(const half8*)&X2h[l16*X2S + kt*32 + quad*8];
            #pragma unroll
            for (int g = 0; g < 4; g++){
                half8 b = *(const half8*)&W2F[(size_t)(kt*256 + 64*g + u)*32 + quad*8];
                acc2[g] = __builtin_amdgcn_mfma_f32_16x16x32_f16(a, b, acc2[g], 0, 0, 0);
            }
        }

        // ---- cell update 2 ----
        #pragma unroll
        for (int r = 0; r < 4; r++){
            int rowl = quad*4 + r;
            float gi = acc2[0][r] + bi2;
            float gf = acc2[1][r] + bf2;
            float gg = acc2[2][r] + bg2;
            float go = acc2[3][r] + bo2;
            float cn = fsig(gf)*c2r[r] + fsig(gi)*ftanh(gg);
            float hn = fsig(go)*ftanh(cn);
            c2r[r] = cn;
            h2r[r] = hn;
            if (t == T_WIN-1) h2s[(size_t)(j0 + rowl)*64 + u] = hn;
        }
    }
}

// ---------- FC head ----------
__global__ __launch_bounds__(256) void fc_head(
        const float* __restrict__ h1s, const float* __restrict__ h2s,
        const float* __restrict__ inner, const float* __restrict__ x,
        const float* __restrict__ fc1_w, const float* __restrict__ fc1_b,
        const float* __restrict__ fc3_w, const float* __restrict__ fc3_b,
        float* __restrict__ out){
    __shared__ float zsm[4][226];
    int wv = threadIdx.x >> 6;
    int f  = threadIdx.x & 63;
    int j  = blockIdx.x*4 + wv;
    int b = j / NN_SZ, n = j - b*NN_SZ;
    for (int k = f; k < 225; k += 64){
        float v;
        if (k < 64)        v = h1s[j*64 + k];
        else if (k < 128)  v = h2s[j*64 + (k-64)];
        else if (k == 128) v = inner[j];
        else {
            int kk = k - 129;
            int w_ = kk >> 3, ff = kk & 7;
            v = x[((b*T_WIN + w_)*NN_SZ + n)*FIN + ff];
        }
        zsm[wv][k] = v;
    }
    __syncthreads();
    float acc = fc1_b[f];
    for (int k = 0; k < 225; k++) acc += zsm[wv][k]*fc1_w[k*64 + f];
    float p = fmaxf(acc, 0.f) * fc3_w[f];
    #pragma unroll
    for (int off = 32; off > 0; off >>= 1) p += __shfl_down(p, off, 64);
    if (f == 0) out[j] = fmaxf(p + fc3_b[0], 0.f);
}

extern "C" void kernel_launch(void* const* d_in, const int* in_sizes, int n_in,
                              void* d_out, int out_size, void* d_ws, size_t ws_size,
                              hipStream_t stream){
    const int*   adj  = (const int*)d_in[0];
    const int*   row  = adj;
    const int*   col  = adj + EDGES;
    const float* aw   = (const float*)d_in[1];
    const float* x    = (const float*)d_in[2];
    const float* inner= (const float*)d_in[3];
    const float* W1   = (const float*)d_in[4];
    const float* b1   = (const float*)d_in[5];
    const float* W2   = (const float*)d_in[6];
    const float* b2   = (const float*)d_in[7];
    const float* g1   = (const float*)d_in[8];
    const float* be1  = (const float*)d_in[9];
    const float* g2   = (const float*)d_in[10];
    const float* be2  = (const float*)d_in[11];
    const float* Wih1 = (const float*)d_in[12];
    const float* Whh1 = (const float*)d_in[13];
    const float* bih1 = (const float*)d_in[14];
    const float* bhh1 = (const float*)d_in[15];
    const float* Wih2 = (const float*)d_in[16];
    const float* Whh2 = (const float*)d_in[17];
    const float* bih2 = (const float*)d_in[18];
    const float* bhh2 = (const float*)d_in[19];
    const float* fc1w = (const float*)d_in[20];
    const float* fc1b = (const float*)d_in[21];
    const float* fc3w = (const float*)d_in[22];
    const float* fc3b = (const float*)d_in[23];
    float* out = (float*)d_out;

    float* ws = (float*)d_ws;
    const size_t NB = (size_t)N_NODES*64;            // 12,288,000 floats
    float* bufX = ws;                                 // hlinH -> LSTM outs + W
    float* bufY = ws + NB;                            // gcnA1 (fp32) -> g2H (f16)
    float* bufZ = ws + 2*NB;                          // h1H (f16) + ax
    int2*  edge_s  = (int2*)(ws + 3*NB);              // E int2
    float* degdis  = ws + 3*NB + (size_t)2*EDGES;     // N (dis)
    float* gsum    = degdis + N_NODES;                // 64
    float* gsq     = gsum + 64;                       // 64
    float* gsum2   = gsq + 64;                        // 64
    float* gsq2    = gsum2 + 64;                      // 64
    unsigned long long* dc = (unsigned long long*)(gsq2 + 64);   // N ull
    int* excl    = (int*)(dc + N_NODES);              // N
    int* bsum    = excl + N_NODES;                    // 1024
    int* bscan   = bsum + 1024;                       // 1024
    int* offsets = bscan + 1024;                      // N+2
    int* rank    = offsets + (N_NODES+2);             // E

    // phase-1 aliases
    float* hlinH = bufX;                              // N*32 floats (f16 pairs)
    _Float16* h1H = (_Float16*)bufZ;                  // N*64 f16
    float* ax    = bufZ + (size_t)N_NODES*32 + 64;    // N*8 fp32
    float* gcnA1 = bufY;                              // N*64 fp32
    float* g2Hf  = bufY;                              // N*32 floats (f16 pairs)

    // LSTM-phase aliases into bufX (hlinH dead after gather2h)
    float* h1s = bufX;
    float* h2s = bufX + (size_t)BN_ROWS*64;
    _Float16* W1F = (_Float16*)(bufX + (size_t)4*BN_ROWS*64);
    _Float16* W2F = W1F + 6*256*32;
    float* b1c = (float*)(W2F + 4*256*32);
    float* b2c = b1c + 256;

    // ---- edge preprocessing ----
    hipMemsetAsync(dc, 0, N_NODES*sizeof(unsigned long long), stream);
    hipMemsetAsync(gsum, 0, 256*sizeof(float), stream);   // gsum/gsq/gsum2/gsq2
    edge_pre <<<(EDGES+255)/256, 256, 0, stream>>>(col, aw, dc, rank);
    scanA    <<<750, 256, 0, stream>>>(dc, excl, bsum);
    scanB    <<<1, 1024, 0, stream>>>(bsum, bscan, 750);
    scanC    <<<750, 256, 0, stream>>>(excl, bscan, dc, degdis, offsets);
    build_csr<<<(EDGES+255)/256, 256, 0, stream>>>(row, col, aw, rank, degdis, offsets, edge_s);

    // ---- GCN layer 1 ----
    aggx_k<<<N_NODES/32, 256, 0, stream>>>(offsets, edge_s, degdis, x, ax);
    lin1b_stats<<<1024, 256, 0, stream>>>(ax, W1, b1, gcnA1, gsum, gsq);

    // ---- fused BN1(inline) + layer-2 linear ----
    lin2_bn<<<N_NODES/L2ROWS, 128, 0, stream>>>(gcnA1, gsum, gsq, g1, be1, W2, h1H, hlinH);

    // ---- GCN layer 2 (one-shot grid for max MLP) + separate f16 stats pass ----
    gather2h<<<N_NODES/8, 256, 0, stream>>>(offsets, edge_s, degdis, hlinH, b2, g2Hf);
    stats2h<<<1024, 256, 0, stream>>>(g2Hf, gsum2, gsq2);

    // ---- fused 12-step LSTM ----
    prep_weights<<<(6*256*32 + 4*256*32 + 512 + 255)/256, 256, 0, stream>>>(
        Wih1, Whh1, bih1, bhh1, Wih2, Whh2, bih2, bhh2, W1F, W2F, b1c, b2c);
    lstm_fused<<<BN_ROWS/16, 256, 0, stream>>>(h1H, (const _Float16*)g2Hf,
                                               gsum2, gsq2, g2, be2,
                                               W1F, W2F, b1c, b2c, h1s, h2s);

    // ---- FC head ----
    fc_head<<<BN_ROWS/4, 256, 0, stream>>>(h1s, h2s, inner, x, fc1w, fc1b, fc3w, fc3b, out);
}